// Round 3
// baseline (4505.613 us; speedup 1.0000x reference)
//
#include <hip/hip_runtime.h>
#include <float.h>

#define NPTS 2048
#define NB 8
#define KNN 8

__device__ __forceinline__ float leakyf(float x){ return x > 0.f ? x : 0.2f*x; }

#define BET(v1,i1,v2,i2) (((v1)>(v2)) || ((v1)==(v2) && (i1)<(i2)))

// sorted-insert into per-lane top-8 (value desc, index asc)
__device__ __forceinline__ void ins8(float tv[8], int tix[8], float v, int ci)
{
    if (BET(v,ci,tv[7],tix[7])){
        tv[7]=v; tix[7]=ci;
#pragma unroll
        for (int q=7;q>=1;q--){
            if (BET(tv[q],tix[q],tv[q-1],tix[q-1])){
                float t=tv[q]; tv[q]=tv[q-1]; tv[q-1]=t;
                int ti=tix[q]; tix[q]=tix[q-1]; tix[q-1]=ti;
            }
        }
    }
}

// wave-wide merge of 64 sorted per-lane top-8 lists; lane0 writes 8 winners.
// ci values are unique per row -> exactly one lane matches the winner.
__device__ __forceinline__ void merge_write8(float tv[8], int tix[8], int lane,
                                             int* __restrict__ dst)
{
    int h = 0;
#pragma unroll
    for (int r=0;r<8;r++){
        float v = (h<8)? tv[h] : -FLT_MAX;
        int  ci = (h<8)? tix[h] : 0x7fffffff;
        float bv = v; int bi = ci;
#pragma unroll
        for (int off=32; off; off>>=1){
            float ov = __shfl_xor(bv, off); int oi = __shfl_xor(bi, off);
            if (BET(ov,oi,bv,bi)){ bv=ov; bi=oi; }
        }
        if (h<8 && v==bv && ci==bi) h++;
        if (lane==0) dst[r] = bi;
    }
}

// ---------------- transpose x (B,3,N) -> xt (B*N, 3) ----------------
__global__ void transpose_x(const float* __restrict__ x, float* __restrict__ xt)
{
    int g = blockIdx.x*256 + threadIdx.x;
    if (g >= NB*NPTS) return;
    int b = g >> 11, n = g & 2047;
    const float* xb = x + (long)b*3*NPTS;
    xt[g*3+0] = xb[n];
    xt[g*3+1] = xb[NPTS+n];
    xt[g*3+2] = xb[2*NPTS+n];
}

// ---------------- FPS (all 3 stages, one block per batch) ----------------
// Non-contracted ops in XLA's order (square muls, left-fold adds): the 896-step
// sequential argmax chain must match the reference bitwise; FMA contraction
// would cascade into different selected indices.
template<int P>
__device__ void fps_stage(const float4* pts, int m, int* sel, int tid,
                          volatile float* wv, volatile int* wj)
{
    float cx[P], cy[P], cz[P], dist[P];
#pragma unroll
    for (int r=0;r<P;r++){
        float4 p = pts[r*256 + tid];
        cx[r]=p.x; cy[r]=p.y; cz[r]=p.z; dist[r]=1e10f;
    }
    int last = 0;
    if (tid==0) sel[0]=0;
    int lane = tid & 63, w = tid >> 6;
    for (int i=1;i<m;i++){
        float4 lp = pts[last];
        float bv = -1.f; int bj = 0x7fffffff;
#pragma unroll
        for (int r=0;r<P;r++){
            float dx=__fsub_rn(cx[r],lp.x), dy=__fsub_rn(cy[r],lp.y), dz=__fsub_rn(cz[r],lp.z);
            float d = __fadd_rn(__fadd_rn(__fmul_rn(dx,dx), __fmul_rn(dy,dy)), __fmul_rn(dz,dz));
            d = fminf(dist[r], d); dist[r] = d;
            int j = r*256 + tid;
            if (d > bv){ bv=d; bj=j; }          // ascending j -> lowest idx on tie
        }
#pragma unroll
        for (int off=32; off; off>>=1){
            float ov = __shfl_xor(bv, off); int oj = __shfl_xor(bj, off);
            if (ov > bv || (ov==bv && oj<bj)){ bv=ov; bj=oj; }
        }
        if (lane==0){ wv[w]=bv; wj[w]=bj; }
        __syncthreads();
        float fv = wv[0]; int fj = wj[0];
#pragma unroll
        for (int q=1;q<4;q++){
            float qv=wv[q]; int qj=wj[q];
            if (qv>fv || (qv==fv && qj<fj)){ fv=qv; fj=qj; }
        }
        last = fj;
        if (tid==0) sel[i]=last;
        __syncthreads();
    }
}

__global__ __launch_bounds__(256)
void fps_all(const float* __restrict__ x, int* __restrict__ idxF,
             float* __restrict__ coorOut)
{
    __shared__ float4 pts1[2048];
    __shared__ float4 pts2[512];
    __shared__ float4 pts3[256];
    __shared__ int sel1[512], sel2[256], sel3[128];
    __shared__ float wv[4];
    __shared__ int wj[4];
    int b = blockIdx.x, tid = threadIdx.x;
    const float* xb = x + (long)b*3*NPTS;
    for (int i=tid; i<2048; i+=256)
        pts1[i] = make_float4(xb[i], xb[NPTS+i], xb[2*NPTS+i], 0.f);
    __syncthreads();
    fps_stage<8>(pts1, 512, sel1, tid, wv, wj);
    __syncthreads();
    for (int i=tid;i<512;i+=256) pts2[i] = pts1[sel1[i]];
    __syncthreads();
    fps_stage<2>(pts2, 256, sel2, tid, wv, wj);
    __syncthreads();
    for (int i=tid;i<256;i+=256) pts3[i] = pts2[sel2[i]];
    __syncthreads();
    fps_stage<1>(pts3, 128, sel3, tid, wv, wj);
    __syncthreads();
    for (int i=tid;i<128;i+=256){
        int gi = sel1[sel2[sel3[i]]];
        idxF[b*128+i] = gi;
        float4 p = pts1[gi];
        coorOut[(long)b*384 + 0*128 + i] = p.x;
        coorOut[(long)b*384 + 1*128 + i] = p.y;
        coorOut[(long)b*384 + 2*128 + i] = p.z;
    }
}

// ---------------- block-1 fused kNN on raw coords (C=3) ----------------
__global__ __launch_bounds__(256)
void knn_c3(const float* __restrict__ x, int* __restrict__ idx)
{
    __shared__ float sx[NPTS], sy[NPTS], sz[NPTS];
    int b = blockIdx.x >> 5, rblk = blockIdx.x & 31;
    const float* xb = x + (long)b*3*NPTS;
    int tid = threadIdx.x;
    for (int i=tid;i<NPTS;i+=256){
        sx[i]=xb[i]; sy[i]=xb[NPTS+i]; sz[i]=xb[2*NPTS+i];
    }
    __syncthreads();
    int w = tid>>6, lane = tid&63;
    for (int rr=0; rr<16; rr++){
        int n = rblk*64 + w*16 + rr;
        float px=sx[n], py=sy[n], pz=sz[n];
        float tv[8]; int tix[8];
#pragma unroll
        for (int i=0;i<8;i++){ tv[i]=-FLT_MAX; tix[i]=0x7fffffff; }
        for (int it=0; it<8; it++){
            int c = it*256 + lane*4;
            float4 qx = *(const float4*)&sx[c];
            float4 qy = *(const float4*)&sy[c];
            float4 qz = *(const float4*)&sz[c];
            float dx, dy, dz;
            dx=qx.x-px; dy=qy.x-py; dz=qz.x-pz;
            ins8(tv,tix, -fmaf(dx,dx,fmaf(dy,dy,dz*dz)), c+0);
            dx=qx.y-px; dy=qy.y-py; dz=qz.y-pz;
            ins8(tv,tix, -fmaf(dx,dx,fmaf(dy,dy,dz*dz)), c+1);
            dx=qx.z-px; dy=qy.z-py; dz=qz.z-pz;
            ins8(tv,tix, -fmaf(dx,dx,fmaf(dy,dy,dz*dz)), c+2);
            dx=qx.w-px; dy=qy.w-py; dz=qz.w-pz;
            ins8(tv,tix, -fmaf(dx,dx,fmaf(dy,dy,dz*dz)), c+3);
        }
        merge_write8(tv, tix, lane, idx + ((long)(b*NPTS+n))*KNN);
    }
}

// ---------------- weight prep: wcat = [w1 ; w2-w1 ; rw] ----------------
__global__ void prep_w(const float* __restrict__ w, const float* __restrict__ rw,
                       float* __restrict__ wcat, int O, int C, int hasR)
{
    int t = blockIdx.x*256 + threadIdx.x;
    if (t >= O*C) return;
    int o = t / C, c = t % C;
    float a = w[o*2*C + c];
    wcat[o*C + c] = a;
    wcat[(O+o)*C + c] = w[o*2*C + C + c] - a;
    if (hasR) wcat[(2*O+o)*C + c] = rw[o*C + c];
}

// ---------------- row squared norms ----------------
__global__ void rownorm(const float* __restrict__ X, float* __restrict__ xx,
                        int lda, int C)
{
    int g = blockIdx.x*256 + threadIdx.x;
    if (g >= NB*NPTS) return;
    const float* r = X + (long)g*lda;
    float s = 0.f;
    for (int c=0;c<C;c++) s += r[c]*r[c];
    xx[g] = s;
}

// ---------------- generic GEMM: C[m][n] = sum_k A[m][k]*B[n][k] ----------------
// SYM: A==B square output; compute lower-triangle tiles only, store tile and
// its transpose (values bitwise-symmetric since mul commutes, same sum order).
template<int VEC, bool SYM>
__global__ __launch_bounds__(256)
void gemm_nt(const float* __restrict__ A, const float* __restrict__ B,
             float* __restrict__ C,
             int M, int Nc, int Kd, int lda, int ldb, int ldc,
             long sA, long sB, long sC)
{
    if (SYM && blockIdx.y > blockIdx.x) return;
    int bz = blockIdx.z;
    A += (long)bz * sA; B += (long)bz * sB; C += (long)bz * sC;
    int tm = blockIdx.y * 128, tn = blockIdx.x * 128;
    __shared__ __align__(16) float As[16][132];
    __shared__ __align__(16) float Bs[16][132];
    int tid = threadIdx.x;
    int ty = tid >> 4, tx = tid & 15;
    int cn0 = tx*4, cn1 = 64 + tx*4;
    float acc[8][8] = {};
    for (int k0 = 0; k0 < Kd; k0 += 16){
        if (VEC == 4){
#pragma unroll
            for (int i=0;i<2;i++){
                int e = tid + i*256;
                int rr = e >> 2, kq = e & 3;
                float4 av = *(const float4*)(A + (long)(tm+rr)*lda + k0 + kq*4);
                float4 bv = *(const float4*)(B + (long)(tn+rr)*ldb + k0 + kq*4);
                As[kq*4+0][rr]=av.x; As[kq*4+1][rr]=av.y; As[kq*4+2][rr]=av.z; As[kq*4+3][rr]=av.w;
                Bs[kq*4+0][rr]=bv.x; Bs[kq*4+1][rr]=bv.y; Bs[kq*4+2][rr]=bv.z; Bs[kq*4+3][rr]=bv.w;
            }
        } else {
#pragma unroll
            for (int i=0;i<8;i++){
                int e = tid + i*256;
                int kk = e & 15, rr = e >> 4;
                int ak = k0 + kk;
                As[kk][rr] = (ak < Kd) ? A[(long)(tm+rr)*lda + ak] : 0.f;
                Bs[kk][rr] = (ak < Kd) ? B[(long)(tn+rr)*ldb + ak] : 0.f;
            }
        }
        __syncthreads();
#pragma unroll
        for (int kk=0;kk<16;kk++){
            float4 a01 = *(const float4*)&As[kk][ty*8];
            float4 a23 = *(const float4*)&As[kk][ty*8+4];
            float4 b01 = *(const float4*)&Bs[kk][cn0];
            float4 b23 = *(const float4*)&Bs[kk][cn1];
            float aa[8] = {a01.x,a01.y,a01.z,a01.w,a23.x,a23.y,a23.z,a23.w};
            float bb[8] = {b01.x,b01.y,b01.z,b01.w,b23.x,b23.y,b23.z,b23.w};
#pragma unroll
            for (int i=0;i<8;i++)
#pragma unroll
                for (int j=0;j<8;j++)
                    acc[i][j] += aa[i]*bb[j];
        }
        __syncthreads();
    }
#pragma unroll
    for (int i=0;i<8;i++){
        long r = tm + ty*8 + i;
        float4 v0 = {acc[i][0],acc[i][1],acc[i][2],acc[i][3]};
        float4 v1 = {acc[i][4],acc[i][5],acc[i][6],acc[i][7]};
        *(float4*)(C + r*ldc + tn + cn0) = v0;
        *(float4*)(C + r*ldc + tn + cn1) = v1;
    }
    if (SYM && blockIdx.x != blockIdx.y){
#pragma unroll
        for (int j=0;j<4;j++){
            long r0 = tn + cn0 + j;
            long r1 = tn + cn1 + j;
            float4 u0 = {acc[0][j],  acc[1][j],  acc[2][j],  acc[3][j]};
            float4 u1 = {acc[4][j],  acc[5][j],  acc[6][j],  acc[7][j]};
            float4 u2 = {acc[0][j+4],acc[1][j+4],acc[2][j+4],acc[3][j+4]};
            float4 u3 = {acc[4][j+4],acc[5][j+4],acc[6][j+4],acc[7][j+4]};
            *(float4*)(C + r0*ldc + tm + ty*8)     = u0;
            *(float4*)(C + r0*ldc + tm + ty*8 + 4) = u1;
            *(float4*)(C + r1*ldc + tm + ty*8)     = u2;
            *(float4*)(C + r1*ldc + tm + ty*8 + 4) = u3;
        }
    }
}

// ---------------- top-8 per row of D (value = 2*dot - xx[m]) ----------------
__global__ __launch_bounds__(256)
void topk8(const float* __restrict__ D, const float* __restrict__ xx,
           int* __restrict__ idx, int b0)
{
    int tid = threadIdx.x, w = tid>>6, lane = tid & 63;
    int gr = blockIdx.x*4 + w;               // row within 2-batch chunk
    int b = b0 + (gr >> 11);
    const float* drow = D + (long)gr*NPTS;
    const float* xb = xx + (long)b*NPTS;
    float tv[8]; int tix[8];
#pragma unroll
    for (int i=0;i<8;i++){ tv[i]=-FLT_MAX; tix[i]=0x7fffffff; }
    for (int it=0; it<8; it++){
        int c = it*256 + lane*4;
        float4 d4 = *(const float4*)(drow + c);
        float4 x4 = *(const float4*)(xb + c);
        ins8(tv,tix, 2.f*d4.x - x4.x, c+0);
        ins8(tv,tix, 2.f*d4.y - x4.y, c+1);
        ins8(tv,tix, 2.f*d4.z - x4.z, c+2);
        ins8(tv,tix, 2.f*d4.w - x4.w, c+3);
    }
    merge_write8(tv, tix, lane, idx + ((long)(b0*NPTS) + gr)*KNN);
}

// ---------------- edge bn stats: per-channel sum/sumsq of f = u[j]+v[n] ----------------
__global__ __launch_bounds__(256)
void stats_edge(const float* __restrict__ uvr, const int* __restrict__ idx,
                float* __restrict__ ps, float* __restrict__ pq, int O, int ld)
{
    int tid = threadIdx.x;
    int r0 = blockIdx.x * 128;
    float s0=0,q0=0,s1=0,q1=0;
    for (int rr=0; rr<128; rr++){
        int g = r0 + rr;
        int b = g >> 11;
        const int* ip = idx + (long)g*KNN;
        const float* vrow = uvr + (long)g*ld + O;
        const float* ub[8];
#pragma unroll
        for (int k=0;k<8;k++) ub[k] = uvr + (long)((b<<11) + ip[k])*ld;
        int o = tid;
        if (o < O){
            float vv = vrow[o];
#pragma unroll
            for (int k=0;k<8;k++){ float f = ub[k][o]+vv; s0+=f; q0+=f*f; }
        }
        o = tid + 256;
        if (o < O){
            float vv = vrow[o];
#pragma unroll
            for (int k=0;k<8;k++){ float f = ub[k][o]+vv; s1+=f; q1+=f*f; }
        }
    }
    if (tid < O){ ps[blockIdx.x*2048 + tid] = s0; pq[blockIdx.x*2048 + tid] = q0; }
    if (tid+256 < O){ ps[blockIdx.x*2048 + tid+256] = s1; pq[blockIdx.x*2048 + tid+256] = q1; }
}

// ---------------- stats -> affine (a, c) ----------------
__global__ void reduce_stats(const float* __restrict__ ps, const float* __restrict__ pq,
                             const float* __restrict__ gam, const float* __restrict__ bet,
                             float* __restrict__ ab, float* __restrict__ cb,
                             int O, int np, float invCnt)
{
    int o = blockIdx.x*256 + threadIdx.x;
    if (o >= O) return;
    float s=0.f, q=0.f;
    for (int p=0;p<np;p++){ s += ps[p*2048 + o]; q += pq[p*2048 + o]; }
    float m = s * invCnt;
    float var = q * invCnt - m*m;
    float a = gam[o] * rsqrtf(var + 1e-5f);
    ab[o] = a;
    cb[o] = bet[o] - m*a;
}

// ---------------- edge finalize: out = leaky(bn(max_k f)) + residual ----------------
__global__ __launch_bounds__(256)
void finalize_edge(const float* __restrict__ uvr, const int* __restrict__ idx,
                   const float* __restrict__ ab, const float* __restrict__ cb,
                   float* __restrict__ hcat, int O, int ld, int hoff, int hasR)
{
    int tid = threadIdx.x;
    int r0 = blockIdx.x * 8;
    for (int rr=0; rr<8; rr++){
        int g = r0 + rr;
        int b = g >> 11;
        const int* ip = idx + (long)g*KNN;
        const float* vrow = uvr + (long)g*ld + O;
        const float* rrow = vrow + O;
        const float* ub[8];
#pragma unroll
        for (int k=0;k<8;k++) ub[k] = uvr + (long)((b<<11) + ip[k])*ld;
        for (int t=0;t<2;t++){
            int o = tid + t*256;
            if (o >= O) break;
            float vv = vrow[o];
            float mx = -FLT_MAX, mn = FLT_MAX;
#pragma unroll
            for (int k=0;k<8;k++){
                float f = ub[k][o] + vv;
                mx = fmaxf(mx, f); mn = fminf(mn, f);
            }
            float a = ab[o], c = cb[o];
            float zz = (a > 0.f) ? (a*mx + c) : (a*mn + c);
            float outv = leakyf(zz);
            if (hasR) outv += rrow[o];
            hcat[(long)g*1024 + hoff + o] = outv;
        }
    }
}

// ---------------- column sums of hcat -> partials -> hbar ----------------
__global__ void colsum_part(const float* __restrict__ H, float* __restrict__ part)
{
    int pb = blockIdx.x;                      // 128 blocks x 128 rows
    int tid = threadIdx.x;
    const float4* h4 = (const float4*)(H + (long)pb*128*1024);
    float4 acc = {0,0,0,0};
    for (int r=0;r<128;r++){
        float4 v = h4[r*256 + tid];
        acc.x+=v.x; acc.y+=v.y; acc.z+=v.z; acc.w+=v.w;
    }
    ((float4*)part)[pb*256 + tid] = acc;
}
__global__ void colsum_fin(const float* __restrict__ part, float* __restrict__ hbar)
{
    int tid = threadIdx.x;
    float4 acc = {0,0,0,0};
    for (int p=0;p<128;p++){
        float4 v = ((const float4*)part)[p*256 + tid];
        acc.x+=v.x; acc.y+=v.y; acc.z+=v.z; acc.w+=v.w;
    }
    ((float4*)hbar)[tid] = acc;
}

// ---------------- Gram partials: P[p] += Hchunk^T * Hchunk (lower tiles) ----------------
__global__ __launch_bounds__(256)
void gram_tn(const float* __restrict__ A, float* __restrict__ P)
{
    if (blockIdx.y < blockIdx.x) return;      // compute ti>=tj (lower+diag)
    int ti = blockIdx.y*128, tj = blockIdx.x*128;
    int bz = blockIdx.z;                      // 16 chunks of 1024 rows
    __shared__ __align__(16) float As[32][132];
    __shared__ __align__(16) float Bs[32][132];
    int tid = threadIdx.x;
    int ty = tid>>4, tx = tid&15;
    float acc[8][8] = {};
    const float* Abase = A + (long)bz*1024*1024;
    for (int k0=0; k0<1024; k0+=32){
#pragma unroll
        for (int i=0;i<4;i++){
            int e = tid + i*256;
            int mm = e>>5, c4 = (e&31)*4;
            const float* arow = Abase + (long)(k0+mm)*1024;
            *(float4*)&As[mm][c4] = *(const float4*)(arow + ti + c4);
            *(float4*)&Bs[mm][c4] = *(const float4*)(arow + tj + c4);
        }
        __syncthreads();
#pragma unroll
        for (int mm=0;mm<32;mm++){
            float4 a01 = *(const float4*)&As[mm][ty*8];
            float4 a23 = *(const float4*)&As[mm][ty*8+4];
            float4 b01 = *(const float4*)&Bs[mm][tx*4];
            float4 b23 = *(const float4*)&Bs[mm][64+tx*4];
            float aa[8] = {a01.x,a01.y,a01.z,a01.w,a23.x,a23.y,a23.z,a23.w};
            float bb[8] = {b01.x,b01.y,b01.z,b01.w,b23.x,b23.y,b23.z,b23.w};
#pragma unroll
            for (int i=0;i<8;i++)
#pragma unroll
                for (int j=0;j<8;j++)
                    acc[i][j] += aa[i]*bb[j];
        }
        __syncthreads();
    }
    float* Pp = P + ((long)bz<<20);
#pragma unroll
    for (int i=0;i<8;i++){
        long r = ti + ty*8 + i;
        float4 v0 = {acc[i][0],acc[i][1],acc[i][2],acc[i][3]};
        float4 v1 = {acc[i][4],acc[i][5],acc[i][6],acc[i][7]};
        *(float4*)(Pp + r*1024 + tj + tx*4)      = v0;
        *(float4*)(Pp + r*1024 + tj + 64 + tx*4) = v1;
    }
}

__global__ void greduce(const float* __restrict__ P, float* __restrict__ G)
{
    long i4 = (long)blockIdx.x*256 + threadIdx.x;   // over 1<<18 float4
    float4 a = ((const float4*)P)[i4];
    for (int p=1;p<16;p++){
        float4 v = ((const float4*)P)[((long)p<<18) + i4];
        a.x+=v.x; a.y+=v.y; a.z+=v.z; a.w+=v.w;
    }
    ((float4*)G)[i4] = a;
}

// fill strictly-upper 64x64 tiles of G from lower triangle
__global__ void mirror_g(float* __restrict__ G)
{
    __shared__ float t[64][65];
    int q = blockIdx.x, I = 0, acc = 15;
    while (q >= acc){ q -= acc; acc--; I++; }
    int J = I + 1 + q;                         // J > I, 16 tiles of 64
    int tid = threadIdx.x;
#pragma unroll
    for (int k=0;k<16;k++){
        int e = tid + k*256;
        int sr = e>>6, sc = e&63;
        t[sr][sc] = G[(long)(J*64+sr)*1024 + I*64+sc];
    }
    __syncthreads();
#pragma unroll
    for (int k=0;k<16;k++){
        int e = tid + k*256;
        int dr = e>>6, dc = e&63;
        G[(long)(I*64+dr)*1024 + J*64+dc] = t[dc][dr];
    }
}

// ---------------- bn1d affine from Gram: m=w5.hbar/N, q=w5.T(row)/N ----------------
__global__ void bn5_prep(const float* __restrict__ w5, const float* __restrict__ T,
                         const float* __restrict__ hbar,
                         const float* __restrict__ g5, const float* __restrict__ b5,
                         float* __restrict__ ab, float* __restrict__ cb)
{
    int w = threadIdx.x>>6, lane = threadIdx.x&63;
    int n = blockIdx.x*4 + w;
    const float4* wr = (const float4*)(w5 + (long)n*1024);
    const float4* tr = (const float4*)(T  + (long)n*1024);
    const float4* hb = (const float4*)hbar;
    float s1=0.f, s2=0.f;
    for (int i=lane;i<256;i+=64){
        float4 wv = wr[i], t4 = tr[i], hv = hb[i];
        s1 += wv.x*hv.x + wv.y*hv.y + wv.z*hv.z + wv.w*hv.w;
        s2 += wv.x*t4.x + wv.y*t4.y + wv.z*t4.z + wv.w*t4.w;
    }
#pragma unroll
    for (int off=32; off; off>>=1){
        s1 += __shfl_xor(s1, off);
        s2 += __shfl_xor(s2, off);
    }
    if (lane==0){
        float m = s1*(1.f/16384.f);
        float qq = s2*(1.f/16384.f);
        float var = qq - m*m;
        float a = g5[n]*rsqrtf(var+1e-5f);
        ab[n]=a; cb[n]=b5[n]-m*a;
    }
}

// ---------------- gather selected hcat rows ----------------
__global__ void gather_rows(const float* __restrict__ src, const int* __restrict__ idxF,
                            float* __restrict__ dst)
{
    int r = blockIdx.x;                    // 0..1023  (b*128+i)
    int b = r >> 7;
    int srow = (b<<11) + idxF[r];
    const float4* s = (const float4*)(src + (long)srow*1024);
    float4* d = (float4*)(dst + (long)r*1024);
    for (int c=threadIdx.x; c<256; c+=256) d[c] = s[c];
}

// ---------------- final f: bn + leaky + max/mean over 128 points ----------------
__global__ void finalize_f(const float* __restrict__ zsel, const float* __restrict__ ab,
                           const float* __restrict__ cb, float* __restrict__ out)
{
    int b = blockIdx.x >> 3, oc = blockIdx.x & 7;
    int o = oc*256 + threadIdx.x;
    float a = ab[o], c = cb[o];
    float mx = -FLT_MAX, sm = 0.f;
    const float* zp = zsel + (long)b*128*2048 + o;
    for (int i=0;i<128;i++){
        float v = leakyf(a*zp[(long)i*2048] + c);
        mx = fmaxf(mx, v); sm += v;
    }
    out[b*4096 + o] = mx;
    out[b*4096 + 2048 + o] = sm * (1.f/128.f);
}

extern "C" void kernel_launch(void* const* d_in, const int* in_sizes, int n_in,
                              void* d_out, int out_size, void* d_ws, size_t ws_size,
                              hipStream_t stream)
{
    (void)in_sizes; (void)n_in; (void)out_size; (void)ws_size;
    const float* x   = (const float*)d_in[0];
    const float* w1  = (const float*)d_in[1];
    const float* w2  = (const float*)d_in[2];
    const float* w3  = (const float*)d_in[3];
    const float* w4  = (const float*)d_in[4];
    const float* w5  = (const float*)d_in[5];
    const float* rw1 = (const float*)d_in[6];
    const float* rw2 = (const float*)d_in[7];
    const float* rw3 = (const float*)d_in[8];
    const float* g1  = (const float*)d_in[9];  const float* b1 = (const float*)d_in[10];
    const float* g2  = (const float*)d_in[11]; const float* b2 = (const float*)d_in[12];
    const float* g3  = (const float*)d_in[13]; const float* b3 = (const float*)d_in[14];
    const float* g4  = (const float*)d_in[15]; const float* b4 = (const float*)d_in[16];
    const float* g5  = (const float*)d_in[17]; const float* b5 = (const float*)d_in[18];
    float* out = (float*)d_out;

    char* wsb = (char*)d_ws;
    size_t off = 0;
    auto alloc = [&](size_t bytes)->char* {
        char* p = wsb + off;
        off += (bytes + 255) & ~(size_t)255;
        return p;
    };
    float* xt    = (float*)alloc((size_t)16384*3*4);
    float* hcat  = (float*)alloc((size_t)16384*1024*4);
    float* uvr   = (float*)alloc((size_t)16384*1536*4);   // aliased: Dbuf, gram P
    float* Dbuf  = uvr;
    float* gramP = uvr;                                   // 16 x 1M floats = 64MB
    float* G     = (float*)alloc((size_t)1024*1024*4);
    float* T     = (float*)alloc((size_t)2048*1024*4);
    float* zselA = (float*)alloc((size_t)1024*1024*4);
    float* zsel  = (float*)alloc((size_t)1024*2048*4);
    float* xx    = (float*)alloc((size_t)16384*4);
    int*   idx   = (int*)  alloc((size_t)16384*8*4);
    float* wcat  = (float*)alloc((size_t)1536*256*4);
    float* ps    = (float*)alloc((size_t)128*2048*4);
    float* pq    = (float*)alloc((size_t)128*2048*4);
    float* cspart= (float*)alloc((size_t)128*1024*4);
    float* hbar  = (float*)alloc((size_t)1024*4);
    float* ab    = (float*)alloc((size_t)2048*4);
    float* cb    = (float*)alloc((size_t)2048*4);
    int*   idxF  = (int*)  alloc((size_t)1024*4);

    transpose_x<<<64, 256, 0, stream>>>(x, xt);
    fps_all<<<8, 256, 0, stream>>>(x, idxF, out);   // writes coor part of d_out

    struct EB {
        const float* X; int lda, C, O, hoff, hasR;
        const float* w; const float* rw; const float* g; const float* bb;
    };
    EB eb[4] = {
        { xt,        3,    3,   128, 0,   0, w1, nullptr, g1, b1 },
        { hcat+0,    1024, 128, 128, 128, 1, w2, rw1,     g2, b2 },
        { hcat+128,  1024, 128, 256, 256, 1, w3, rw2,     g3, b3 },
        { hcat+256,  1024, 256, 512, 512, 1, w4, rw3,     g4, b4 },
    };
    for (int i=0;i<4;i++){
        EB e = eb[i];
        int ld = (2 + e.hasR) * e.O;
        int tot = e.O * e.C;
        prep_w<<<(tot+255)/256, 256, 0, stream>>>(e.w, e.rw, wcat, e.O, e.C, e.hasR);
        if (i == 0){
            knn_c3<<<256, 256, 0, stream>>>(x, idx);
            gemm_nt<1,false><<<dim3(ld/128, 128, 1), 256, 0, stream>>>(
                e.X, wcat, uvr, 16384, ld, e.C, e.lda, e.C, ld, 0, 0, 0);
        } else {
            rownorm<<<64, 256, 0, stream>>>(e.X, xx, e.lda, e.C);
            for (int b0=0; b0<8; b0+=2){
                const float* Ab = e.X + (long)b0*NPTS*e.lda;
                gemm_nt<4,true><<<dim3(16,16,2), 256, 0, stream>>>(
                    Ab, Ab, Dbuf, 2048, 2048, e.C, e.lda, e.lda, 2048,
                    (long)NPTS*e.lda, (long)NPTS*e.lda, (long)NPTS*NPTS);
                topk8<<<1024, 256, 0, stream>>>(Dbuf, xx, idx, b0);
            }
            gemm_nt<4,false><<<dim3(ld/128, 128, 1), 256, 0, stream>>>(
                e.X, wcat, uvr, 16384, ld, e.C, e.lda, e.C, ld, 0, 0, 0);
        }
        stats_edge<<<128, 256, 0, stream>>>(uvr, idx, ps, pq, e.O, ld);
        reduce_stats<<<(e.O+255)/256, 256, 0, stream>>>(ps, pq, e.g, e.bb, ab, cb,
                                                        e.O, 128, 1.f/131072.f);
        finalize_edge<<<2048, 256, 0, stream>>>(uvr, idx, ab, cb, hcat, e.O, ld,
                                                e.hoff, e.hasR);
    }

    // ----- block 5 via Gram: stats without materializing z -----
    colsum_part<<<128, 256, 0, stream>>>(hcat, cspart);
    colsum_fin<<<1, 256, 0, stream>>>(cspart, hbar);
    gram_tn<<<dim3(8,8,16), 256, 0, stream>>>(hcat, gramP);
    greduce<<<1024, 256, 0, stream>>>(gramP, G);
    mirror_g<<<120, 256, 0, stream>>>(G);
    gemm_nt<4,false><<<dim3(8,16,1), 256, 0, stream>>>(
        w5, G, T, 2048, 1024, 1024, 1024, 1024, 1024, 0, 0, 0);
    bn5_prep<<<512, 256, 0, stream>>>(w5, T, hbar, g5, b5, ab, cb);
    gather_rows<<<1024, 256, 0, stream>>>(hcat, idxF, zselA);
    gemm_nt<4,false><<<dim3(16,8,1), 256, 0, stream>>>(
        zselA, w5, zsel, 1024, 2048, 1024, 1024, 1024, 2048, 0, 0, 0);
    finalize_f<<<64, 256, 0, stream>>>(zsel, ab, cb, out + 3072);
}

// Round 5
// 4312.944 us; speedup vs baseline: 1.0447x; 1.0447x over previous
//
#include <hip/hip_runtime.h>
#include <float.h>

#define NPTS 2048
#define NB 8
#define KNN 8

__device__ __forceinline__ float leakyf(float x){ return x > 0.f ? x : 0.2f*x; }

#define BET(v1,i1,v2,i2) (((v1)>(v2)) || ((v1)==(v2) && (i1)<(i2)))

// sorted-insert into per-lane top-8 (value desc, index asc); all indices
// compile-time so tv/tix stay in VGPRs (runtime indexing would spill to
// scratch -- this was the 22 GB FETCH_SIZE pathology in round 3).
__device__ __forceinline__ void ins8(float tv[8], int tix[8], float v, int ci)
{
    if (BET(v,ci,tv[7],tix[7])){
        tv[7]=v; tix[7]=ci;
#pragma unroll
        for (int q=7;q>=1;q--){
            if (BET(tv[q],tix[q],tv[q-1],tix[q-1])){
                float t=tv[q]; tv[q]=tv[q-1]; tv[q-1]=t;
                int ti=tix[q]; tix[q]=tix[q-1]; tix[q-1]=ti;
            }
        }
    }
}

// wave-wide merge of 64 sorted per-lane top-8 lists; lane0 writes 8 winners.
// NO runtime indexing: each round the winning lane pops its head via an
// unrolled shift. ci unique per row -> exactly one lane matches the winner.
__device__ __forceinline__ void merge_write8(float tv[8], int tix[8], int lane,
                                             int* __restrict__ dst)
{
#pragma unroll
    for (int r=0;r<8;r++){
        float bv = tv[0]; int bi = tix[0];
#pragma unroll
        for (int off=32; off; off>>=1){
            float ov = __shfl_xor(bv, off); int oi = __shfl_xor(bi, off);
            if (BET(ov,oi,bv,bi)){ bv=ov; bi=oi; }
        }
        if (tv[0]==bv && tix[0]==bi){
#pragma unroll
            for (int q=0;q<7;q++){ tv[q]=tv[q+1]; tix[q]=tix[q+1]; }
            tv[7]=-FLT_MAX; tix[7]=0x7fffffff;
        }
        if (lane==0) dst[r] = bi;
    }
}

// ---------------- transpose x (B,3,N) -> xt (B*N, 3) ----------------
__global__ void transpose_x(const float* __restrict__ x, float* __restrict__ xt)
{
    int g = blockIdx.x*256 + threadIdx.x;
    if (g >= NB*NPTS) return;
    int b = g >> 11, n = g & 2047;
    const float* xb = x + (long)b*3*NPTS;
    xt[g*3+0] = xb[n];
    xt[g*3+1] = xb[NPTS+n];
    xt[g*3+2] = xb[2*NPTS+n];
}

// ---------------- FPS: ONE WAVE per batch, zero barriers in the step loop ----
// Non-contracted ops in XLA's order (square muls, left-fold adds): the 896-step
// sequential argmax chain must match the reference bitwise.
// Emission order matches jax.lax.scan: sel[0]=0 (initial last), sel[i] = argmax
// after folding dist-to-sel[i-1]; ties -> lowest index (argmax first-match).
template<int P>
__device__ void fps_stage_w(const float4* pts, int m, int* sel, int lane)
{
    float cx[P], cy[P], cz[P], dist[P];
#pragma unroll
    for (int r=0;r<P;r++){
        float4 p = pts[r*64 + lane];
        cx[r]=p.x; cy[r]=p.y; cz[r]=p.z; dist[r]=1e10f;
    }
    int last = 0;
    if (lane==0) sel[0]=0;
    for (int i=1;i<m;i++){
        float4 lp = pts[last];
        float bv = -1.f; int bj = 0x7fffffff;
#pragma unroll
        for (int r=0;r<P;r++){
            float dx=__fsub_rn(cx[r],lp.x), dy=__fsub_rn(cy[r],lp.y), dz=__fsub_rn(cz[r],lp.z);
            float d = __fadd_rn(__fadd_rn(__fmul_rn(dx,dx), __fmul_rn(dy,dy)), __fmul_rn(dz,dz));
            d = fminf(dist[r], d); dist[r] = d;
            int j = r*64 + lane;
            if (d > bv){ bv=d; bj=j; }          // ascending j -> lowest idx on tie
        }
#pragma unroll
        for (int off=32; off; off>>=1){
            float ov = __shfl_xor(bv, off); int oj = __shfl_xor(bj, off);
            if (ov > bv || (ov==bv && oj<bj)){ bv=ov; bj=oj; }
        }
        last = bj;                               // all lanes converge to winner
        if (lane==0) sel[i]=last;
    }
}

__global__ __launch_bounds__(64)
void fps_all(const float* __restrict__ x, int* __restrict__ idxF,
             float* __restrict__ coorOut)
{
    __shared__ float4 pts1[2048];
    __shared__ float4 pts2[512];
    __shared__ float4 pts3[256];
    __shared__ int sel1[512], sel2[256], sel3[128];
    int b = blockIdx.x, lane = threadIdx.x;
    const float* xb = x + (long)b*3*NPTS;
    for (int i=lane; i<2048; i+=64)
        pts1[i] = make_float4(xb[i], xb[NPTS+i], xb[2*NPTS+i], 0.f);
    __syncthreads();
    fps_stage_w<32>(pts1, 512, sel1, lane);
    __syncthreads();
    for (int i=lane;i<512;i+=64) pts2[i] = pts1[sel1[i]];
    __syncthreads();
    fps_stage_w<8>(pts2, 256, sel2, lane);
    __syncthreads();
    for (int i=lane;i<256;i+=64) pts3[i] = pts2[sel2[i]];
    __syncthreads();
    fps_stage_w<4>(pts3, 128, sel3, lane);
    __syncthreads();
    for (int i=lane;i<128;i+=64){
        int gi = sel1[sel2[sel3[i]]];
        idxF[b*128+i] = gi;
        float4 p = pts1[gi];
        coorOut[(long)b*384 + 0*128 + i] = p.x;
        coorOut[(long)b*384 + 1*128 + i] = p.y;
        coorOut[(long)b*384 + 2*128 + i] = p.z;
    }
}

// ---------------- block-1 fused kNN on raw coords (C=3) ----------------
__global__ __launch_bounds__(256)
void knn_c3(const float* __restrict__ x, int* __restrict__ idx)
{
    __shared__ float sx[NPTS], sy[NPTS], sz[NPTS];
    int b = blockIdx.x >> 5, rblk = blockIdx.x & 31;
    const float* xb = x + (long)b*3*NPTS;
    int tid = threadIdx.x;
    for (int i=tid;i<NPTS;i+=256){
        sx[i]=xb[i]; sy[i]=xb[NPTS+i]; sz[i]=xb[2*NPTS+i];
    }
    __syncthreads();
    int w = tid>>6, lane = tid&63;
    for (int rr=0; rr<16; rr++){
        int n = rblk*64 + w*16 + rr;
        float px=sx[n], py=sy[n], pz=sz[n];
        float tv[8]; int tix[8];
#pragma unroll
        for (int i=0;i<8;i++){ tv[i]=-FLT_MAX; tix[i]=0x7fffffff; }
        for (int it=0; it<8; it++){
            int c = it*256 + lane*4;
            float4 qx = *(const float4*)&sx[c];
            float4 qy = *(const float4*)&sy[c];
            float4 qz = *(const float4*)&sz[c];
            float dx, dy, dz;
            dx=qx.x-px; dy=qy.x-py; dz=qz.x-pz;
            ins8(tv,tix, -fmaf(dx,dx,fmaf(dy,dy,dz*dz)), c+0);
            dx=qx.y-px; dy=qy.y-py; dz=qz.y-pz;
            ins8(tv,tix, -fmaf(dx,dx,fmaf(dy,dy,dz*dz)), c+1);
            dx=qx.z-px; dy=qy.z-py; dz=qz.z-pz;
            ins8(tv,tix, -fmaf(dx,dx,fmaf(dy,dy,dz*dz)), c+2);
            dx=qx.w-px; dy=qy.w-py; dz=qz.w-pz;
            ins8(tv,tix, -fmaf(dx,dx,fmaf(dy,dy,dz*dz)), c+3);
        }
        merge_write8(tv, tix, lane, idx + ((long)(b*NPTS+n))*KNN);
    }
}

// ---------------- weight prep: wcat = [w1 ; w2-w1 ; rw] ----------------
__global__ void prep_w(const float* __restrict__ w, const float* __restrict__ rw,
                       float* __restrict__ wcat, int O, int C, int hasR)
{
    int t = blockIdx.x*256 + threadIdx.x;
    if (t >= O*C) return;
    int o = t / C, c = t % C;
    float a = w[o*2*C + c];
    wcat[o*C + c] = a;
    wcat[(O+o)*C + c] = w[o*2*C + C + c] - a;
    if (hasR) wcat[(2*O+o)*C + c] = rw[o*C + c];
}

// ---------------- row squared norms ----------------
__global__ void rownorm(const float* __restrict__ X, float* __restrict__ xx,
                        int lda, int C)
{
    int g = blockIdx.x*256 + threadIdx.x;
    if (g >= NB*NPTS) return;
    const float* r = X + (long)g*lda;
    float s = 0.f;
    for (int c=0;c<C;c++) s += r[c]*r[c];
    xx[g] = s;
}

// ---------------- generic GEMM: C[m][n] = sum_k A[m][k]*B[n][k] ----------------
// SYM: A==B square output; compute lower-triangle tiles only, store tile and
// its transpose (values bitwise-symmetric since mul commutes, same sum order).
template<int VEC, bool SYM>
__global__ __launch_bounds__(256)
void gemm_nt(const float* __restrict__ A, const float* __restrict__ B,
             float* __restrict__ C,
             int M, int Nc, int Kd, int lda, int ldb, int ldc,
             long sA, long sB, long sC)
{
    if (SYM && blockIdx.y > blockIdx.x) return;
    int bz = blockIdx.z;
    A += (long)bz * sA; B += (long)bz * sB; C += (long)bz * sC;
    int tm = blockIdx.y * 128, tn = blockIdx.x * 128;
    __shared__ __align__(16) float As[16][132];
    __shared__ __align__(16) float Bs[16][132];
    int tid = threadIdx.x;
    int ty = tid >> 4, tx = tid & 15;
    int cn0 = tx*4, cn1 = 64 + tx*4;
    float acc[8][8] = {};
    for (int k0 = 0; k0 < Kd; k0 += 16){
        if (VEC == 4){
#pragma unroll
            for (int i=0;i<2;i++){
                int e = tid + i*256;
                int rr = e >> 2, kq = e & 3;
                float4 av = *(const float4*)(A + (long)(tm+rr)*lda + k0 + kq*4);
                float4 bv = *(const float4*)(B + (long)(tn+rr)*ldb + k0 + kq*4);
                As[kq*4+0][rr]=av.x; As[kq*4+1][rr]=av.y; As[kq*4+2][rr]=av.z; As[kq*4+3][rr]=av.w;
                Bs[kq*4+0][rr]=bv.x; Bs[kq*4+1][rr]=bv.y; Bs[kq*4+2][rr]=bv.z; Bs[kq*4+3][rr]=bv.w;
            }
        } else {
#pragma unroll
            for (int i=0;i<8;i++){
                int e = tid + i*256;
                int kk = e & 15, rr = e >> 4;
                int ak = k0 + kk;
                As[kk][rr] = (ak < Kd) ? A[(long)(tm+rr)*lda + ak] : 0.f;
                Bs[kk][rr] = (ak < Kd) ? B[(long)(tn+rr)*ldb + ak] : 0.f;
            }
        }
        __syncthreads();
#pragma unroll
        for (int kk=0;kk<16;kk++){
            float4 a01 = *(const float4*)&As[kk][ty*8];
            float4 a23 = *(const float4*)&As[kk][ty*8+4];
            float4 b01 = *(const float4*)&Bs[kk][cn0];
            float4 b23 = *(const float4*)&Bs[kk][cn1];
            float aa[8] = {a01.x,a01.y,a01.z,a01.w,a23.x,a23.y,a23.z,a23.w};
            float bb[8] = {b01.x,b01.y,b01.z,b01.w,b23.x,b23.y,b23.z,b23.w};
#pragma unroll
            for (int i=0;i<8;i++)
#pragma unroll
                for (int j=0;j<8;j++)
                    acc[i][j] += aa[i]*bb[j];
        }
        __syncthreads();
    }
#pragma unroll
    for (int i=0;i<8;i++){
        long r = tm + ty*8 + i;
        float4 v0 = {acc[i][0],acc[i][1],acc[i][2],acc[i][3]};
        float4 v1 = {acc[i][4],acc[i][5],acc[i][6],acc[i][7]};
        *(float4*)(C + r*ldc + tn + cn0) = v0;
        *(float4*)(C + r*ldc + tn + cn1) = v1;
    }
    if (SYM && blockIdx.x != blockIdx.y){
#pragma unroll
        for (int j=0;j<4;j++){
            long r0 = tn + cn0 + j;
            long r1 = tn + cn1 + j;
            float4 u0 = {acc[0][j],  acc[1][j],  acc[2][j],  acc[3][j]};
            float4 u1 = {acc[4][j],  acc[5][j],  acc[6][j],  acc[7][j]};
            float4 u2 = {acc[0][j+4],acc[1][j+4],acc[2][j+4],acc[3][j+4]};
            float4 u3 = {acc[4][j+4],acc[5][j+4],acc[6][j+4],acc[7][j+4]};
            *(float4*)(C + r0*ldc + tm + ty*8)     = u0;
            *(float4*)(C + r0*ldc + tm + ty*8 + 4) = u1;
            *(float4*)(C + r1*ldc + tm + ty*8)     = u2;
            *(float4*)(C + r1*ldc + tm + ty*8 + 4) = u3;
        }
    }
}

// ---------------- top-8 per row of D (value = 2*dot - xx[m]) ----------------
__global__ __launch_bounds__(256)
void topk8(const float* __restrict__ D, const float* __restrict__ xx,
           int* __restrict__ idx, int b0)
{
    int tid = threadIdx.x, w = tid>>6, lane = tid & 63;
    int gr = blockIdx.x*4 + w;               // row within 2-batch chunk
    int b = b0 + (gr >> 11);
    const float* drow = D + (long)gr*NPTS;
    const float* xb = xx + (long)b*NPTS;
    float tv[8]; int tix[8];
#pragma unroll
    for (int i=0;i<8;i++){ tv[i]=-FLT_MAX; tix[i]=0x7fffffff; }
    for (int it=0; it<8; it++){
        int c = it*256 + lane*4;
        float4 d4 = *(const float4*)(drow + c);
        float4 x4 = *(const float4*)(xb + c);
        ins8(tv,tix, 2.f*d4.x - x4.x, c+0);
        ins8(tv,tix, 2.f*d4.y - x4.y, c+1);
        ins8(tv,tix, 2.f*d4.z - x4.z, c+2);
        ins8(tv,tix, 2.f*d4.w - x4.w, c+3);
    }
    merge_write8(tv, tix, lane, idx + ((long)(b0*NPTS) + gr)*KNN);
}

// ------- edge bn stats + max/min: one gather pass produces everything -------
__global__ __launch_bounds__(256)
void stats_edge(const float* __restrict__ uvr, const int* __restrict__ idx,
                float* __restrict__ ps, float* __restrict__ pq,
                float* __restrict__ mxb, float* __restrict__ mnb,
                int O, int ld)
{
    int tid = threadIdx.x;
    int r0 = blockIdx.x * 128;
    float s0=0,q0=0,s1=0,q1=0;
    for (int rr=0; rr<128; rr++){
        int g = r0 + rr;
        int b = g >> 11;
        const int* ip = idx + (long)g*KNN;
        const float* vrow = uvr + (long)g*ld + O;
        const float* ub[8];
#pragma unroll
        for (int k=0;k<8;k++) ub[k] = uvr + (long)((b<<11) + ip[k])*ld;
        int o = tid;
        if (o < O){
            float vv = vrow[o];
            float mx=-FLT_MAX, mn=FLT_MAX;
#pragma unroll
            for (int k=0;k<8;k++){
                float f = ub[k][o]+vv;
                s0+=f; q0+=f*f; mx=fmaxf(mx,f); mn=fminf(mn,f);
            }
            mxb[(long)g*O+o]=mx; mnb[(long)g*O+o]=mn;
        }
        o = tid + 256;
        if (o < O){
            float vv = vrow[o];
            float mx=-FLT_MAX, mn=FLT_MAX;
#pragma unroll
            for (int k=0;k<8;k++){
                float f = ub[k][o]+vv;
                s1+=f; q1+=f*f; mx=fmaxf(mx,f); mn=fminf(mn,f);
            }
            mxb[(long)g*O+o]=mx; mnb[(long)g*O+o]=mn;
        }
    }
    if (tid < O){ ps[blockIdx.x*2048 + tid] = s0; pq[blockIdx.x*2048 + tid] = q0; }
    if (tid+256 < O){ ps[blockIdx.x*2048 + tid+256] = s1; pq[blockIdx.x*2048 + tid+256] = q1; }
}

// ---------------- stats -> affine (a, c) ----------------
__global__ void reduce_stats(const float* __restrict__ ps, const float* __restrict__ pq,
                             const float* __restrict__ gam, const float* __restrict__ bet,
                             float* __restrict__ ab, float* __restrict__ cb,
                             int O, int np, float invCnt)
{
    int o = blockIdx.x*256 + threadIdx.x;
    if (o >= O) return;
    float s=0.f, q=0.f;
    for (int p=0;p<np;p++){ s += ps[p*2048 + o]; q += pq[p*2048 + o]; }
    float m = s * invCnt;
    float var = q * invCnt - m*m;
    float a = gam[o] * rsqrtf(var + 1e-5f);
    ab[o] = a;
    cb[o] = bet[o] - m*a;
}

// -------- edge finalize: pure streaming (max/min precomputed in stats) ------
__global__ void finalize_edge(const float* __restrict__ mxb, const float* __restrict__ mnb,
                              const float* __restrict__ uvr,
                              const float* __restrict__ ab, const float* __restrict__ cb,
                              float* __restrict__ hcat, int lgO, int ld, int hoff, int hasR)
{
    long t = (long)blockIdx.x*256 + threadIdx.x;
    int O = 1 << lgO;
    int o = (int)(t & (O-1));
    int g = (int)(t >> lgO);
    float a = ab[o], c = cb[o];
    float mx = mxb[t], mn = mnb[t];
    float zz = (a > 0.f) ? (a*mx + c) : (a*mn + c);
    float outv = leakyf(zz);
    if (hasR) outv += uvr[(long)g*ld + 2*O + o];
    hcat[(long)g*1024 + hoff + o] = outv;
}

// ---------------- column sums of hcat -> partials -> hbar ----------------
__global__ void colsum_part(const float* __restrict__ H, float* __restrict__ part)
{
    int pb = blockIdx.x;                      // 128 blocks x 128 rows
    int tid = threadIdx.x;
    const float4* h4 = (const float4*)(H + (long)pb*128*1024);
    float4 acc = {0,0,0,0};
    for (int r=0;r<128;r++){
        float4 v = h4[r*256 + tid];
        acc.x+=v.x; acc.y+=v.y; acc.z+=v.z; acc.w+=v.w;
    }
    ((float4*)part)[pb*256 + tid] = acc;
}
__global__ void colsum_fin(const float* __restrict__ part, float* __restrict__ hbar)
{
    int tid = threadIdx.x;
    float4 acc = {0,0,0,0};
    for (int p=0;p<128;p++){
        float4 v = ((const float4*)part)[p*256 + tid];
        acc.x+=v.x; acc.y+=v.y; acc.z+=v.z; acc.w+=v.w;
    }
    ((float4*)hbar)[tid] = acc;
}

// ---------------- Gram partials: P[p] += Hchunk^T * Hchunk (lower tiles) ----------------
__global__ __launch_bounds__(256)
void gram_tn(const float* __restrict__ A, float* __restrict__ P)
{
    if (blockIdx.y < blockIdx.x) return;      // compute ti>=tj (lower+diag)
    int ti = blockIdx.y*128, tj = blockIdx.x*128;
    int bz = blockIdx.z;                      // 16 chunks of 1024 rows
    __shared__ __align__(16) float As[32][132];
    __shared__ __align__(16) float Bs[32][132];
    int tid = threadIdx.x;
    int ty = tid>>4, tx = tid&15;
    float acc[8][8] = {};
    const float* Abase = A + (long)bz*1024*1024;
    for (int k0=0; k0<1024; k0+=32){
#pragma unroll
        for (int i=0;i<4;i++){
            int e = tid + i*256;
            int mm = e>>5, c4 = (e&31)*4;
            const float* arow = Abase + (long)(k0+mm)*1024;
            *(float4*)&As[mm][c4] = *(const float4*)(arow + ti + c4);
            *(float4*)&Bs[mm][c4] = *(const float4*)(arow + tj + c4);
        }
        __syncthreads();
#pragma unroll
        for (int mm=0;mm<32;mm++){
            float4 a01 = *(const float4*)&As[mm][ty*8];
            float4 a23 = *(const float4*)&As[mm][ty*8+4];
            float4 b01 = *(const float4*)&Bs[mm][tx*4];
            float4 b23 = *(const float4*)&Bs[mm][64+tx*4];
            float aa[8] = {a01.x,a01.y,a01.z,a01.w,a23.x,a23.y,a23.z,a23.w};
            float bb[8] = {b01.x,b01.y,b01.z,b01.w,b23.x,b23.y,b23.z,b23.w};
#pragma unroll
            for (int i=0;i<8;i++)
#pragma unroll
                for (int j=0;j<8;j++)
                    acc[i][j] += aa[i]*bb[j];
        }
        __syncthreads();
    }
    float* Pp = P + ((long)bz<<20);
#pragma unroll
    for (int i=0;i<8;i++){
        long r = ti + ty*8 + i;
        float4 v0 = {acc[i][0],acc[i][1],acc[i][2],acc[i][3]};
        float4 v1 = {acc[i][4],acc[i][5],acc[i][6],acc[i][7]};
        *(float4*)(Pp + r*1024 + tj + tx*4)      = v0;
        *(float4*)(Pp + r*1024 + tj + 64 + tx*4) = v1;
    }
}

__global__ void greduce(const float* __restrict__ P, float* __restrict__ G)
{
    long i4 = (long)blockIdx.x*256 + threadIdx.x;   // over 1<<18 float4
    float4 a = ((const float4*)P)[i4];
    for (int p=1;p<16;p++){
        float4 v = ((const float4*)P)[((long)p<<18) + i4];
        a.x+=v.x; a.y+=v.y; a.z+=v.z; a.w+=v.w;
    }
    ((float4*)G)[i4] = a;
}

// fill strictly-upper 64x64 tiles of G from lower triangle
__global__ void mirror_g(float* __restrict__ G)
{
    __shared__ float t[64][65];
    int q = blockIdx.x, I = 0, acc = 15;
    while (q >= acc){ q -= acc; acc--; I++; }
    int J = I + 1 + q;                         // J > I, 16 tiles of 64
    int tid = threadIdx.x;
#pragma unroll
    for (int k=0;k<16;k++){
        int e = tid + k*256;
        int sr = e>>6, sc = e&63;
        t[sr][sc] = G[(long)(J*64+sr)*1024 + I*64+sc];
    }
    __syncthreads();
#pragma unroll
    for (int k=0;k<16;k++){
        int e = tid + k*256;
        int dr = e>>6, dc = e&63;
        G[(long)(I*64+dr)*1024 + J*64+dc] = t[dc][dr];
    }
}

// ---------------- bn1d affine from Gram: m=w5.hbar/N, q=w5.T(row)/N ----------------
__global__ void bn5_prep(const float* __restrict__ w5, const float* __restrict__ T,
                         const float* __restrict__ hbar,
                         const float* __restrict__ g5, const float* __restrict__ b5,
                         float* __restrict__ ab, float* __restrict__ cb)
{
    int w = threadIdx.x>>6, lane = threadIdx.x&63;
    int n = blockIdx.x*4 + w;
    const float4* wr = (const float4*)(w5 + (long)n*1024);
    const float4* tr = (const float4*)(T  + (long)n*1024);
    const float4* hb = (const float4*)hbar;
    float s1=0.f, s2=0.f;
    for (int i=lane;i<256;i+=64){
        float4 wv = wr[i], t4 = tr[i], hv = hb[i];
        s1 += wv.x*hv.x + wv.y*hv.y + wv.z*hv.z + wv.w*hv.w;
        s2 += wv.x*t4.x + wv.y*t4.y + wv.z*t4.z + wv.w*t4.w;
    }
#pragma unroll
    for (int off=32; off; off>>=1){
        s1 += __shfl_xor(s1, off);
        s2 += __shfl_xor(s2, off);
    }
    if (lane==0){
        float m = s1*(1.f/16384.f);
        float qq = s2*(1.f/16384.f);
        float var = qq - m*m;
        float a = g5[n]*rsqrtf(var+1e-5f);
        ab[n]=a; cb[n]=b5[n]-m*a;
    }
}

// ---------------- gather selected hcat rows ----------------
__global__ void gather_rows(const float* __restrict__ src, const int* __restrict__ idxF,
                            float* __restrict__ dst)
{
    int r = blockIdx.x;                    // 0..1023  (b*128+i)
    int b = r >> 7;
    int srow = (b<<11) + idxF[r];
    const float4* s = (const float4*)(src + (long)srow*1024);
    float4* d = (float4*)(dst + (long)r*1024);
    for (int c=threadIdx.x; c<256; c+=256) d[c] = s[c];
}

// ---------------- final f: bn + leaky + max/mean over 128 points ----------------
__global__ void finalize_f(const float* __restrict__ zsel, const float* __restrict__ ab,
                           const float* __restrict__ cb, float* __restrict__ out)
{
    int b = blockIdx.x >> 3, oc = blockIdx.x & 7;
    int o = oc*256 + threadIdx.x;
    float a = ab[o], c = cb[o];
    float mx = -FLT_MAX, sm = 0.f;
    const float* zp = zsel + (long)b*128*2048 + o;
    for (int i=0;i<128;i++){
        float v = leakyf(a*zp[(long)i*2048] + c);
        mx = fmaxf(mx, v); sm += v;
    }
    out[b*4096 + o] = mx;
    out[b*4096 + 2048 + o] = sm * (1.f/128.f);
}

extern "C" void kernel_launch(void* const* d_in, const int* in_sizes, int n_in,
                              void* d_out, int out_size, void* d_ws, size_t ws_size,
                              hipStream_t stream)
{
    (void)in_sizes; (void)n_in; (void)out_size; (void)ws_size;
    const float* x   = (const float*)d_in[0];
    const float* w1  = (const float*)d_in[1];
    const float* w2  = (const float*)d_in[2];
    const float* w3  = (const float*)d_in[3];
    const float* w4  = (const float*)d_in[4];
    const float* w5  = (const float*)d_in[5];
    const float* rw1 = (const float*)d_in[6];
    const float* rw2 = (const float*)d_in[7];
    const float* rw3 = (const float*)d_in[8];
    const float* g1  = (const float*)d_in[9];  const float* b1 = (const float*)d_in[10];
    const float* g2  = (const float*)d_in[11]; const float* b2 = (const float*)d_in[12];
    const float* g3  = (const float*)d_in[13]; const float* b3 = (const float*)d_in[14];
    const float* g4  = (const float*)d_in[15]; const float* b4 = (const float*)d_in[16];
    const float* g5  = (const float*)d_in[17]; const float* b5 = (const float*)d_in[18];
    float* out = (float*)d_out;

    char* wsb = (char*)d_ws;
    size_t off = 0;
    auto alloc = [&](size_t bytes)->char* {
        char* p = wsb + off;
        off += (bytes + 255) & ~(size_t)255;
        return p;
    };
    float* xt    = (float*)alloc((size_t)16384*3*4);
    float* hcat  = (float*)alloc((size_t)16384*1024*4);
    float* uvr   = (float*)alloc((size_t)16384*1536*4);   // aliased: Dbuf, gram P
    float* Dbuf  = uvr;
    float* gramP = uvr;                                   // 16 x 1M floats = 64MB
    float* G     = (float*)alloc((size_t)1024*1024*4);
    float* T     = (float*)alloc((size_t)2048*1024*4);
    float* zselA = (float*)alloc((size_t)1024*1024*4);
    float* zsel  = (float*)alloc((size_t)1024*2048*4);
    float* mxb   = (float*)alloc((size_t)16384*512*4);
    float* mnb   = (float*)alloc((size_t)16384*512*4);
    float* xx    = (float*)alloc((size_t)16384*4);
    int*   idx   = (int*)  alloc((size_t)16384*8*4);
    float* wcat  = (float*)alloc((size_t)1536*256*4);
    float* ps    = (float*)alloc((size_t)128*2048*4);
    float* pq    = (float*)alloc((size_t)128*2048*4);
    float* cspart= (float*)alloc((size_t)128*1024*4);
    float* hbar  = (float*)alloc((size_t)1024*4);
    float* ab    = (float*)alloc((size_t)2048*4);
    float* cb    = (float*)alloc((size_t)2048*4);
    int*   idxF  = (int*)  alloc((size_t)1024*4);

    transpose_x<<<64, 256, 0, stream>>>(x, xt);
    fps_all<<<8, 64, 0, stream>>>(x, idxF, out);    // writes coor part of d_out

    struct EB {
        const float* X; int lda, C, O, lgO, hoff, hasR;
        const float* w; const float* rw; const float* g; const float* bb;
    };
    EB eb[4] = {
        { xt,        3,    3,   128, 7, 0,   0, w1, nullptr, g1, b1 },
        { hcat+0,    1024, 128, 128, 7, 128, 1, w2, rw1,     g2, b2 },
        { hcat+128,  1024, 128, 256, 8, 256, 1, w3, rw2,     g3, b3 },
        { hcat+256,  1024, 256, 512, 9, 512, 1, w4, rw3,     g4, b4 },
    };
    for (int i=0;i<4;i++){
        EB e = eb[i];
        int ld = (2 + e.hasR) * e.O;
        int tot = e.O * e.C;
        prep_w<<<(tot+255)/256, 256, 0, stream>>>(e.w, e.rw, wcat, e.O, e.C, e.hasR);
        if (i == 0){
            knn_c3<<<256, 256, 0, stream>>>(x, idx);
            gemm_nt<1,false><<<dim3(ld/128, 128, 1), 256, 0, stream>>>(
                e.X, wcat, uvr, 16384, ld, e.C, e.lda, e.C, ld, 0, 0, 0);
        } else {
            rownorm<<<64, 256, 0, stream>>>(e.X, xx, e.lda, e.C);
            for (int b0=0; b0<8; b0+=2){
                const float* Ab = e.X + (long)b0*NPTS*e.lda;
                gemm_nt<4,true><<<dim3(16,16,2), 256, 0, stream>>>(
                    Ab, Ab, Dbuf, 2048, 2048, e.C, e.lda, e.lda, 2048,
                    (long)NPTS*e.lda, (long)NPTS*e.lda, (long)NPTS*NPTS);
                topk8<<<1024, 256, 0, stream>>>(Dbuf, xx, idx, b0);
            }
            gemm_nt<4,false><<<dim3(ld/128, 128, 1), 256, 0, stream>>>(
                e.X, wcat, uvr, 16384, ld, e.C, e.lda, e.C, ld, 0, 0, 0);
        }
        stats_edge<<<128, 256, 0, stream>>>(uvr, idx, ps, pq, mxb, mnb, e.O, ld);
        reduce_stats<<<(e.O+255)/256, 256, 0, stream>>>(ps, pq, e.g, e.bb, ab, cb,
                                                        e.O, 128, 1.f/131072.f);
        finalize_edge<<<64*e.O, 256, 0, stream>>>(mxb, mnb, uvr, ab, cb, hcat,
                                                  e.lgO, ld, e.hoff, e.hasR);
    }

    // ----- block 5 via Gram: stats without materializing z -----
    colsum_part<<<128, 256, 0, stream>>>(hcat, cspart);
    colsum_fin<<<1, 256, 0, stream>>>(cspart, hbar);
    gram_tn<<<dim3(8,8,16), 256, 0, stream>>>(hcat, gramP);
    greduce<<<1024, 256, 0, stream>>>(gramP, G);
    mirror_g<<<120, 256, 0, stream>>>(G);
    gemm_nt<4,false><<<dim3(8,16,1), 256, 0, stream>>>(
        w5, G, T, 2048, 1024, 1024, 1024, 1024, 1024, 0, 0, 0);
    bn5_prep<<<512, 256, 0, stream>>>(w5, T, hbar, g5, b5, ab, cb);
    gather_rows<<<1024, 256, 0, stream>>>(hcat, idxF, zselA);
    gemm_nt<4,false><<<dim3(16,8,1), 256, 0, stream>>>(
        zselA, w5, zsel, 1024, 2048, 1024, 1024, 1024, 2048, 0, 0, 0);
    finalize_f<<<64, 256, 0, stream>>>(zsel, ab, cb, out + 3072);
}

// Round 6
// 3959.420 us; speedup vs baseline: 1.1379x; 1.0893x over previous
//
#include <hip/hip_runtime.h>
#include <float.h>

#define NPTS 2048
#define NB 8
#define KNN 8

__device__ __forceinline__ float leakyf(float x){ return x > 0.f ? x : 0.2f*x; }

#define BET(v1,i1,v2,i2) (((v1)>(v2)) || ((v1)==(v2) && (i1)<(i2)))

// sorted-insert into per-lane top-8 (value desc, index asc); compile-time
// indices only (runtime indexing spills to scratch -- round-3 22GB pathology).
__device__ __forceinline__ void ins8(float tv[8], int tix[8], float v, int ci)
{
    if (BET(v,ci,tv[7],tix[7])){
        tv[7]=v; tix[7]=ci;
#pragma unroll
        for (int q=7;q>=1;q--){
            if (BET(tv[q],tix[q],tv[q-1],tix[q-1])){
                float t=tv[q]; tv[q]=tv[q-1]; tv[q-1]=t;
                int ti=tix[q]; tix[q]=tix[q-1]; tix[q-1]=ti;
            }
        }
    }
}

// wave-wide merge of 64 sorted per-lane top-8 lists; lane0 writes 8 winners.
__device__ __forceinline__ void merge_write8(float tv[8], int tix[8], int lane,
                                             int* __restrict__ dst)
{
#pragma unroll
    for (int r=0;r<8;r++){
        float bv = tv[0]; int bi = tix[0];
#pragma unroll
        for (int off=32; off; off>>=1){
            float ov = __shfl_xor(bv, off); int oi = __shfl_xor(bi, off);
            if (BET(ov,oi,bv,bi)){ bv=ov; bi=oi; }
        }
        if (tv[0]==bv && tix[0]==bi){
#pragma unroll
            for (int q=0;q<7;q++){ tv[q]=tv[q+1]; tix[q]=tix[q+1]; }
            tv[7]=-FLT_MAX; tix[7]=0x7fffffff;
        }
        if (lane==0) dst[r] = bi;
    }
}

// ---------------- transpose x (B,3,N) -> xt (B*N, 3) ----------------
__global__ void transpose_x(const float* __restrict__ x, float* __restrict__ xt)
{
    int g = blockIdx.x*256 + threadIdx.x;
    if (g >= NB*NPTS) return;
    int b = g >> 11, n = g & 2047;
    const float* xb = x + (long)b*3*NPTS;
    xt[g*3+0] = xb[n];
    xt[g*3+1] = xb[NPTS+n];
    xt[g*3+2] = xb[2*NPTS+n];
}

// =================== FPS via DPP argmax (exact) ===================
// Packing (dist_bits<<32)|(2047-j) is exact: dist>=0 so float bits are
// monotonic as u32; u64 max == argmax with tie -> LOWEST j (XLA argmax).
// DPP steps (~4cy) replace ds_swizzle shuffles (~120cy) -- round-5 counters
// showed fps 89% stalled on the shuffle chain.
__device__ __forceinline__ unsigned long long u64max(unsigned long long a,
                                                     unsigned long long b)
{ return a > b ? a : b; }

template<int CTRL>
__device__ __forceinline__ unsigned long long dpp_max_step(unsigned long long v)
{
    unsigned plo = (unsigned)__builtin_amdgcn_update_dpp(0, (int)(unsigned)v,      CTRL, 0xF, 0xF, true);
    unsigned phi = (unsigned)__builtin_amdgcn_update_dpp(0, (int)(unsigned)(v>>32), CTRL, 0xF, 0xF, true);
    unsigned long long p = ((unsigned long long)phi << 32) | plo;
    return u64max(v, p);   // bound_ctrl 0-fill never wins: real candidates > 0
}

__device__ __forceinline__ int wave_argmax_finish(unsigned long long best)
{
    best = dpp_max_step<0x111>(best);   // row_shr:1
    best = dpp_max_step<0x112>(best);   // row_shr:2
    best = dpp_max_step<0x114>(best);   // row_shr:4
    best = dpp_max_step<0x118>(best);   // row_shr:8  -> lane15/31/47/63 row max
    best = dpp_max_step<0x142>(best);   // row_bcast:15 -> lane31/63 half max
    best = dpp_max_step<0x143>(best);   // row_bcast:31 -> lane63 global max
    unsigned lo = (unsigned)__builtin_amdgcn_readlane((int)(unsigned)best, 63);
    return 2047 - (int)lo;              // SGPR-uniform winner index
}

// Distance arithmetic: non-contracted ops in XLA's order (square muls,
// left-fold adds) -- the 896-step sequential chain must match bitwise.
// COORD_LDS: re-read coords from LDS each iter (reg-lean, stage 1 P=32);
// else coords live in registers (stages 2/3).
template<int P, bool COORD_LDS>
__device__ void fps_stage_w(const float4* __restrict__ pts, int m, int* sel, int lane)
{
    float cx[P], cy[P], cz[P], dist[P];
#pragma unroll
    for (int r=0;r<P;r++){
        if (!COORD_LDS){
            float4 p = pts[r*64 + lane];
            cx[r]=p.x; cy[r]=p.y; cz[r]=p.z;
        }
        dist[r]=1e10f;
    }
    int base = 2047 - lane;
    int last = 0;
    if (lane==0) sel[0]=0;
    for (int i=1;i<m;i++){
        float4 lp = pts[last];
        unsigned long long t[P/2];
#pragma unroll
        for (int k=0;k<P/2;k++){
#pragma unroll
            for (int h=0;h<2;h++){
                int r = 2*k+h;
                float qx, qy, qz;
                if (COORD_LDS){ float4 q = pts[r*64 + lane]; qx=q.x; qy=q.y; qz=q.z; }
                else          { qx=cx[r]; qy=cy[r]; qz=cz[r]; }
                float dx=__fsub_rn(qx,lp.x), dy=__fsub_rn(qy,lp.y), dz=__fsub_rn(qz,lp.z);
                float d = __fadd_rn(__fadd_rn(__fmul_rn(dx,dx), __fmul_rn(dy,dy)), __fmul_rn(dz,dz));
                dist[r] = fminf(dist[r], d);
            }
            unsigned long long a = ((unsigned long long)__float_as_uint(dist[2*k  ])<<32) | (unsigned)(base - 64*(2*k  ));
            unsigned long long b = ((unsigned long long)__float_as_uint(dist[2*k+1])<<32) | (unsigned)(base - 64*(2*k+1));
            t[k] = u64max(a, b);
        }
#pragma unroll
        for (int s=P/4; s>=1; s>>=1)
#pragma unroll
            for (int k=0;k<s;k++) t[k] = u64max(t[k], t[k+s]);
        int win = wave_argmax_finish(t[0]);
        last = win;
        if (lane==0) sel[i] = win;
    }
}

// ---------------- block-1 fused kNN on raw coords (C=3) ----------------
__global__ __launch_bounds__(256)
void knn_c3(const float* __restrict__ x, int* __restrict__ idx)
{
    __shared__ float sx[NPTS], sy[NPTS], sz[NPTS];
    int b = blockIdx.x >> 5, rblk = blockIdx.x & 31;
    const float* xb = x + (long)b*3*NPTS;
    int tid = threadIdx.x;
    for (int i=tid;i<NPTS;i+=256){
        sx[i]=xb[i]; sy[i]=xb[NPTS+i]; sz[i]=xb[2*NPTS+i];
    }
    __syncthreads();
    int w = tid>>6, lane = tid&63;
    for (int rr=0; rr<16; rr++){
        int n = rblk*64 + w*16 + rr;
        float px=sx[n], py=sy[n], pz=sz[n];
        float tv[8]; int tix[8];
#pragma unroll
        for (int i=0;i<8;i++){ tv[i]=-FLT_MAX; tix[i]=0x7fffffff; }
        for (int it=0; it<8; it++){
            int c = it*256 + lane*4;
            float4 qx = *(const float4*)&sx[c];
            float4 qy = *(const float4*)&sy[c];
            float4 qz = *(const float4*)&sz[c];
            float dx, dy, dz;
            dx=qx.x-px; dy=qy.x-py; dz=qz.x-pz;
            ins8(tv,tix, -fmaf(dx,dx,fmaf(dy,dy,dz*dz)), c+0);
            dx=qx.y-px; dy=qy.y-py; dz=qz.y-pz;
            ins8(tv,tix, -fmaf(dx,dx,fmaf(dy,dy,dz*dz)), c+1);
            dx=qx.z-px; dy=qy.z-py; dz=qz.z-pz;
            ins8(tv,tix, -fmaf(dx,dx,fmaf(dy,dy,dz*dz)), c+2);
            dx=qx.w-px; dy=qy.w-py; dz=qz.w-pz;
            ins8(tv,tix, -fmaf(dx,dx,fmaf(dy,dy,dz*dz)), c+3);
        }
        merge_write8(tv, tix, lane, idx + ((long)(b*NPTS+n))*KNN);
    }
}

// ---------------- weight prep: wcat = [w1 ; w2-w1 ; rw] ----------------
__global__ void prep_w(const float* __restrict__ w, const float* __restrict__ rw,
                       float* __restrict__ wcat, int O, int C, int hasR)
{
    int t = blockIdx.x*256 + threadIdx.x;
    if (t >= O*C) return;
    int o = t / C, c = t % C;
    float a = w[o*2*C + c];
    wcat[o*C + c] = a;
    wcat[(O+o)*C + c] = w[o*2*C + C + c] - a;
    if (hasR) wcat[(2*O+o)*C + c] = rw[o*C + c];
}

// ---------------- row squared norms ----------------
__global__ void rownorm(const float* __restrict__ X, float* __restrict__ xx,
                        int lda, int C)
{
    int g = blockIdx.x*256 + threadIdx.x;
    if (g >= NB*NPTS) return;
    const float* r = X + (long)g*lda;
    float s = 0.f;
    for (int c=0;c<C;c++) s += r[c]*r[c];
    xx[g] = s;
}

// ---------------- generic GEMM: C[m][n] = sum_k A[m][k]*B[n][k] ----------------
template<int VEC, bool SYM>
__global__ __launch_bounds__(256)
void gemm_nt(const float* __restrict__ A, const float* __restrict__ B,
             float* __restrict__ C,
             int M, int Nc, int Kd, int lda, int ldb, int ldc,
             long sA, long sB, long sC)
{
    if (SYM && blockIdx.y > blockIdx.x) return;
    int bz = blockIdx.z;
    A += (long)bz * sA; B += (long)bz * sB; C += (long)bz * sC;
    int tm = blockIdx.y * 128, tn = blockIdx.x * 128;
    __shared__ __align__(16) float As[16][132];
    __shared__ __align__(16) float Bs[16][132];
    int tid = threadIdx.x;
    int ty = tid >> 4, tx = tid & 15;
    int cn0 = tx*4, cn1 = 64 + tx*4;
    float acc[8][8] = {};
    for (int k0 = 0; k0 < Kd; k0 += 16){
        if (VEC == 4){
#pragma unroll
            for (int i=0;i<2;i++){
                int e = tid + i*256;
                int rr = e >> 2, kq = e & 3;
                float4 av = *(const float4*)(A + (long)(tm+rr)*lda + k0 + kq*4);
                float4 bv = *(const float4*)(B + (long)(tn+rr)*ldb + k0 + kq*4);
                As[kq*4+0][rr]=av.x; As[kq*4+1][rr]=av.y; As[kq*4+2][rr]=av.z; As[kq*4+3][rr]=av.w;
                Bs[kq*4+0][rr]=bv.x; Bs[kq*4+1][rr]=bv.y; Bs[kq*4+2][rr]=bv.z; Bs[kq*4+3][rr]=bv.w;
            }
        } else {
#pragma unroll
            for (int i=0;i<8;i++){
                int e = tid + i*256;
                int kk = e & 15, rr = e >> 4;
                int ak = k0 + kk;
                As[kk][rr] = (ak < Kd) ? A[(long)(tm+rr)*lda + ak] : 0.f;
                Bs[kk][rr] = (ak < Kd) ? B[(long)(tn+rr)*ldb + ak] : 0.f;
            }
        }
        __syncthreads();
#pragma unroll
        for (int kk=0;kk<16;kk++){
            float4 a01 = *(const float4*)&As[kk][ty*8];
            float4 a23 = *(const float4*)&As[kk][ty*8+4];
            float4 b01 = *(const float4*)&Bs[kk][cn0];
            float4 b23 = *(const float4*)&Bs[kk][cn1];
            float aa[8] = {a01.x,a01.y,a01.z,a01.w,a23.x,a23.y,a23.z,a23.w};
            float bb[8] = {b01.x,b01.y,b01.z,b01.w,b23.x,b23.y,b23.z,b23.w};
#pragma unroll
            for (int i=0;i<8;i++)
#pragma unroll
                for (int j=0;j<8;j++)
                    acc[i][j] += aa[i]*bb[j];
        }
        __syncthreads();
    }
#pragma unroll
    for (int i=0;i<8;i++){
        long r = tm + ty*8 + i;
        float4 v0 = {acc[i][0],acc[i][1],acc[i][2],acc[i][3]};
        float4 v1 = {acc[i][4],acc[i][5],acc[i][6],acc[i][7]};
        *(float4*)(C + r*ldc + tn + cn0) = v0;
        *(float4*)(C + r*ldc + tn + cn1) = v1;
    }
    if (SYM && blockIdx.x != blockIdx.y){
#pragma unroll
        for (int j=0;j<4;j++){
            long r0 = tn + cn0 + j;
            long r1 = tn + cn1 + j;
            float4 u0 = {acc[0][j],  acc[1][j],  acc[2][j],  acc[3][j]};
            float4 u1 = {acc[4][j],  acc[5][j],  acc[6][j],  acc[7][j]};
            float4 u2 = {acc[0][j+4],acc[1][j+4],acc[2][j+4],acc[3][j+4]};
            float4 u3 = {acc[4][j+4],acc[5][j+4],acc[6][j+4],acc[7][j+4]};
            *(float4*)(C + r0*ldc + tm + ty*8)     = u0;
            *(float4*)(C + r0*ldc + tm + ty*8 + 4) = u1;
            *(float4*)(C + r1*ldc + tm + ty*8)     = u2;
            *(float4*)(C + r1*ldc + tm + ty*8 + 4) = u3;
        }
    }
}

// ---------------- top-8 per row of D (value = 2*dot - xx[m]) ----------------
__global__ __launch_bounds__(256)
void topk8(const float* __restrict__ D, const float* __restrict__ xx,
           int* __restrict__ idx, int b0)
{
    int tid = threadIdx.x, w = tid>>6, lane = tid & 63;
    int gr = blockIdx.x*4 + w;
    int b = b0 + (gr >> 11);
    const float* drow = D + (long)gr*NPTS;
    const float* xb = xx + (long)b*NPTS;
    float tv[8]; int tix[8];
#pragma unroll
    for (int i=0;i<8;i++){ tv[i]=-FLT_MAX; tix[i]=0x7fffffff; }
    for (int it=0; it<8; it++){
        int c = it*256 + lane*4;
        float4 d4 = *(const float4*)(drow + c);
        float4 x4 = *(const float4*)(xb + c);
        ins8(tv,tix, 2.f*d4.x - x4.x, c+0);
        ins8(tv,tix, 2.f*d4.y - x4.y, c+1);
        ins8(tv,tix, 2.f*d4.z - x4.z, c+2);
        ins8(tv,tix, 2.f*d4.w - x4.w, c+3);
    }
    merge_write8(tv, tix, lane, idx + ((long)(b0*NPTS) + gr)*KNN);
}

// ------- edge bn stats + max/min: one gather pass produces everything -------
__global__ __launch_bounds__(256)
void stats_edge(const float* __restrict__ uvr, const int* __restrict__ idx,
                float* __restrict__ ps, float* __restrict__ pq,
                float* __restrict__ mxb, float* __restrict__ mnb,
                int O, int ld)
{
    int tid = threadIdx.x;
    int r0 = blockIdx.x * 128;
    float s0=0,q0=0,s1=0,q1=0;
    for (int rr=0; rr<128; rr++){
        int g = r0 + rr;
        int b = g >> 11;
        const int* ip = idx + (long)g*KNN;
        const float* vrow = uvr + (long)g*ld + O;
        const float* ub[8];
#pragma unroll
        for (int k=0;k<8;k++) ub[k] = uvr + (long)((b<<11) + ip[k])*ld;
        int o = tid;
        if (o < O){
            float vv = vrow[o];
            float mx=-FLT_MAX, mn=FLT_MAX;
#pragma unroll
            for (int k=0;k<8;k++){
                float f = ub[k][o]+vv;
                s0+=f; q0+=f*f; mx=fmaxf(mx,f); mn=fminf(mn,f);
            }
            mxb[(long)g*O+o]=mx; mnb[(long)g*O+o]=mn;
        }
        o = tid + 256;
        if (o < O){
            float vv = vrow[o];
            float mx=-FLT_MAX, mn=FLT_MAX;
#pragma unroll
            for (int k=0;k<8;k++){
                float f = ub[k][o]+vv;
                s1+=f; q1+=f*f; mx=fmaxf(mx,f); mn=fminf(mn,f);
            }
            mxb[(long)g*O+o]=mx; mnb[(long)g*O+o]=mn;
        }
    }
    if (tid < O){ ps[blockIdx.x*2048 + tid] = s0; pq[blockIdx.x*2048 + tid] = q0; }
    if (tid+256 < O){ ps[blockIdx.x*2048 + tid+256] = s1; pq[blockIdx.x*2048 + tid+256] = q1; }
}

// ---------------- stats -> affine (a, c) ----------------
__global__ void reduce_stats(const float* __restrict__ ps, const float* __restrict__ pq,
                             const float* __restrict__ gam, const float* __restrict__ bet,
                             float* __restrict__ ab, float* __restrict__ cb,
                             int O, int np, float invCnt)
{
    int o = blockIdx.x*256 + threadIdx.x;
    if (o >= O) return;
    float s=0.f, q=0.f;
    for (int p=0;p<np;p++){ s += ps[p*2048 + o]; q += pq[p*2048 + o]; }
    float m = s * invCnt;
    float var = q * invCnt - m*m;
    float a = gam[o] * rsqrtf(var + 1e-5f);
    ab[o] = a;
    cb[o] = bet[o] - m*a;
}

// -------- edge finalize: pure streaming (max/min precomputed in stats) ------
__global__ void finalize_edge(const float* __restrict__ mxb, const float* __restrict__ mnb,
                              const float* __restrict__ uvr,
                              const float* __restrict__ ab, const float* __restrict__ cb,
                              float* __restrict__ hcat, int lgO, int ld, int hoff, int hasR)
{
    long t = (long)blockIdx.x*256 + threadIdx.x;
    int O = 1 << lgO;
    int o = (int)(t & (O-1));
    int g = (int)(t >> lgO);
    float a = ab[o], c = cb[o];
    float mx = mxb[t], mn = mnb[t];
    float zz = (a > 0.f) ? (a*mx + c) : (a*mn + c);
    float outv = leakyf(zz);
    if (hasR) outv += uvr[(long)g*ld + 2*O + o];
    hcat[(long)g*1024 + hoff + o] = outv;
}

// ---------------- column sums of hcat -> partials -> hbar ----------------
__global__ void colsum_part(const float* __restrict__ H, float* __restrict__ part)
{
    int pb = blockIdx.x;
    int tid = threadIdx.x;
    const float4* h4 = (const float4*)(H + (long)pb*128*1024);
    float4 acc = {0,0,0,0};
    for (int r=0;r<128;r++){
        float4 v = h4[r*256 + tid];
        acc.x+=v.x; acc.y+=v.y; acc.z+=v.z; acc.w+=v.w;
    }
    ((float4*)part)[pb*256 + tid] = acc;
}
__global__ void colsum_fin(const float* __restrict__ part, float* __restrict__ hbar)
{
    int tid = threadIdx.x;
    float4 acc = {0,0,0,0};
    for (int p=0;p<128;p++){
        float4 v = ((const float4*)part)[p*256 + tid];
        acc.x+=v.x; acc.y+=v.y; acc.z+=v.z; acc.w+=v.w;
    }
    ((float4*)hbar)[tid] = acc;
}

// ======= fused: Gram partials + FPS (independent work, one stream) =======
// Blocks 0-7: FPS per batch (~300us, hidden under gram ~550us).
// Blocks 8+: gram lower-triangle tiles (flattened old (8,8,16) grid).
struct FpsSh {
    float4 pts1[2048]; float4 pts2[512]; float4 pts3[256];
    int sel1[512]; int sel2[256]; int sel3[128];
};
struct GramSh { __align__(16) float As[32][132]; __align__(16) float Bs[32][132]; };
union ShU { FpsSh f; GramSh g; };

__global__ __launch_bounds__(256)
void gram_fps(const float* __restrict__ A, float* __restrict__ P,
              const float* __restrict__ x, int* __restrict__ idxF,
              float* __restrict__ coorOut)
{
    __shared__ ShU sh;
    int tid = threadIdx.x;
    if (blockIdx.x < 8){
        int b = blockIdx.x;
        const float* xb = x + (long)b*3*NPTS;
        for (int i=tid;i<2048;i+=256)
            sh.f.pts1[i] = make_float4(xb[i], xb[NPTS+i], xb[2*NPTS+i], 0.f);
        __syncthreads();
        if (tid < 64) fps_stage_w<32,true>(sh.f.pts1, 512, sh.f.sel1, tid);
        __syncthreads();
        for (int i=tid;i<512;i+=256) sh.f.pts2[i] = sh.f.pts1[sh.f.sel1[i]];
        __syncthreads();
        if (tid < 64) fps_stage_w<8,false>(sh.f.pts2, 256, sh.f.sel2, tid);
        __syncthreads();
        for (int i=tid;i<256;i+=256) sh.f.pts3[i] = sh.f.pts2[sh.f.sel2[i]];
        __syncthreads();
        if (tid < 64) fps_stage_w<4,false>(sh.f.pts3, 128, sh.f.sel3, tid);
        __syncthreads();
        for (int i=tid;i<128;i+=256){
            int gi = sh.f.sel1[sh.f.sel2[sh.f.sel3[i]]];
            idxF[b*128+i] = gi;
            float4 p = sh.f.pts1[gi];
            coorOut[(long)b*384 + 0*128 + i] = p.x;
            coorOut[(long)b*384 + 1*128 + i] = p.y;
            coorOut[(long)b*384 + 2*128 + i] = p.z;
        }
        return;
    }
    int id8 = blockIdx.x - 8;
    int bx = id8 & 7, by = (id8 >> 3) & 7, bz = id8 >> 6;   // 16 K-chunks
    if (by < bx) return;                                    // lower+diag only
    int ti = by*128, tj = bx*128;
    int ty = tid>>4, tx = tid&15;
    float acc[8][8] = {};
    const float* Abase = A + (long)bz*1024*1024;
    for (int k0=0; k0<1024; k0+=32){
#pragma unroll
        for (int i=0;i<4;i++){
            int e = tid + i*256;
            int mm = e>>5, c4 = (e&31)*4;
            const float* arow = Abase + (long)(k0+mm)*1024;
            *(float4*)&sh.g.As[mm][c4] = *(const float4*)(arow + ti + c4);
            *(float4*)&sh.g.Bs[mm][c4] = *(const float4*)(arow + tj + c4);
        }
        __syncthreads();
#pragma unroll
        for (int mm=0;mm<32;mm++){
            float4 a01 = *(const float4*)&sh.g.As[mm][ty*8];
            float4 a23 = *(const float4*)&sh.g.As[mm][ty*8+4];
            float4 b01 = *(const float4*)&sh.g.Bs[mm][tx*4];
            float4 b23 = *(const float4*)&sh.g.Bs[mm][64+tx*4];
            float aa[8] = {a01.x,a01.y,a01.z,a01.w,a23.x,a23.y,a23.z,a23.w};
            float bb[8] = {b01.x,b01.y,b01.z,b01.w,b23.x,b23.y,b23.z,b23.w};
#pragma unroll
            for (int i=0;i<8;i++)
#pragma unroll
                for (int j=0;j<8;j++)
                    acc[i][j] += aa[i]*bb[j];
        }
        __syncthreads();
    }
    float* Pp = P + ((long)bz<<20);
#pragma unroll
    for (int i=0;i<8;i++){
        long r = ti + ty*8 + i;
        float4 v0 = {acc[i][0],acc[i][1],acc[i][2],acc[i][3]};
        float4 v1 = {acc[i][4],acc[i][5],acc[i][6],acc[i][7]};
        *(float4*)(Pp + r*1024 + tj + tx*4)      = v0;
        *(float4*)(Pp + r*1024 + tj + 64 + tx*4) = v1;
    }
}

__global__ void greduce(const float* __restrict__ P, float* __restrict__ G)
{
    long i4 = (long)blockIdx.x*256 + threadIdx.x;
    float4 a = ((const float4*)P)[i4];
    for (int p=1;p<16;p++){
        float4 v = ((const float4*)P)[((long)p<<18) + i4];
        a.x+=v.x; a.y+=v.y; a.z+=v.z; a.w+=v.w;
    }
    ((float4*)G)[i4] = a;
}

// fill strictly-upper 64x64 tiles of G from lower triangle
__global__ void mirror_g(float* __restrict__ G)
{
    __shared__ float t[64][65];
    int q = blockIdx.x, I = 0, acc = 15;
    while (q >= acc){ q -= acc; acc--; I++; }
    int J = I + 1 + q;
    int tid = threadIdx.x;
#pragma unroll
    for (int k=0;k<16;k++){
        int e = tid + k*256;
        int sr = e>>6, sc = e&63;
        t[sr][sc] = G[(long)(J*64+sr)*1024 + I*64+sc];
    }
    __syncthreads();
#pragma unroll
    for (int k=0;k<16;k++){
        int e = tid + k*256;
        int dr = e>>6, dc = e&63;
        G[(long)(I*64+dr)*1024 + J*64+dc] = t[dc][dr];
    }
}

// ---------------- bn1d affine from Gram ----------------
__global__ void bn5_prep(const float* __restrict__ w5, const float* __restrict__ T,
                         const float* __restrict__ hbar,
                         const float* __restrict__ g5, const float* __restrict__ b5,
                         float* __restrict__ ab, float* __restrict__ cb)
{
    int w = threadIdx.x>>6, lane = threadIdx.x&63;
    int n = blockIdx.x*4 + w;
    const float4* wr = (const float4*)(w5 + (long)n*1024);
    const float4* tr = (const float4*)(T  + (long)n*1024);
    const float4* hb = (const float4*)hbar;
    float s1=0.f, s2=0.f;
    for (int i=lane;i<256;i+=64){
        float4 wv = wr[i], t4 = tr[i], hv = hb[i];
        s1 += wv.x*hv.x + wv.y*hv.y + wv.z*hv.z + wv.w*hv.w;
        s2 += wv.x*t4.x + wv.y*t4.y + wv.z*t4.z + wv.w*t4.w;
    }
#pragma unroll
    for (int off=32; off; off>>=1){
        s1 += __shfl_xor(s1, off);
        s2 += __shfl_xor(s2, off);
    }
    if (lane==0){
        float m = s1*(1.f/16384.f);
        float qq = s2*(1.f/16384.f);
        float var = qq - m*m;
        float a = g5[n]*rsqrtf(var+1e-5f);
        ab[n]=a; cb[n]=b5[n]-m*a;
    }
}

// ---------------- gather selected hcat rows ----------------
__global__ void gather_rows(const float* __restrict__ src, const int* __restrict__ idxF,
                            float* __restrict__ dst)
{
    int r = blockIdx.x;
    int b = r >> 7;
    int srow = (b<<11) + idxF[r];
    const float4* s = (const float4*)(src + (long)srow*1024);
    float4* d = (float4*)(dst + (long)r*1024);
    for (int c=threadIdx.x; c<256; c+=256) d[c] = s[c];
}

// ---------------- final f: bn + leaky + max/mean over 128 points ----------------
__global__ void finalize_f(const float* __restrict__ zsel, const float* __restrict__ ab,
                           const float* __restrict__ cb, float* __restrict__ out)
{
    int b = blockIdx.x >> 3, oc = blockIdx.x & 7;
    int o = oc*256 + threadIdx.x;
    float a = ab[o], c = cb[o];
    float mx = -FLT_MAX, sm = 0.f;
    const float* zp = zsel + (long)b*128*2048 + o;
    for (int i=0;i<128;i++){
        float v = leakyf(a*zp[(long)i*2048] + c);
        mx = fmaxf(mx, v); sm += v;
    }
    out[b*4096 + o] = mx;
    out[b*4096 + 2048 + o] = sm * (1.f/128.f);
}

extern "C" void kernel_launch(void* const* d_in, const int* in_sizes, int n_in,
                              void* d_out, int out_size, void* d_ws, size_t ws_size,
                              hipStream_t stream)
{
    (void)in_sizes; (void)n_in; (void)out_size; (void)ws_size;
    const float* x   = (const float*)d_in[0];
    const float* w1  = (const float*)d_in[1];
    const float* w2  = (const float*)d_in[2];
    const float* w3  = (const float*)d_in[3];
    const float* w4  = (const float*)d_in[4];
    const float* w5  = (const float*)d_in[5];
    const float* rw1 = (const float*)d_in[6];
    const float* rw2 = (const float*)d_in[7];
    const float* rw3 = (const float*)d_in[8];
    const float* g1  = (const float*)d_in[9];  const float* b1 = (const float*)d_in[10];
    const float* g2  = (const float*)d_in[11]; const float* b2 = (const float*)d_in[12];
    const float* g3  = (const float*)d_in[13]; const float* b3 = (const float*)d_in[14];
    const float* g4  = (const float*)d_in[15]; const float* b4 = (const float*)d_in[16];
    const float* g5  = (const float*)d_in[17]; const float* b5 = (const float*)d_in[18];
    float* out = (float*)d_out;

    char* wsb = (char*)d_ws;
    size_t off = 0;
    auto alloc = [&](size_t bytes)->char* {
        char* p = wsb + off;
        off += (bytes + 255) & ~(size_t)255;
        return p;
    };
    float* xt    = (float*)alloc((size_t)16384*3*4);
    float* hcat  = (float*)alloc((size_t)16384*1024*4);
    float* uvr   = (float*)alloc((size_t)16384*1536*4);   // aliased: Dbuf, gram P
    float* Dbuf  = uvr;
    float* gramP = uvr;
    float* G     = (float*)alloc((size_t)1024*1024*4);
    float* T     = (float*)alloc((size_t)2048*1024*4);
    float* zselA = (float*)alloc((size_t)1024*1024*4);
    float* zsel  = (float*)alloc((size_t)1024*2048*4);
    float* mxb   = (float*)alloc((size_t)16384*512*4);
    float* mnb   = (float*)alloc((size_t)16384*512*4);
    float* xx    = (float*)alloc((size_t)16384*4);
    int*   idx   = (int*)  alloc((size_t)16384*8*4);
    float* wcat  = (float*)alloc((size_t)1536*256*4);
    float* ps    = (float*)alloc((size_t)128*2048*4);
    float* pq    = (float*)alloc((size_t)128*2048*4);
    float* cspart= (float*)alloc((size_t)128*1024*4);
    float* hbar  = (float*)alloc((size_t)1024*4);
    float* ab    = (float*)alloc((size_t)2048*4);
    float* cb    = (float*)alloc((size_t)2048*4);
    int*   idxF  = (int*)  alloc((size_t)1024*4);

    transpose_x<<<64, 256, 0, stream>>>(x, xt);

    struct EB {
        const float* X; int lda, C, O, lgO, hoff, hasR;
        const float* w; const float* rw; const float* g; const float* bb;
    };
    EB eb[4] = {
        { xt,        3,    3,   128, 7, 0,   0, w1, nullptr, g1, b1 },
        { hcat+0,    1024, 128, 128, 7, 128, 1, w2, rw1,     g2, b2 },
        { hcat+128,  1024, 128, 256, 8, 256, 1, w3, rw2,     g3, b3 },
        { hcat+256,  1024, 256, 512, 9, 512, 1, w4, rw3,     g4, b4 },
    };
    for (int i=0;i<4;i++){
        EB e = eb[i];
        int ld = (2 + e.hasR) * e.O;
        int tot = e.O * e.C;
        prep_w<<<(tot+255)/256, 256, 0, stream>>>(e.w, e.rw, wcat, e.O, e.C, e.hasR);
        if (i == 0){
            knn_c3<<<256, 256, 0, stream>>>(x, idx);
            gemm_nt<1,false><<<dim3(ld/128, 128, 1), 256, 0, stream>>>(
                e.X, wcat, uvr, 16384, ld, e.C, e.lda, e.C, ld, 0, 0, 0);
        } else {
            rownorm<<<64, 256, 0, stream>>>(e.X, xx, e.lda, e.C);
            for (int b0=0; b0<8; b0+=2){
                const float* Ab = e.X + (long)b0*NPTS*e.lda;
                gemm_nt<4,true><<<dim3(16,16,2), 256, 0, stream>>>(
                    Ab, Ab, Dbuf, 2048, 2048, e.C, e.lda, e.lda, 2048,
                    (long)NPTS*e.lda, (long)NPTS*e.lda, (long)NPTS*NPTS);
                topk8<<<1024, 256, 0, stream>>>(Dbuf, xx, idx, b0);
            }
            gemm_nt<4,false><<<dim3(ld/128, 128, 1), 256, 0, stream>>>(
                e.X, wcat, uvr, 16384, ld, e.C, e.lda, e.C, ld, 0, 0, 0);
        }
        stats_edge<<<128, 256, 0, stream>>>(uvr, idx, ps, pq, mxb, mnb, e.O, ld);
        reduce_stats<<<(e.O+255)/256, 256, 0, stream>>>(ps, pq, e.g, e.bb, ab, cb,
                                                        e.O, 128, 1.f/131072.f);
        finalize_edge<<<64*e.O, 256, 0, stream>>>(mxb, mnb, uvr, ab, cb, hcat,
                                                  e.lgO, ld, e.hoff, e.hasR);
    }

    // ----- block 5 via Gram (+ FPS riding along, fully independent) -----
    colsum_part<<<128, 256, 0, stream>>>(hcat, cspart);
    colsum_fin<<<1, 256, 0, stream>>>(cspart, hbar);
    gram_fps<<<8 + 8*8*16, 256, 0, stream>>>(hcat, gramP, x, idxF, out);
    greduce<<<1024, 256, 0, stream>>>(gramP, G);
    mirror_g<<<120, 256, 0, stream>>>(G);
    gemm_nt<4,false><<<dim3(8,16,1), 256, 0, stream>>>(
        w5, G, T, 2048, 1024, 1024, 1024, 1024, 1024, 0, 0, 0);
    bn5_prep<<<512, 256, 0, stream>>>(w5, T, hbar, g5, b5, ab, cb);
    gather_rows<<<1024, 256, 0, stream>>>(hcat, idxF, zselA);
    gemm_nt<4,false><<<dim3(16,8,1), 256, 0, stream>>>(
        zselA, w5, zsel, 1024, 2048, 1024, 1024, 1024, 2048, 0, 0, 0);
    finalize_f<<<64, 256, 0, stream>>>(zsel, ab, cb, out + 3072);
}

// Round 7
// 3524.373 us; speedup vs baseline: 1.2784x; 1.1234x over previous
//
#include <hip/hip_runtime.h>
#include <float.h>

#define NPTS 2048
#define NB 8
#define KNN 8

__device__ __forceinline__ float leakyf(float x){ return x > 0.f ? x : 0.2f*x; }

#define BET(v1,i1,v2,i2) (((v1)>(v2)) || ((v1)==(v2) && (i1)<(i2)))

// sorted-insert into per-lane top-8 (value desc, index asc); compile-time
// indices only (runtime indexing spills to scratch -- round-3 22GB pathology).
__device__ __forceinline__ void ins8(float tv[8], int tix[8], float v, int ci)
{
    if (BET(v,ci,tv[7],tix[7])){
        tv[7]=v; tix[7]=ci;
#pragma unroll
        for (int q=7;q>=1;q--){
            if (BET(tv[q],tix[q],tv[q-1],tix[q-1])){
                float t=tv[q]; tv[q]=tv[q-1]; tv[q-1]=t;
                int ti=tix[q]; tix[q]=tix[q-1]; tix[q-1]=ti;
            }
        }
    }
}

// wave-wide merge of 64 sorted per-lane top-8 lists; lane0 writes 8 winners.
__device__ __forceinline__ void merge_write8(float tv[8], int tix[8], int lane,
                                             int* __restrict__ dst)
{
#pragma unroll
    for (int r=0;r<8;r++){
        float bv = tv[0]; int bi = tix[0];
#pragma unroll
        for (int off=32; off; off>>=1){
            float ov = __shfl_xor(bv, off); int oi = __shfl_xor(bi, off);
            if (BET(ov,oi,bv,bi)){ bv=ov; bi=oi; }
        }
        if (tv[0]==bv && tix[0]==bi){
#pragma unroll
            for (int q=0;q<7;q++){ tv[q]=tv[q+1]; tix[q]=tix[q+1]; }
            tv[7]=-FLT_MAX; tix[7]=0x7fffffff;
        }
        if (lane==0) dst[r] = bi;
    }
}

// ---------------- transpose x (B,3,N) -> xt (B*N, 3) ----------------
__global__ void transpose_x(const float* __restrict__ x, float* __restrict__ xt)
{
    int g = blockIdx.x*256 + threadIdx.x;
    if (g >= NB*NPTS) return;
    int b = g >> 11, n = g & 2047;
    const float* xb = x + (long)b*3*NPTS;
    xt[g*3+0] = xb[n];
    xt[g*3+1] = xb[NPTS+n];
    xt[g*3+2] = xb[2*NPTS+n];
}

// =================== FPS: 4-wave + registers + DPP argmax ===================
// Packing (dist_bits<<32)|(2047-j) is exact: dist>=0 so float bits are
// monotonic as u32; u64 max == argmax with tie -> LOWEST j (XLA argmax).
// Proven correct in round 6 (passed). Round-6 lesson: coords must stay in
// REGISTERS (LDS re-reads ate the DPP gain); one barrier/iter via parity
// double-buffered wave-result slots.
__device__ __forceinline__ unsigned long long u64max(unsigned long long a,
                                                     unsigned long long b)
{ return a > b ? a : b; }

template<int CTRL>
__device__ __forceinline__ unsigned long long dpp_max_step(unsigned long long v)
{
    unsigned plo = (unsigned)__builtin_amdgcn_update_dpp(0, (int)(unsigned)v,      CTRL, 0xF, 0xF, true);
    unsigned phi = (unsigned)__builtin_amdgcn_update_dpp(0, (int)(unsigned)(v>>32), CTRL, 0xF, 0xF, true);
    unsigned long long p = ((unsigned long long)phi << 32) | plo;
    return u64max(v, p);   // bound_ctrl 0-fill never beats a real candidate
}

__device__ __forceinline__ unsigned long long wave_reduce_max(unsigned long long v)
{
    v = dpp_max_step<0x111>(v);   // row_shr:1
    v = dpp_max_step<0x112>(v);   // row_shr:2
    v = dpp_max_step<0x114>(v);   // row_shr:4
    v = dpp_max_step<0x118>(v);   // row_shr:8   -> lane15/31/47/63 row maxes
    v = dpp_max_step<0x142>(v);   // row_bcast:15
    v = dpp_max_step<0x143>(v);   // row_bcast:31 -> lane63 wave max
    return v;
}

// Distance arithmetic: non-contracted ops in XLA's order (square muls,
// left-fold adds) -- the 896-step sequential chain must match bitwise.
// 256 threads, NPP points/thread in registers, j = r*256 + tid.
template<int NPP>
__device__ void fps_stage_mw(const float4* __restrict__ pts, int m, int* sel,
                             int tid, unsigned long long* wv /* [2][4] */)
{
    float cx[NPP], cy[NPP], cz[NPP], dist[NPP];
#pragma unroll
    for (int r=0;r<NPP;r++){
        float4 p = pts[r*256 + tid];
        cx[r]=p.x; cy[r]=p.y; cz[r]=p.z; dist[r]=1e10f;
    }
    int w = tid>>6, lane = tid&63;
    int last = 0;
    if (tid==0) sel[0]=0;
    for (int i=1;i<m;i++){
        float4 lp = pts[last];
#pragma unroll
        for (int r=0;r<NPP;r++){
            float dx=__fsub_rn(cx[r],lp.x), dy=__fsub_rn(cy[r],lp.y), dz=__fsub_rn(cz[r],lp.z);
            float d = __fadd_rn(__fadd_rn(__fmul_rn(dx,dx), __fmul_rn(dy,dy)), __fmul_rn(dz,dz));
            dist[r] = fminf(dist[r], d);
        }
        unsigned long long t[(NPP+1)/2];
        if (NPP == 1){
            t[0] = ((unsigned long long)__float_as_uint(dist[0])<<32) | (unsigned)(2047 - tid);
        } else {
#pragma unroll
            for (int k=0;k<NPP/2;k++){
                unsigned long long a = ((unsigned long long)__float_as_uint(dist[2*k  ])<<32) | (unsigned)(2047 - ((2*k  )*256+tid));
                unsigned long long b = ((unsigned long long)__float_as_uint(dist[2*k+1])<<32) | (unsigned)(2047 - ((2*k+1)*256+tid));
                t[k] = u64max(a, b);
            }
#pragma unroll
            for (int s=NPP/4; s>=1; s>>=1)
#pragma unroll
                for (int k=0;k<s;k++) t[k] = u64max(t[k], t[k+s]);
        }
        unsigned long long best = wave_reduce_max(t[0]);
        if (lane==63) wv[(i&1)*4 + w] = best;
        __syncthreads();
        unsigned long long b0 = wv[(i&1)*4+0], b1 = wv[(i&1)*4+1];
        unsigned long long b2 = wv[(i&1)*4+2], b3 = wv[(i&1)*4+3];
        best = u64max(u64max(b0,b1), u64max(b2,b3));
        int win = 2047 - (int)(unsigned)best;
        last = win;
        if (tid==0) sel[i] = win;
    }
}

// ---------------- block-1 fused kNN on raw coords (C=3) ----------------
__global__ __launch_bounds__(256)
void knn_c3(const float* __restrict__ x, int* __restrict__ idx)
{
    __shared__ float sx[NPTS], sy[NPTS], sz[NPTS];
    int b = blockIdx.x >> 5, rblk = blockIdx.x & 31;
    const float* xb = x + (long)b*3*NPTS;
    int tid = threadIdx.x;
    for (int i=tid;i<NPTS;i+=256){
        sx[i]=xb[i]; sy[i]=xb[NPTS+i]; sz[i]=xb[2*NPTS+i];
    }
    __syncthreads();
    int w = tid>>6, lane = tid&63;
    for (int rr=0; rr<16; rr++){
        int n = rblk*64 + w*16 + rr;
        float px=sx[n], py=sy[n], pz=sz[n];
        float tv[8]; int tix[8];
#pragma unroll
        for (int i=0;i<8;i++){ tv[i]=-FLT_MAX; tix[i]=0x7fffffff; }
        for (int it=0; it<8; it++){
            int c = it*256 + lane*4;
            float4 qx = *(const float4*)&sx[c];
            float4 qy = *(const float4*)&sy[c];
            float4 qz = *(const float4*)&sz[c];
            float dx, dy, dz;
            dx=qx.x-px; dy=qy.x-py; dz=qz.x-pz;
            ins8(tv,tix, -fmaf(dx,dx,fmaf(dy,dy,dz*dz)), c+0);
            dx=qx.y-px; dy=qy.y-py; dz=qz.y-pz;
            ins8(tv,tix, -fmaf(dx,dx,fmaf(dy,dy,dz*dz)), c+1);
            dx=qx.z-px; dy=qy.z-py; dz=qz.z-pz;
            ins8(tv,tix, -fmaf(dx,dx,fmaf(dy,dy,dz*dz)), c+2);
            dx=qx.w-px; dy=qy.w-py; dz=qz.w-pz;
            ins8(tv,tix, -fmaf(dx,dx,fmaf(dy,dy,dz*dz)), c+3);
        }
        merge_write8(tv, tix, lane, idx + ((long)(b*NPTS+n))*KNN);
    }
}

// ---------------- weight prep: wcat = [w1 ; w2-w1 ; rw] ----------------
__global__ void prep_w(const float* __restrict__ w, const float* __restrict__ rw,
                       float* __restrict__ wcat, int O, int C, int hasR)
{
    int t = blockIdx.x*256 + threadIdx.x;
    if (t >= O*C) return;
    int o = t / C, c = t % C;
    float a = w[o*2*C + c];
    wcat[o*C + c] = a;
    wcat[(O+o)*C + c] = w[o*2*C + C + c] - a;
    if (hasR) wcat[(2*O+o)*C + c] = rw[o*C + c];
}

// ---------------- row squared norms ----------------
__global__ void rownorm(const float* __restrict__ X, float* __restrict__ xx,
                        int lda, int C)
{
    int g = blockIdx.x*256 + threadIdx.x;
    if (g >= NB*NPTS) return;
    const float* r = X + (long)g*lda;
    float s = 0.f;
    for (int c=0;c<C;c++) s += r[c]*r[c];
    xx[g] = s;
}

// ---------------- generic GEMM: C[m][n] = sum_k A[m][k]*B[n][k] ----------------
template<int VEC, bool SYM>
__global__ __launch_bounds__(256)
void gemm_nt(const float* __restrict__ A, const float* __restrict__ B,
             float* __restrict__ C,
             int M, int Nc, int Kd, int lda, int ldb, int ldc,
             long sA, long sB, long sC)
{
    if (SYM && blockIdx.y > blockIdx.x) return;
    int bz = blockIdx.z;
    A += (long)bz * sA; B += (long)bz * sB; C += (long)bz * sC;
    int tm = blockIdx.y * 128, tn = blockIdx.x * 128;
    __shared__ __align__(16) float As[16][132];
    __shared__ __align__(16) float Bs[16][132];
    int tid = threadIdx.x;
    int ty = tid >> 4, tx = tid & 15;
    int cn0 = tx*4, cn1 = 64 + tx*4;
    float acc[8][8] = {};
    for (int k0 = 0; k0 < Kd; k0 += 16){
        if (VEC == 4){
#pragma unroll
            for (int i=0;i<2;i++){
                int e = tid + i*256;
                int rr = e >> 2, kq = e & 3;
                float4 av = *(const float4*)(A + (long)(tm+rr)*lda + k0 + kq*4);
                float4 bv = *(const float4*)(B + (long)(tn+rr)*ldb + k0 + kq*4);
                As[kq*4+0][rr]=av.x; As[kq*4+1][rr]=av.y; As[kq*4+2][rr]=av.z; As[kq*4+3][rr]=av.w;
                Bs[kq*4+0][rr]=bv.x; Bs[kq*4+1][rr]=bv.y; Bs[kq*4+2][rr]=bv.z; Bs[kq*4+3][rr]=bv.w;
            }
        } else {
#pragma unroll
            for (int i=0;i<8;i++){
                int e = tid + i*256;
                int kk = e & 15, rr = e >> 4;
                int ak = k0 + kk;
                As[kk][rr] = (ak < Kd) ? A[(long)(tm+rr)*lda + ak] : 0.f;
                Bs[kk][rr] = (ak < Kd) ? B[(long)(tn+rr)*ldb + ak] : 0.f;
            }
        }
        __syncthreads();
#pragma unroll
        for (int kk=0;kk<16;kk++){
            float4 a01 = *(const float4*)&As[kk][ty*8];
            float4 a23 = *(const float4*)&As[kk][ty*8+4];
            float4 b01 = *(const float4*)&Bs[kk][cn0];
            float4 b23 = *(const float4*)&Bs[kk][cn1];
            float aa[8] = {a01.x,a01.y,a01.z,a01.w,a23.x,a23.y,a23.z,a23.w};
            float bb[8] = {b01.x,b01.y,b01.z,b01.w,b23.x,b23.y,b23.z,b23.w};
#pragma unroll
            for (int i=0;i<8;i++)
#pragma unroll
                for (int j=0;j<8;j++)
                    acc[i][j] += aa[i]*bb[j];
        }
        __syncthreads();
    }
#pragma unroll
    for (int i=0;i<8;i++){
        long r = tm + ty*8 + i;
        float4 v0 = {acc[i][0],acc[i][1],acc[i][2],acc[i][3]};
        float4 v1 = {acc[i][4],acc[i][5],acc[i][6],acc[i][7]};
        *(float4*)(C + r*ldc + tn + cn0) = v0;
        *(float4*)(C + r*ldc + tn + cn1) = v1;
    }
    if (SYM && blockIdx.x != blockIdx.y){
#pragma unroll
        for (int j=0;j<4;j++){
            long r0 = tn + cn0 + j;
            long r1 = tn + cn1 + j;
            float4 u0 = {acc[0][j],  acc[1][j],  acc[2][j],  acc[3][j]};
            float4 u1 = {acc[4][j],  acc[5][j],  acc[6][j],  acc[7][j]};
            float4 u2 = {acc[0][j+4],acc[1][j+4],acc[2][j+4],acc[3][j+4]};
            float4 u3 = {acc[4][j+4],acc[5][j+4],acc[6][j+4],acc[7][j+4]};
            *(float4*)(C + r0*ldc + tm + ty*8)     = u0;
            *(float4*)(C + r0*ldc + tm + ty*8 + 4) = u1;
            *(float4*)(C + r1*ldc + tm + ty*8)     = u2;
            *(float4*)(C + r1*ldc + tm + ty*8 + 4) = u3;
        }
    }
}

// ---------------- top-8 per row of D (value = 2*dot - xx[m]) ----------------
__global__ __launch_bounds__(256)
void topk8(const float* __restrict__ D, const float* __restrict__ xx,
           int* __restrict__ idx, int b0)
{
    int tid = threadIdx.x, w = tid>>6, lane = tid & 63;
    int gr = blockIdx.x*4 + w;
    int b = b0 + (gr >> 11);
    const float* drow = D + (long)gr*NPTS;
    const float* xb = xx + (long)b*NPTS;
    float tv[8]; int tix[8];
#pragma unroll
    for (int i=0;i<8;i++){ tv[i]=-FLT_MAX; tix[i]=0x7fffffff; }
    for (int it=0; it<8; it++){
        int c = it*256 + lane*4;
        float4 d4 = *(const float4*)(drow + c);
        float4 x4 = *(const float4*)(xb + c);
        ins8(tv,tix, 2.f*d4.x - x4.x, c+0);
        ins8(tv,tix, 2.f*d4.y - x4.y, c+1);
        ins8(tv,tix, 2.f*d4.z - x4.z, c+2);
        ins8(tv,tix, 2.f*d4.w - x4.w, c+3);
    }
    merge_write8(tv, tix, lane, idx + ((long)(b0*NPTS) + gr)*KNN);
}

// ------- edge bn stats + max/min: one gather pass produces everything -------
__global__ __launch_bounds__(256)
void stats_edge(const float* __restrict__ uvr, const int* __restrict__ idx,
                float* __restrict__ ps, float* __restrict__ pq,
                float* __restrict__ mxb, float* __restrict__ mnb,
                int O, int ld)
{
    int tid = threadIdx.x;
    int r0 = blockIdx.x * 128;
    float s0=0,q0=0,s1=0,q1=0;
    for (int rr=0; rr<128; rr++){
        int g = r0 + rr;
        int b = g >> 11;
        const int* ip = idx + (long)g*KNN;
        const float* vrow = uvr + (long)g*ld + O;
        const float* ub[8];
#pragma unroll
        for (int k=0;k<8;k++) ub[k] = uvr + (long)((b<<11) + ip[k])*ld;
        int o = tid;
        if (o < O){
            float vv = vrow[o];
            float mx=-FLT_MAX, mn=FLT_MAX;
#pragma unroll
            for (int k=0;k<8;k++){
                float f = ub[k][o]+vv;
                s0+=f; q0+=f*f; mx=fmaxf(mx,f); mn=fminf(mn,f);
            }
            mxb[(long)g*O+o]=mx; mnb[(long)g*O+o]=mn;
        }
        o = tid + 256;
        if (o < O){
            float vv = vrow[o];
            float mx=-FLT_MAX, mn=FLT_MAX;
#pragma unroll
            for (int k=0;k<8;k++){
                float f = ub[k][o]+vv;
                s1+=f; q1+=f*f; mx=fmaxf(mx,f); mn=fminf(mn,f);
            }
            mxb[(long)g*O+o]=mx; mnb[(long)g*O+o]=mn;
        }
    }
    if (tid < O){ ps[blockIdx.x*2048 + tid] = s0; pq[blockIdx.x*2048 + tid] = q0; }
    if (tid+256 < O){ ps[blockIdx.x*2048 + tid+256] = s1; pq[blockIdx.x*2048 + tid+256] = q1; }
}

// ---------------- stats -> affine (a, c) ----------------
__global__ void reduce_stats(const float* __restrict__ ps, const float* __restrict__ pq,
                             const float* __restrict__ gam, const float* __restrict__ bet,
                             float* __restrict__ ab, float* __restrict__ cb,
                             int O, int np, float invCnt)
{
    int o = blockIdx.x*256 + threadIdx.x;
    if (o >= O) return;
    float s=0.f, q=0.f;
    for (int p=0;p<np;p++){ s += ps[p*2048 + o]; q += pq[p*2048 + o]; }
    float m = s * invCnt;
    float var = q * invCnt - m*m;
    float a = gam[o] * rsqrtf(var + 1e-5f);
    ab[o] = a;
    cb[o] = bet[o] - m*a;
}

// -------- edge finalize: pure streaming (max/min precomputed in stats) ------
__global__ void finalize_edge(const float* __restrict__ mxb, const float* __restrict__ mnb,
                              const float* __restrict__ uvr,
                              const float* __restrict__ ab, const float* __restrict__ cb,
                              float* __restrict__ hcat, int lgO, int ld, int hoff, int hasR)
{
    long t = (long)blockIdx.x*256 + threadIdx.x;
    int O = 1 << lgO;
    int o = (int)(t & (O-1));
    int g = (int)(t >> lgO);
    float a = ab[o], c = cb[o];
    float mx = mxb[t], mn = mnb[t];
    float zz = (a > 0.f) ? (a*mx + c) : (a*mn + c);
    float outv = leakyf(zz);
    if (hasR) outv += uvr[(long)g*ld + 2*O + o];
    hcat[(long)g*1024 + hoff + o] = outv;
}

// ---------------- column sums of hcat -> partials -> hbar ----------------
__global__ void colsum_part(const float* __restrict__ H, float* __restrict__ part)
{
    int pb = blockIdx.x;
    int tid = threadIdx.x;
    const float4* h4 = (const float4*)(H + (long)pb*128*1024);
    float4 acc = {0,0,0,0};
    for (int r=0;r<128;r++){
        float4 v = h4[r*256 + tid];
        acc.x+=v.x; acc.y+=v.y; acc.z+=v.z; acc.w+=v.w;
    }
    ((float4*)part)[pb*256 + tid] = acc;
}
__global__ void colsum_fin(const float* __restrict__ part, float* __restrict__ hbar)
{
    int tid = threadIdx.x;
    float4 acc = {0,0,0,0};
    for (int p=0;p<128;p++){
        float4 v = ((const float4*)part)[p*256 + tid];
        acc.x+=v.x; acc.y+=v.y; acc.z+=v.z; acc.w+=v.w;
    }
    ((float4*)hbar)[tid] = acc;
}

// ======= fused: Gram partials + FPS (independent work, one stream) =======
struct FpsSh {
    float4 pts1[2048]; float4 pts2[512]; float4 pts3[256];
    int sel1[512]; int sel2[256]; int sel3[128];
    unsigned long long wv[8];                 // [2 parity][4 waves]
};
struct GramSh { __align__(16) float As[32][132]; __align__(16) float Bs[32][132]; };
union ShU { FpsSh f; GramSh g; };

__global__ __launch_bounds__(256)
void gram_fps(const float* __restrict__ A, float* __restrict__ P,
              const float* __restrict__ x, int* __restrict__ idxF,
              float* __restrict__ coorOut)
{
    __shared__ ShU sh;
    int tid = threadIdx.x;
    if (blockIdx.x < 8){
        int b = blockIdx.x;
        const float* xb = x + (long)b*3*NPTS;
        for (int i=tid;i<2048;i+=256)
            sh.f.pts1[i] = make_float4(xb[i], xb[NPTS+i], xb[2*NPTS+i], 0.f);
        __syncthreads();
        fps_stage_mw<8>(sh.f.pts1, 512, sh.f.sel1, tid, sh.f.wv);
        __syncthreads();
        for (int i=tid;i<512;i+=256) sh.f.pts2[i] = sh.f.pts1[sh.f.sel1[i]];
        __syncthreads();
        fps_stage_mw<2>(sh.f.pts2, 256, sh.f.sel2, tid, sh.f.wv);
        __syncthreads();
        for (int i=tid;i<256;i+=256) sh.f.pts3[i] = sh.f.pts2[sh.f.sel2[i]];
        __syncthreads();
        fps_stage_mw<1>(sh.f.pts3, 128, sh.f.sel3, tid, sh.f.wv);
        __syncthreads();
        for (int i=tid;i<128;i+=256){
            int gi = sh.f.sel1[sh.f.sel2[sh.f.sel3[i]]];
            idxF[b*128+i] = gi;
            float4 p = sh.f.pts1[gi];
            coorOut[(long)b*384 + 0*128 + i] = p.x;
            coorOut[(long)b*384 + 1*128 + i] = p.y;
            coorOut[(long)b*384 + 2*128 + i] = p.z;
        }
        return;
    }
    int id8 = blockIdx.x - 8;
    int bx = id8 & 7, by = (id8 >> 3) & 7, bz = id8 >> 6;   // 16 K-chunks
    if (by < bx) return;                                    // lower+diag only
    int ti = by*128, tj = bx*128;
    int ty = tid>>4, tx = tid&15;
    float acc[8][8] = {};
    const float* Abase = A + (long)bz*1024*1024;
    for (int k0=0; k0<1024; k0+=32){
#pragma unroll
        for (int i=0;i<4;i++){
            int e = tid + i*256;
            int mm = e>>5, c4 = (e&31)*4;
            const float* arow = Abase + (long)(k0+mm)*1024;
            *(float4*)&sh.g.As[mm][c4] = *(const float4*)(arow + ti + c4);
            *(float4*)&sh.g.Bs[mm][c4] = *(const float4*)(arow + tj + c4);
        }
        __syncthreads();
#pragma unroll
        for (int mm=0;mm<32;mm++){
            float4 a01 = *(const float4*)&sh.g.As[mm][ty*8];
            float4 a23 = *(const float4*)&sh.g.As[mm][ty*8+4];
            float4 b01 = *(const float4*)&sh.g.Bs[mm][tx*4];
            float4 b23 = *(const float4*)&sh.g.Bs[mm][64+tx*4];
            float aa[8] = {a01.x,a01.y,a01.z,a01.w,a23.x,a23.y,a23.z,a23.w};
            float bb[8] = {b01.x,b01.y,b01.z,b01.w,b23.x,b23.y,b23.z,b23.w};
#pragma unroll
            for (int i=0;i<8;i++)
#pragma unroll
                for (int j=0;j<8;j++)
                    acc[i][j] += aa[i]*bb[j];
        }
        __syncthreads();
    }
    float* Pp = P + ((long)bz<<20);
#pragma unroll
    for (int i=0;i<8;i++){
        long r = ti + ty*8 + i;
        float4 v0 = {acc[i][0],acc[i][1],acc[i][2],acc[i][3]};
        float4 v1 = {acc[i][4],acc[i][5],acc[i][6],acc[i][7]};
        *(float4*)(Pp + r*1024 + tj + tx*4)      = v0;
        *(float4*)(Pp + r*1024 + tj + 64 + tx*4) = v1;
    }
}

__global__ void greduce(const float* __restrict__ P, float* __restrict__ G)
{
    long i4 = (long)blockIdx.x*256 + threadIdx.x;
    float4 a = ((const float4*)P)[i4];
    for (int p=1;p<16;p++){
        float4 v = ((const float4*)P)[((long)p<<18) + i4];
        a.x+=v.x; a.y+=v.y; a.z+=v.z; a.w+=v.w;
    }
    ((float4*)G)[i4] = a;
}

// fill strictly-upper 64x64 tiles of G from lower triangle
__global__ void mirror_g(float* __restrict__ G)
{
    __shared__ float t[64][65];
    int q = blockIdx.x, I = 0, acc = 15;
    while (q >= acc){ q -= acc; acc--; I++; }
    int J = I + 1 + q;
    int tid = threadIdx.x;
#pragma unroll
    for (int k=0;k<16;k++){
        int e = tid + k*256;
        int sr = e>>6, sc = e&63;
        t[sr][sc] = G[(long)(J*64+sr)*1024 + I*64+sc];
    }
    __syncthreads();
#pragma unroll
    for (int k=0;k<16;k++){
        int e = tid + k*256;
        int dr = e>>6, dc = e&63;
        G[(long)(I*64+dr)*1024 + J*64+dc] = t[dc][dr];
    }
}

// ---------------- bn1d affine from Gram ----------------
__global__ void bn5_prep(const float* __restrict__ w5, const float* __restrict__ T,
                         const float* __restrict__ hbar,
                         const float* __restrict__ g5, const float* __restrict__ b5,
                         float* __restrict__ ab, float* __restrict__ cb)
{
    int w = threadIdx.x>>6, lane = threadIdx.x&63;
    int n = blockIdx.x*4 + w;
    const float4* wr = (const float4*)(w5 + (long)n*1024);
    const float4* tr = (const float4*)(T  + (long)n*1024);
    const float4* hb = (const float4*)hbar;
    float s1=0.f, s2=0.f;
    for (int i=lane;i<256;i+=64){
        float4 wv = wr[i], t4 = tr[i], hv = hb[i];
        s1 += wv.x*hv.x + wv.y*hv.y + wv.z*hv.z + wv.w*hv.w;
        s2 += wv.x*t4.x + wv.y*t4.y + wv.z*t4.z + wv.w*t4.w;
    }
#pragma unroll
    for (int off=32; off; off>>=1){
        s1 += __shfl_xor(s1, off);
        s2 += __shfl_xor(s2, off);
    }
    if (lane==0){
        float m = s1*(1.f/16384.f);
        float qq = s2*(1.f/16384.f);
        float var = qq - m*m;
        float a = g5[n]*rsqrtf(var+1e-5f);
        ab[n]=a; cb[n]=b5[n]-m*a;
    }
}

// ---------------- gather selected hcat rows ----------------
__global__ void gather_rows(const float* __restrict__ src, const int* __restrict__ idxF,
                            float* __restrict__ dst)
{
    int r = blockIdx.x;
    int b = r >> 7;
    int srow = (b<<11) + idxF[r];
    const float4* s = (const float4*)(src + (long)srow*1024);
    float4* d = (float4*)(dst + (long)r*1024);
    for (int c=threadIdx.x; c<256; c+=256) d[c] = s[c];
}

// ---------------- final f: bn + leaky + max/mean over 128 points ----------------
__global__ void finalize_f(const float* __restrict__ zsel, const float* __restrict__ ab,
                           const float* __restrict__ cb, float* __restrict__ out)
{
    int b = blockIdx.x >> 3, oc = blockIdx.x & 7;
    int o = oc*256 + threadIdx.x;
    float a = ab[o], c = cb[o];
    float mx = -FLT_MAX, sm = 0.f;
    const float* zp = zsel + (long)b*128*2048 + o;
    for (int i=0;i<128;i++){
        float v = leakyf(a*zp[(long)i*2048] + c);
        mx = fmaxf(mx, v); sm += v;
    }
    out[b*4096 + o] = mx;
    out[b*4096 + 2048 + o] = sm * (1.f/128.f);
}

extern "C" void kernel_launch(void* const* d_in, const int* in_sizes, int n_in,
                              void* d_out, int out_size, void* d_ws, size_t ws_size,
                              hipStream_t stream)
{
    (void)in_sizes; (void)n_in; (void)out_size; (void)ws_size;
    const float* x   = (const float*)d_in[0];
    const float* w1  = (const float*)d_in[1];
    const float* w2  = (const float*)d_in[2];
    const float* w3  = (const float*)d_in[3];
    const float* w4  = (const float*)d_in[4];
    const float* w5  = (const float*)d_in[5];
    const float* rw1 = (const float*)d_in[6];
    const float* rw2 = (const float*)d_in[7];
    const float* rw3 = (const float*)d_in[8];
    const float* g1  = (const float*)d_in[9];  const float* b1 = (const float*)d_in[10];
    const float* g2  = (const float*)d_in[11]; const float* b2 = (const float*)d_in[12];
    const float* g3  = (const float*)d_in[13]; const float* b3 = (const float*)d_in[14];
    const float* g4  = (const float*)d_in[15]; const float* b4 = (const float*)d_in[16];
    const float* g5  = (const float*)d_in[17]; const float* b5 = (const float*)d_in[18];
    float* out = (float*)d_out;

    char* wsb = (char*)d_ws;
    size_t off = 0;
    auto alloc = [&](size_t bytes)->char* {
        char* p = wsb + off;
        off += (bytes + 255) & ~(size_t)255;
        return p;
    };
    float* xt    = (float*)alloc((size_t)16384*3*4);
    float* hcat  = (float*)alloc((size_t)16384*1024*4);
    float* uvr   = (float*)alloc((size_t)16384*1536*4);   // aliased: Dbuf, gram P
    float* Dbuf  = uvr;
    float* gramP = uvr;
    float* G     = (float*)alloc((size_t)1024*1024*4);
    float* T     = (float*)alloc((size_t)2048*1024*4);
    float* zselA = (float*)alloc((size_t)1024*1024*4);
    float* zsel  = (float*)alloc((size_t)1024*2048*4);
    float* mxb   = (float*)alloc((size_t)16384*512*4);
    float* mnb   = (float*)alloc((size_t)16384*512*4);
    float* xx    = (float*)alloc((size_t)16384*4);
    int*   idx   = (int*)  alloc((size_t)16384*8*4);
    float* wcat  = (float*)alloc((size_t)1536*256*4);
    float* ps    = (float*)alloc((size_t)128*2048*4);
    float* pq    = (float*)alloc((size_t)128*2048*4);
    float* cspart= (float*)alloc((size_t)128*1024*4);
    float* hbar  = (float*)alloc((size_t)1024*4);
    float* ab    = (float*)alloc((size_t)2048*4);
    float* cb    = (float*)alloc((size_t)2048*4);
    int*   idxF  = (int*)  alloc((size_t)1024*4);

    transpose_x<<<64, 256, 0, stream>>>(x, xt);

    struct EB {
        const float* X; int lda, C, O, lgO, hoff, hasR;
        const float* w; const float* rw; const float* g; const float* bb;
    };
    EB eb[4] = {
        { xt,        3,    3,   128, 7, 0,   0, w1, nullptr, g1, b1 },
        { hcat+0,    1024, 128, 128, 7, 128, 1, w2, rw1,     g2, b2 },
        { hcat+128,  1024, 128, 256, 8, 256, 1, w3, rw2,     g3, b3 },
        { hcat+256,  1024, 256, 512, 9, 512, 1, w4, rw3,     g4, b4 },
    };
    for (int i=0;i<4;i++){
        EB e = eb[i];
        int ld = (2 + e.hasR) * e.O;
        int tot = e.O * e.C;
        prep_w<<<(tot+255)/256, 256, 0, stream>>>(e.w, e.rw, wcat, e.O, e.C, e.hasR);
        if (i == 0){
            knn_c3<<<256, 256, 0, stream>>>(x, idx);
            gemm_nt<1,false><<<dim3(ld/128, 128, 1), 256, 0, stream>>>(
                e.X, wcat, uvr, 16384, ld, e.C, e.lda, e.C, ld, 0, 0, 0);
        } else {
            rownorm<<<64, 256, 0, stream>>>(e.X, xx, e.lda, e.C);
            for (int b0=0; b0<8; b0+=2){
                const float* Ab = e.X + (long)b0*NPTS*e.lda;
                gemm_nt<4,true><<<dim3(16,16,2), 256, 0, stream>>>(
                    Ab, Ab, Dbuf, 2048, 2048, e.C, e.lda, e.lda, 2048,
                    (long)NPTS*e.lda, (long)NPTS*e.lda, (long)NPTS*NPTS);
                topk8<<<1024, 256, 0, stream>>>(Dbuf, xx, idx, b0);
            }
            gemm_nt<4,false><<<dim3(ld/128, 128, 1), 256, 0, stream>>>(
                e.X, wcat, uvr, 16384, ld, e.C, e.lda, e.C, ld, 0, 0, 0);
        }
        stats_edge<<<128, 256, 0, stream>>>(uvr, idx, ps, pq, mxb, mnb, e.O, ld);
        reduce_stats<<<(e.O+255)/256, 256, 0, stream>>>(ps, pq, e.g, e.bb, ab, cb,
                                                        e.O, 128, 1.f/131072.f);
        finalize_edge<<<64*e.O, 256, 0, stream>>>(mxb, mnb, uvr, ab, cb, hcat,
                                                  e.lgO, ld, e.hoff, e.hasR);
    }

    // ----- block 5 via Gram (+ FPS riding along, fully independent) -----
    colsum_part<<<128, 256, 0, stream>>>(hcat, cspart);
    colsum_fin<<<1, 256, 0, stream>>>(cspart, hbar);
    gram_fps<<<8 + 8*8*16, 256, 0, stream>>>(hcat, gramP, x, idxF, out);
    greduce<<<1024, 256, 0, stream>>>(gramP, G);
    mirror_g<<<120, 256, 0, stream>>>(G);
    gemm_nt<4,false><<<dim3(8,16,1), 256, 0, stream>>>(
        w5, G, T, 2048, 1024, 1024, 1024, 1024, 1024, 0, 0, 0);
    bn5_prep<<<512, 256, 0, stream>>>(w5, T, hbar, g5, b5, ab, cb);
    gather_rows<<<1024, 256, 0, stream>>>(hcat, idxF, zselA);
    gemm_nt<4,false><<<dim3(16,8,1), 256, 0, stream>>>(
        zselA, w5, zsel, 1024, 2048, 1024, 1024, 1024, 2048, 0, 0, 0);
    finalize_f<<<64, 256, 0, stream>>>(zsel, ab, cb, out + 3072);
}

// Round 8
// 3052.472 us; speedup vs baseline: 1.4761x; 1.1546x over previous
//
#include <hip/hip_runtime.h>
#include <float.h>

#define NPTS 2048
#define NB 8
#define KNN 8

typedef short bf16x8 __attribute__((ext_vector_type(8)));
typedef float f32x4  __attribute__((ext_vector_type(4)));

__device__ __forceinline__ float leakyf(float x){ return x > 0.f ? x : 0.2f*x; }

// fp32 -> bf16 round-to-nearest-even (matches XLA)
__device__ __forceinline__ unsigned short f2bf(float f){
    unsigned u = __float_as_uint(f);
    return (unsigned short)((u + 0x7FFF + ((u>>16)&1)) >> 16);
}

#define BET(v1,i1,v2,i2) (((v1)>(v2)) || ((v1)==(v2) && (i1)<(i2)))

// sorted-insert into per-lane top-8; compile-time indices only (runtime
// indexing spills to scratch -- round-3 22GB pathology).
__device__ __forceinline__ void ins8(float tv[8], int tix[8], float v, int ci)
{
    if (BET(v,ci,tv[7],tix[7])){
        tv[7]=v; tix[7]=ci;
#pragma unroll
        for (int q=7;q>=1;q--){
            if (BET(tv[q],tix[q],tv[q-1],tix[q-1])){
                float t=tv[q]; tv[q]=tv[q-1]; tv[q-1]=t;
                int ti=tix[q]; tix[q]=tix[q-1]; tix[q-1]=ti;
            }
        }
    }
}

__device__ __forceinline__ void merge_write8(float tv[8], int tix[8], int lane,
                                             int* __restrict__ dst)
{
#pragma unroll
    for (int r=0;r<8;r++){
        float bv = tv[0]; int bi = tix[0];
#pragma unroll
        for (int off=32; off; off>>=1){
            float ov = __shfl_xor(bv, off); int oi = __shfl_xor(bi, off);
            if (BET(ov,oi,bv,bi)){ bv=ov; bi=oi; }
        }
        if (tv[0]==bv && tix[0]==bi){
#pragma unroll
            for (int q=0;q<7;q++){ tv[q]=tv[q+1]; tix[q]=tix[q+1]; }
            tv[7]=-FLT_MAX; tix[7]=0x7fffffff;
        }
        if (lane==0) dst[r] = bi;
    }
}

// ---------------- transpose x (B,3,N) -> xt (B*N, 3) ----------------
__global__ void transpose_x(const float* __restrict__ x, float* __restrict__ xt)
{
    int g = blockIdx.x*256 + threadIdx.x;
    if (g >= NB*NPTS) return;
    int b = g >> 11, n = g & 2047;
    const float* xb = x + (long)b*3*NPTS;
    xt[g*3+0] = xb[n];
    xt[g*3+1] = xb[NPTS+n];
    xt[g*3+2] = xb[2*NPTS+n];
}

// =================== FPS: 4-wave + registers + DPP argmax (exact) ==========
__device__ __forceinline__ unsigned long long u64max(unsigned long long a,
                                                     unsigned long long b)
{ return a > b ? a : b; }

template<int CTRL>
__device__ __forceinline__ unsigned long long dpp_max_step(unsigned long long v)
{
    unsigned plo = (unsigned)__builtin_amdgcn_update_dpp(0, (int)(unsigned)v,      CTRL, 0xF, 0xF, true);
    unsigned phi = (unsigned)__builtin_amdgcn_update_dpp(0, (int)(unsigned)(v>>32), CTRL, 0xF, 0xF, true);
    unsigned long long p = ((unsigned long long)phi << 32) | plo;
    return u64max(v, p);
}

__device__ __forceinline__ unsigned long long wave_reduce_max(unsigned long long v)
{
    v = dpp_max_step<0x111>(v);
    v = dpp_max_step<0x112>(v);
    v = dpp_max_step<0x114>(v);
    v = dpp_max_step<0x118>(v);
    v = dpp_max_step<0x142>(v);
    v = dpp_max_step<0x143>(v);
    return v;
}

// Non-contracted ops in XLA's order; (dist<<32)|(2047-j) packing -> exact
// argmax with tie -> lowest j. Proven correct rounds 6-7.
template<int NPP>
__device__ void fps_stage_mw(const float4* __restrict__ pts, int m, int* sel,
                             int tid, unsigned long long* wv)
{
    float cx[NPP], cy[NPP], cz[NPP], dist[NPP];
#pragma unroll
    for (int r=0;r<NPP;r++){
        float4 p = pts[r*256 + tid];
        cx[r]=p.x; cy[r]=p.y; cz[r]=p.z; dist[r]=1e10f;
    }
    int w = tid>>6, lane = tid&63;
    int last = 0;
    if (tid==0) sel[0]=0;
    for (int i=1;i<m;i++){
        float4 lp = pts[last];
#pragma unroll
        for (int r=0;r<NPP;r++){
            float dx=__fsub_rn(cx[r],lp.x), dy=__fsub_rn(cy[r],lp.y), dz=__fsub_rn(cz[r],lp.z);
            float d = __fadd_rn(__fadd_rn(__fmul_rn(dx,dx), __fmul_rn(dy,dy)), __fmul_rn(dz,dz));
            dist[r] = fminf(dist[r], d);
        }
        unsigned long long t[(NPP+1)/2];
        if (NPP == 1){
            t[0] = ((unsigned long long)__float_as_uint(dist[0])<<32) | (unsigned)(2047 - tid);
        } else {
#pragma unroll
            for (int k=0;k<NPP/2;k++){
                unsigned long long a = ((unsigned long long)__float_as_uint(dist[2*k  ])<<32) | (unsigned)(2047 - ((2*k  )*256+tid));
                unsigned long long b = ((unsigned long long)__float_as_uint(dist[2*k+1])<<32) | (unsigned)(2047 - ((2*k+1)*256+tid));
                t[k] = u64max(a, b);
            }
#pragma unroll
            for (int s=NPP/4; s>=1; s>>=1)
#pragma unroll
                for (int k=0;k<s;k++) t[k] = u64max(t[k], t[k+s]);
        }
        unsigned long long best = wave_reduce_max(t[0]);
        if (lane==63) wv[(i&1)*4 + w] = best;
        __syncthreads();
        unsigned long long b0 = wv[(i&1)*4+0], b1 = wv[(i&1)*4+1];
        unsigned long long b2 = wv[(i&1)*4+2], b3 = wv[(i&1)*4+3];
        best = u64max(u64max(b0,b1), u64max(b2,b3));
        int win = 2047 - (int)(unsigned)best;
        last = win;
        if (tid==0) sel[i] = win;
    }
}

struct FpsSh {
    float4 pts1[2048]; float4 pts2[512]; float4 pts3[256];
    int sel1[512]; int sel2[256]; int sel3[128];
    unsigned long long wv[8];
};
struct GemmSh { __align__(16) float As[16][132]; __align__(16) float Bs[16][132]; };
union ShU { FpsSh f; GemmSh g; };

__device__ void fps_block(const float* __restrict__ x, int* __restrict__ idxF,
                          float* __restrict__ coorOut, int b, int tid, FpsSh& sh)
{
    const float* xb = x + (long)b*3*NPTS;
    for (int i=tid;i<2048;i+=256)
        sh.pts1[i] = make_float4(xb[i], xb[NPTS+i], xb[2*NPTS+i], 0.f);
    __syncthreads();
    fps_stage_mw<8>(sh.pts1, 512, sh.sel1, tid, sh.wv);
    __syncthreads();
    for (int i=tid;i<512;i+=256) sh.pts2[i] = sh.pts1[sh.sel1[i]];
    __syncthreads();
    fps_stage_mw<2>(sh.pts2, 256, sh.sel2, tid, sh.wv);
    __syncthreads();
    for (int i=tid;i<256;i+=256) sh.pts3[i] = sh.pts2[sh.sel2[i]];
    __syncthreads();
    fps_stage_mw<1>(sh.pts3, 128, sh.sel3, tid, sh.wv);
    __syncthreads();
    for (int i=tid;i<128;i+=256){
        int gi = sh.sel1[sh.sel2[sh.sel3[i]]];
        idxF[b*128+i] = gi;
        float4 p = sh.pts1[gi];
        coorOut[(long)b*384 + 0*128 + i] = p.x;
        coorOut[(long)b*384 + 1*128 + i] = p.y;
        coorOut[(long)b*384 + 2*128 + i] = p.z;
    }
}

// ------- block-1 fused kNN on raw coords (C=3); 1024 blocks for occupancy ---
__global__ __launch_bounds__(256)
void knn_c3(const float* __restrict__ x, int* __restrict__ idx)
{
    __shared__ float sx[NPTS], sy[NPTS], sz[NPTS];
    int b = blockIdx.x >> 7, rblk = blockIdx.x & 127;
    const float* xb = x + (long)b*3*NPTS;
    int tid = threadIdx.x;
    for (int i=tid;i<NPTS;i+=256){
        sx[i]=xb[i]; sy[i]=xb[NPTS+i]; sz[i]=xb[2*NPTS+i];
    }
    __syncthreads();
    int w = tid>>6, lane = tid&63;
    for (int rr=0; rr<4; rr++){
        int n = rblk*16 + w*4 + rr;
        float px=sx[n], py=sy[n], pz=sz[n];
        float tv[8]; int tix[8];
#pragma unroll
        for (int i=0;i<8;i++){ tv[i]=-FLT_MAX; tix[i]=0x7fffffff; }
        for (int it=0; it<8; it++){
            int c = it*256 + lane*4;
            float4 qx = *(const float4*)&sx[c];
            float4 qy = *(const float4*)&sy[c];
            float4 qz = *(const float4*)&sz[c];
            float dx, dy, dz;
            dx=qx.x-px; dy=qy.x-py; dz=qz.x-pz;
            ins8(tv,tix, -fmaf(dx,dx,fmaf(dy,dy,dz*dz)), c+0);
            dx=qx.y-px; dy=qy.y-py; dz=qz.y-pz;
            ins8(tv,tix, -fmaf(dx,dx,fmaf(dy,dy,dz*dz)), c+1);
            dx=qx.z-px; dy=qy.z-py; dz=qz.z-pz;
            ins8(tv,tix, -fmaf(dx,dx,fmaf(dy,dy,dz*dz)), c+2);
            dx=qx.w-px; dy=qy.w-py; dz=qz.w-pz;
            ins8(tv,tix, -fmaf(dx,dx,fmaf(dy,dy,dz*dz)), c+3);
        }
        merge_write8(tv, tix, lane, idx + ((long)(b*NPTS+n))*KNN);
    }
}

// ---------------- weight prep: wcat = [w1 ; w2-w1 ; rw] ----------------
__global__ void prep_w(const float* __restrict__ w, const float* __restrict__ rw,
                       float* __restrict__ wcat, int O, int C, int hasR)
{
    int t = blockIdx.x*256 + threadIdx.x;
    if (t >= O*C) return;
    int o = t / C, c = t % C;
    float a = w[o*2*C + c];
    wcat[o*C + c] = a;
    wcat[(O+o)*C + c] = w[o*2*C + C + c] - a;
    if (hasR) wcat[(2*O+o)*C + c] = rw[o*C + c];
}

// ---------------- row squared norms ----------------
__global__ void rownorm(const float* __restrict__ X, float* __restrict__ xx,
                        int lda, int C)
{
    int g = blockIdx.x*256 + threadIdx.x;
    if (g >= NB*NPTS) return;
    const float* r = X + (long)g*lda;
    float s = 0.f;
    for (int c=0;c<C;c++) s += r[c]*r[c];
    xx[g] = s;
}

// ------------- generic GEMM body: C[m][n] = sum_k A[m][k]*B[n][k] -----------
template<int VEC, bool SYM>
__device__ __forceinline__ void gemm_body(
    float (*As)[132], float (*Bs)[132],
    const float* __restrict__ A, const float* __restrict__ B, float* __restrict__ C,
    int Kd, int lda, int ldb, int ldc, int bx, int by, int tid)
{
    int tm = by * 128, tn = bx * 128;
    int ty = tid >> 4, tx = tid & 15;
    int cn0 = tx*4, cn1 = 64 + tx*4;
    float acc[8][8] = {};
    for (int k0 = 0; k0 < Kd; k0 += 16){
        if (VEC == 4){
#pragma unroll
            for (int i=0;i<2;i++){
                int e = tid + i*256;
                int rr = e >> 2, kq = e & 3;
                float4 av = *(const float4*)(A + (long)(tm+rr)*lda + k0 + kq*4);
                float4 bv = *(const float4*)(B + (long)(tn+rr)*ldb + k0 + kq*4);
                As[kq*4+0][rr]=av.x; As[kq*4+1][rr]=av.y; As[kq*4+2][rr]=av.z; As[kq*4+3][rr]=av.w;
                Bs[kq*4+0][rr]=bv.x; Bs[kq*4+1][rr]=bv.y; Bs[kq*4+2][rr]=bv.z; Bs[kq*4+3][rr]=bv.w;
            }
        } else {
#pragma unroll
            for (int i=0;i<8;i++){
                int e = tid + i*256;
                int kk = e & 15, rr = e >> 4;
                int ak = k0 + kk;
                As[kk][rr] = (ak < Kd) ? A[(long)(tm+rr)*lda + ak] : 0.f;
                Bs[kk][rr] = (ak < Kd) ? B[(long)(tn+rr)*ldb + ak] : 0.f;
            }
        }
        __syncthreads();
#pragma unroll
        for (int kk=0;kk<16;kk++){
            float4 a01 = *(const float4*)&As[kk][ty*8];
            float4 a23 = *(const float4*)&As[kk][ty*8+4];
            float4 b01 = *(const float4*)&Bs[kk][cn0];
            float4 b23 = *(const float4*)&Bs[kk][cn1];
            float aa[8] = {a01.x,a01.y,a01.z,a01.w,a23.x,a23.y,a23.z,a23.w};
            float bb[8] = {b01.x,b01.y,b01.z,b01.w,b23.x,b23.y,b23.z,b23.w};
#pragma unroll
            for (int i=0;i<8;i++)
#pragma unroll
                for (int j=0;j<8;j++)
                    acc[i][j] += aa[i]*bb[j];
        }
        __syncthreads();
    }
#pragma unroll
    for (int i=0;i<8;i++){
        long r = tm + ty*8 + i;
        float4 v0 = {acc[i][0],acc[i][1],acc[i][2],acc[i][3]};
        float4 v1 = {acc[i][4],acc[i][5],acc[i][6],acc[i][7]};
        *(float4*)(C + r*ldc + tn + cn0) = v0;
        *(float4*)(C + r*ldc + tn + cn1) = v1;
    }
    if (SYM && bx != by){
#pragma unroll
        for (int j=0;j<4;j++){
            long r0 = tn + cn0 + j;
            long r1 = tn + cn1 + j;
            float4 u0 = {acc[0][j],  acc[1][j],  acc[2][j],  acc[3][j]};
            float4 u1 = {acc[4][j],  acc[5][j],  acc[6][j],  acc[7][j]};
            float4 u2 = {acc[0][j+4],acc[1][j+4],acc[2][j+4],acc[3][j+4]};
            float4 u3 = {acc[4][j+4],acc[5][j+4],acc[6][j+4],acc[7][j+4]};
            *(float4*)(C + r0*ldc + tm + ty*8)     = u0;
            *(float4*)(C + r0*ldc + tm + ty*8 + 4) = u1;
            *(float4*)(C + r1*ldc + tm + ty*8)     = u2;
            *(float4*)(C + r1*ldc + tm + ty*8 + 4) = u3;
        }
    }
}

template<int VEC, bool SYM>
__global__ __launch_bounds__(256)
void gemm_nt(const float* __restrict__ A, const float* __restrict__ B,
             float* __restrict__ C,
             int Kd, int lda, int ldb, int ldc,
             long sA, long sB, long sC)
{
    if (SYM && blockIdx.y > blockIdx.x) return;
    __shared__ GemmSh sh;
    int bz = blockIdx.z;
    gemm_body<VEC,SYM>(sh.As, sh.Bs, A + (long)bz*sA, B + (long)bz*sB,
                       C + (long)bz*sC, Kd, lda, ldb, ldc,
                       blockIdx.x, blockIdx.y, threadIdx.x);
}

// ---- fused: block-4 uvr GEMM + FPS (fps ~250us hides under gemm ~300us) ----
__global__ __launch_bounds__(256)
void uvr_fps(const float* __restrict__ A, const float* __restrict__ B,
             float* __restrict__ C, int Kd, int lda, int ldb, int ldc, int nx,
             const float* __restrict__ x, int* __restrict__ idxF,
             float* __restrict__ coorOut)
{
    __shared__ ShU sh;
    if (blockIdx.x < 8){
        fps_block(x, idxF, coorOut, blockIdx.x, threadIdx.x, sh.f);
        return;
    }
    int id = blockIdx.x - 8;
    gemm_body<4,false>(sh.g.As, sh.g.Bs, A, B, C, Kd, lda, ldb, ldc,
                       id % nx, id / nx, threadIdx.x);
}

// ---------------- top-8 per row of D (value = 2*dot - xx[m]) ----------------
__global__ __launch_bounds__(256)
void topk8(const float* __restrict__ D, const float* __restrict__ xx,
           int* __restrict__ idx, int b0)
{
    int tid = threadIdx.x, w = tid>>6, lane = tid & 63;
    int gr = blockIdx.x*4 + w;
    int b = b0 + (gr >> 11);
    const float* drow = D + (long)gr*NPTS;
    const float* xb = xx + (long)b*NPTS;
    float tv[8]; int tix[8];
#pragma unroll
    for (int i=0;i<8;i++){ tv[i]=-FLT_MAX; tix[i]=0x7fffffff; }
    for (int it=0; it<8; it++){
        int c = it*256 + lane*4;
        float4 d4 = *(const float4*)(drow + c);
        float4 x4 = *(const float4*)(xb + c);
        ins8(tv,tix, 2.f*d4.x - x4.x, c+0);
        ins8(tv,tix, 2.f*d4.y - x4.y, c+1);
        ins8(tv,tix, 2.f*d4.z - x4.z, c+2);
        ins8(tv,tix, 2.f*d4.w - x4.w, c+3);
    }
    merge_write8(tv, tix, lane, idx + ((long)(b0*NPTS) + gr)*KNN);
}

// ------- edge bn stats + max/min: one gather pass produces everything -------
__global__ __launch_bounds__(256)
void stats_edge(const float* __restrict__ uvr, const int* __restrict__ idx,
                float* __restrict__ ps, float* __restrict__ pq,
                float* __restrict__ mxb, float* __restrict__ mnb,
                int O, int ld)
{
    int tid = threadIdx.x;
    int r0 = blockIdx.x * 128;
    float s0=0,q0=0,s1=0,q1=0;
    for (int rr=0; rr<128; rr++){
        int g = r0 + rr;
        int b = g >> 11;
        const int* ip = idx + (long)g*KNN;
        const float* vrow = uvr + (long)g*ld + O;
        const float* ub[8];
#pragma unroll
        for (int k=0;k<8;k++) ub[k] = uvr + (long)((b<<11) + ip[k])*ld;
        int o = tid;
        if (o < O){
            float vv = vrow[o];
            float mx=-FLT_MAX, mn=FLT_MAX;
#pragma unroll
            for (int k=0;k<8;k++){
                float f = ub[k][o]+vv;
                s0+=f; q0+=f*f; mx=fmaxf(mx,f); mn=fminf(mn,f);
            }
            mxb[(long)g*O+o]=mx; mnb[(long)g*O+o]=mn;
        }
        o = tid + 256;
        if (o < O){
            float vv = vrow[o];
            float mx=-FLT_MAX, mn=FLT_MAX;
#pragma unroll
            for (int k=0;k<8;k++){
                float f = ub[k][o]+vv;
                s1+=f; q1+=f*f; mx=fmaxf(mx,f); mn=fminf(mn,f);
            }
            mxb[(long)g*O+o]=mx; mnb[(long)g*O+o]=mn;
        }
    }
    if (tid < O){ ps[blockIdx.x*2048 + tid] = s0; pq[blockIdx.x*2048 + tid] = q0; }
    if (tid+256 < O){ ps[blockIdx.x*2048 + tid+256] = s1; pq[blockIdx.x*2048 + tid+256] = q1; }
}

// ---------------- stats -> affine (a, c) ----------------
__global__ void reduce_stats(const float* __restrict__ ps, const float* __restrict__ pq,
                             const float* __restrict__ gam, const float* __restrict__ bet,
                             float* __restrict__ ab, float* __restrict__ cb,
                             int O, int np, float invCnt)
{
    int o = blockIdx.x*256 + threadIdx.x;
    if (o >= O) return;
    float s=0.f, q=0.f;
    for (int p=0;p<np;p++){ s += ps[p*2048 + o]; q += pq[p*2048 + o]; }
    float m = s * invCnt;
    float var = q * invCnt - m*m;
    float a = gam[o] * rsqrtf(var + 1e-5f);
    ab[o] = a;
    cb[o] = bet[o] - m*a;
}

// -------- edge finalize: pure streaming (max/min precomputed in stats) ------
__global__ void finalize_edge(const float* __restrict__ mxb, const float* __restrict__ mnb,
                              const float* __restrict__ uvr,
                              const float* __restrict__ ab, const float* __restrict__ cb,
                              float* __restrict__ hcat, int lgO, int ld, int hoff, int hasR)
{
    long t = (long)blockIdx.x*256 + threadIdx.x;
    int O = 1 << lgO;
    int o = (int)(t & (O-1));
    int g = (int)(t >> lgO);
    float a = ab[o], c = cb[o];
    float mx = mxb[t], mn = mnb[t];
    float zz = (a > 0.f) ? (a*mx + c) : (a*mn + c);
    float outv = leakyf(zz);
    if (hasR) outv += uvr[(long)g*ld + 2*O + o];
    hcat[(long)g*1024 + hoff + o] = outv;
}

__global__ void colsum_fin(const float* __restrict__ part, float* __restrict__ hbar)
{
    int tid = threadIdx.x;
    float4 acc = {0,0,0,0};
    for (int p=0;p<128;p++){
        float4 v = ((const float4*)part)[p*256 + tid];
        acc.x+=v.x; acc.y+=v.y; acc.z+=v.z; acc.w+=v.w;
    }
    ((float4*)hbar)[tid] = acc;
}

// ====== MFMA bf16 Gram partials (lower-tri tiles) + folded colsum_part ======
// G[i][j] = sum_m H[m][i]*H[m][j]; 8 chunks x 36 tiles; in-kernel fp32->bf16
// convert + transpose into LDS [128][40] with XOR-swizzled k-groups.
// mfma_f32_16x16x32_bf16: A row=lane&15 k=(lane>>4)*8+e; D col=lane&15,
// row=(lane>>4)*4+reg. bf16 error only perturbs bn5 variance (normalizes out).
__global__ __launch_bounds__(256)
void gram_colsum(const float* __restrict__ H, float* __restrict__ P,
                 float* __restrict__ cspart)
{
    __shared__ __align__(16) unsigned short As[128][40];
    __shared__ __align__(16) unsigned short Bs[128][40];
    int tid = threadIdx.x;
    if (blockIdx.x >= 288){
        int pb = blockIdx.x - 288;                // 0..127: colsum part
        const float4* h4 = (const float4*)(H + (long)pb*128*1024);
        float4 acc = {0,0,0,0};
        for (int r=0;r<128;r++){
            float4 v = h4[r*256 + tid];
            acc.x+=v.x; acc.y+=v.y; acc.z+=v.z; acc.w+=v.w;
        }
        ((float4*)cspart)[pb*256 + tid] = acc;
        return;
    }
    int bz = blockIdx.x / 36, t36 = blockIdx.x % 36;
    int I = 0, q = t36, accq = 8;
    while (q >= accq){ q -= accq; accq--; I++; }
    int ti = (I + q)*128, tj = I*128;             // rows ti >= cols tj
    int w = tid>>6, lane = tid&63;
    int wr = (w>>1)*64, wc = (w&1)*64;
    f32x4 acc[16];
#pragma unroll
    for (int i=0;i<16;i++) acc[i] = (f32x4){0.f,0.f,0.f,0.f};
    const float* Hc = H + (long)bz*2048*1024;
    for (int m0=0; m0<2048; m0+=32){
#pragma unroll
        for (int it=0; it<4; it++){
            int e = tid + it*256;                 // 0..1023
            int mm = e >> 5;                      // m_local 0..31
            int c4 = (e & 31) * 4;
            const float* row = Hc + (long)(m0+mm)*1024;
            float4 av = *(const float4*)(row + ti + c4);
            float4 bv = *(const float4*)(row + tj + c4);
            int mg = mm >> 3, ml = mm & 7;
            float fa[4] = {av.x, av.y, av.z, av.w};
            float fb[4] = {bv.x, bv.y, bv.z, bv.w};
#pragma unroll
            for (int qq=0; qq<4; qq++){
                int ia = c4 + qq;
                int pos = ((mg ^ ((ia>>2)&3))<<3) + ml;
                As[ia][pos] = f2bf(fa[qq]);
                Bs[ia][pos] = f2bf(fb[qq]);
            }
        }
        __syncthreads();
        bf16x8 af[4], bf[4];
#pragma unroll
        for (int f=0; f<4; f++){
            int ra = wr + f*16 + (lane&15);
            int ga = ((lane>>4) ^ ((ra>>2)&3)) << 3;
            af[f] = *(const bf16x8*)&As[ra][ga];
            int rb = wc + f*16 + (lane&15);
            int gb = ((lane>>4) ^ ((rb>>2)&3)) << 3;
            bf[f] = *(const bf16x8*)&Bs[rb][gb];
        }
#pragma unroll
        for (int fi=0; fi<4; fi++)
#pragma unroll
        for (int fj=0; fj<4; fj++)
            acc[fi*4+fj] = __builtin_amdgcn_mfma_f32_16x16x32_bf16(
                af[fi], bf[fj], acc[fi*4+fj], 0, 0, 0);
        __syncthreads();
    }
    float* Pp = P + ((long)bz<<20);
#pragma unroll
    for (int fi=0; fi<4; fi++)
#pragma unroll
    for (int fj=0; fj<4; fj++){
        int row0 = ti + wr + fi*16 + (lane>>4)*4;
        int col  = tj + wc + fj*16 + (lane&15);
#pragma unroll
        for (int r4=0; r4<4; r4++)
            Pp[(long)(row0+r4)*1024 + col] = acc[fi*4+fj][r4];
    }
}

__global__ void greduce(const float* __restrict__ P, float* __restrict__ G)
{
    long i4 = (long)blockIdx.x*256 + threadIdx.x;
    float4 a = ((const float4*)P)[i4];
    for (int p=1;p<8;p++){
        float4 v = ((const float4*)P)[((long)p<<18) + i4];
        a.x+=v.x; a.y+=v.y; a.z+=v.z; a.w+=v.w;
    }
    ((float4*)G)[i4] = a;
}

// fill strictly-upper 64x64 tiles of G from lower triangle
__global__ void mirror_g(float* __restrict__ G)
{
    __shared__ float t[64][65];
    int q = blockIdx.x, I = 0, acc = 15;
    while (q >= acc){ q -= acc; acc--; I++; }
    int J = I + 1 + q;
    int tid = threadIdx.x;
#pragma unroll
    for (int k=0;k<16;k++){
        int e = tid + k*256;
        int sr = e>>6, sc = e&63;
        t[sr][sc] = G[(long)(J*64+sr)*1024 + I*64+sc];
    }
    __syncthreads();
#pragma unroll
    for (int k=0;k<16;k++){
        int e = tid + k*256;
        int dr = e>>6, dc = e&63;
        G[(long)(I*64+dr)*1024 + J*64+dc] = t[dc][dr];
    }
}

// ---------------- bn1d affine from Gram ----------------
__global__ void bn5_prep(const float* __restrict__ w5, const float* __restrict__ T,
                         const float* __restrict__ hbar,
                         const float* __restrict__ g5, const float* __restrict__ b5,
                         float* __restrict__ ab, float* __restrict__ cb)
{
    int w = threadIdx.x>>6, lane = threadIdx.x&63;
    int n = blockIdx.x*4 + w;
    const float4* wr = (const float4*)(w5 + (long)n*1024);
    const float4* tr = (const float4*)(T  + (long)n*1024);
    const float4* hb = (const float4*)hbar;
    float s1=0.f, s2=0.f;
    for (int i=lane;i<256;i+=64){
        float4 wv = wr[i], t4 = tr[i], hv = hb[i];
        s1 += wv.x*hv.x + wv.y*hv.y + wv.z*hv.z + wv.w*hv.w;
        s2 += wv.x*t4.x + wv.y*t4.y + wv.z*t4.z + wv.w*t4.w;
    }
#pragma unroll
    for (int off=32; off; off>>=1){
        s1 += __shfl_xor(s1, off);
        s2 += __shfl_xor(s2, off);
    }
    if (lane==0){
        float m = s1*(1.f/16384.f);
        float qq = s2*(1.f/16384.f);
        float var = qq - m*m;
        float a = g5[n]*rsqrtf(var+1e-5f);
        ab[n]=a; cb[n]=b5[n]-m*a;
    }
}

// ---------------- gather selected hcat rows ----------------
__global__ void gather_rows(const float* __restrict__ src, const int* __restrict__ idxF,
                            float* __restrict__ dst)
{
    int r = blockIdx.x;
    int b = r >> 7;
    int srow = (b<<11) + idxF[r];
    const float4* s = (const float4*)(src + (long)srow*1024);
    float4* d = (float4*)(dst + (long)r*1024);
    for (int c=threadIdx.x; c<256; c+=256) d[c] = s[c];
}

// ---------------- final f: bn + leaky + max/mean over 128 points ------------
__global__ void finalize_f(const float* __restrict__ zsel, const float* __restrict__ ab,
                           const float* __restrict__ cb, float* __restrict__ out)
{
    int b = blockIdx.x >> 3, oc = blockIdx.x & 7;
    int o = oc*256 + threadIdx.x;
    float a = ab[o], c = cb[o];
    float mx = -FLT_MAX, sm = 0.f;
    const float* zp = zsel + (long)b*128*2048 + o;
    for (int i=0;i<128;i++){
        float v = leakyf(a*zp[(long)i*2048] + c);
        mx = fmaxf(mx, v); sm += v;
    }
    out[b*4096 + o] = mx;
    out[b*4096 + 2048 + o] = sm * (1.f/128.f);
}

extern "C" void kernel_launch(void* const* d_in, const int* in_sizes, int n_in,
                              void* d_out, int out_size, void* d_ws, size_t ws_size,
                              hipStream_t stream)
{
    (void)in_sizes; (void)n_in; (void)out_size; (void)ws_size;
    const float* x   = (const float*)d_in[0];
    const float* w1  = (const float*)d_in[1];
    const float* w2  = (const float*)d_in[2];
    const float* w3  = (const float*)d_in[3];
    const float* w4  = (const float*)d_in[4];
    const float* w5  = (const float*)d_in[5];
    const float* rw1 = (const float*)d_in[6];
    const float* rw2 = (const float*)d_in[7];
    const float* rw3 = (const float*)d_in[8];
    const float* g1  = (const float*)d_in[9];  const float* b1 = (const float*)d_in[10];
    const float* g2  = (const float*)d_in[11]; const float* b2 = (const float*)d_in[12];
    const float* g3  = (const float*)d_in[13]; const float* b3 = (const float*)d_in[14];
    const float* g4  = (const float*)d_in[15]; const float* b4 = (const float*)d_in[16];
    const float* g5  = (const float*)d_in[17]; const float* b5 = (const float*)d_in[18];
    float* out = (float*)d_out;

    char* wsb = (char*)d_ws;
    size_t off = 0;
    auto alloc = [&](size_t bytes)->char* {
        char* p = wsb + off;
        off += (bytes + 255) & ~(size_t)255;
        return p;
    };
    float* xt    = (float*)alloc((size_t)16384*3*4);
    float* hcat  = (float*)alloc((size_t)16384*1024*4);
    float* uvr   = (float*)alloc((size_t)16384*1536*4);   // aliased: Dbuf(64MB), gramP(32MB)
    float* Dbuf  = uvr;
    float* gramP = uvr;
    float* G     = (float*)alloc((size_t)1024*1024*4);
    float* T     = (float*)alloc((size_t)2048*1024*4);
    float* zselA = (float*)alloc((size_t)1024*1024*4);
    float* zsel  = (float*)alloc((size_t)1024*2048*4);
    float* mxb   = (float*)alloc((size_t)16384*512*4);
    float* mnb   = (float*)alloc((size_t)16384*512*4);
    float* xx    = (float*)alloc((size_t)16384*4);
    int*   idx   = (int*)  alloc((size_t)16384*8*4);
    float* wcat  = (float*)alloc((size_t)1536*256*4);
    float* ps    = (float*)alloc((size_t)128*2048*4);
    float* pq    = (float*)alloc((size_t)128*2048*4);
    float* cspart= (float*)alloc((size_t)128*1024*4);
    float* hbar  = (float*)alloc((size_t)1024*4);
    float* ab    = (float*)alloc((size_t)2048*4);
    float* cb    = (float*)alloc((size_t)2048*4);
    int*   idxF  = (int*)  alloc((size_t)1024*4);

    transpose_x<<<64, 256, 0, stream>>>(x, xt);

    struct EB {
        const float* X; int lda, C, O, lgO, hoff, hasR;
        const float* w; const float* rw; const float* g; const float* bb;
    };
    EB eb[4] = {
        { xt,        3,    3,   128, 7, 0,   0, w1, nullptr, g1, b1 },
        { hcat+0,    1024, 128, 128, 7, 128, 1, w2, rw1,     g2, b2 },
        { hcat+128,  1024, 128, 256, 8, 256, 1, w3, rw2,     g3, b3 },
        { hcat+256,  1024, 256, 512, 9, 512, 1, w4, rw3,     g4, b4 },
    };
    for (int i=0;i<4;i++){
        EB e = eb[i];
        int ld = (2 + e.hasR) * e.O;
        int nx = ld / 128;
        int tot = e.O * e.C;
        prep_w<<<(tot+255)/256, 256, 0, stream>>>(e.w, e.rw, wcat, e.O, e.C, e.hasR);
        if (i == 0){
            knn_c3<<<1024, 256, 0, stream>>>(x, idx);
            gemm_nt<1,false><<<dim3(nx, 128, 1), 256, 0, stream>>>(
                e.X, wcat, uvr, e.C, e.lda, e.C, ld, 0, 0, 0);
        } else {
            rownorm<<<64, 256, 0, stream>>>(e.X, xx, e.lda, e.C);
            for (int b0=0; b0<8; b0+=4){
                const float* Ab = e.X + (long)b0*NPTS*e.lda;
                gemm_nt<4,true><<<dim3(16,16,4), 256, 0, stream>>>(
                    Ab, Ab, Dbuf, e.C, e.lda, e.lda, 2048,
                    (long)NPTS*e.lda, (long)NPTS*e.lda, (long)NPTS*NPTS);
                topk8<<<2048, 256, 0, stream>>>(Dbuf, xx, idx, b0);
            }
            if (i == 3)
                uvr_fps<<<8 + nx*128, 256, 0, stream>>>(
                    e.X, wcat, uvr, e.C, e.lda, e.C, ld, nx, x, idxF, out);
            else
                gemm_nt<4,false><<<dim3(nx, 128, 1), 256, 0, stream>>>(
                    e.X, wcat, uvr, e.C, e.lda, e.C, ld, 0, 0, 0);
        }
        stats_edge<<<128, 256, 0, stream>>>(uvr, idx, ps, pq, mxb, mnb, e.O, ld);
        reduce_stats<<<(e.O+255)/256, 256, 0, stream>>>(ps, pq, e.g, e.bb, ab, cb,
                                                        e.O, 128, 1.f/131072.f);
        finalize_edge<<<64*e.O, 256, 0, stream>>>(mxb, mnb, uvr, ab, cb, hcat,
                                                  e.lgO, ld, e.hoff, e.hasR);
    }

    // ----- block 5 via bf16-MFMA Gram + folded colsum -----
    gram_colsum<<<288 + 128, 256, 0, stream>>>(hcat, gramP, cspart);
    colsum_fin<<<1, 256, 0, stream>>>(cspart, hbar);
    greduce<<<1024, 256, 0, stream>>>(gramP, G);
    mirror_g<<<120, 256, 0, stream>>>(G);
    gemm_nt<4,false><<<dim3(8,16,1), 256, 0, stream>>>(
        w5, G, T, 1024, 1024, 1024, 1024, 0, 0, 0);
    bn5_prep<<<512, 256, 0, stream>>>(w5, T, hbar, g5, b5, ab, cb);
    gather_rows<<<1024, 256, 0, stream>>>(hcat, idxF, zselA);
    gemm_nt<4,false><<<dim3(16,8,1), 256, 0, stream>>>(
        zselA, w5, zsel, 1024, 1024, 1024, 2048, 0, 0, 0);
    finalize_f<<<64, 256, 0, stream>>>(zsel, ab, cb, out + 3072);
}

// Round 10
// 2826.294 us; speedup vs baseline: 1.5942x; 1.0800x over previous
//
#include <hip/hip_runtime.h>
#include <float.h>

#define NPTS 2048
#define NB 8
#define KNN 8

typedef short bf16x8 __attribute__((ext_vector_type(8)));
typedef float f32x4  __attribute__((ext_vector_type(4)));

__device__ __forceinline__ float leakyf(float x){ return x > 0.f ? x : 0.2f*x; }

__device__ __forceinline__ unsigned short f2bf(float f){
    unsigned u = __float_as_uint(f);
    return (unsigned short)((u + 0x7FFF + ((u>>16)&1)) >> 16);
}

#define BET(v1,i1,v2,i2) (((v1)>(v2)) || ((v1)==(v2) && (i1)<(i2)))

// sorted-insert into per-lane top-8; compile-time indices only (runtime
// indexing spills to scratch -- round-3 22GB pathology).
__device__ __forceinline__ void ins8(float tv[8], int tix[8], float v, int ci)
{
    if (BET(v,ci,tv[7],tix[7])){
        tv[7]=v; tix[7]=ci;
#pragma unroll
        for (int q=7;q>=1;q--){
            if (BET(tv[q],tix[q],tv[q-1],tix[q-1])){
                float t=tv[q]; tv[q]=tv[q-1]; tv[q-1]=t;
                int ti=tix[q]; tix[q]=tix[q-1]; tix[q-1]=ti;
            }
        }
    }
}

__device__ __forceinline__ void merge_write8(float tv[8], int tix[8], int lane,
                                             int* __restrict__ dst)
{
#pragma unroll
    for (int r=0;r<8;r++){
        float bv = tv[0]; int bi = tix[0];
#pragma unroll
        for (int off=32; off; off>>=1){
            float ov = __shfl_xor(bv, off); int oi = __shfl_xor(bi, off);
            if (BET(ov,oi,bv,bi)){ bv=ov; bi=oi; }
        }
        if (tv[0]==bv && tix[0]==bi){
#pragma unroll
            for (int q=0;q<7;q++){ tv[q]=tv[q+1]; tix[q]=tix[q+1]; }
            tv[7]=-FLT_MAX; tix[7]=0x7fffffff;
        }
        if (lane==0) dst[r] = bi;
    }
}

// ---------------- transpose x (B,3,N) -> xt (B*N, 3) ----------------
__global__ void transpose_x(const float* __restrict__ x, float* __restrict__ xt)
{
    int g = blockIdx.x*256 + threadIdx.x;
    if (g >= NB*NPTS) return;
    int b = g >> 11, n = g & 2047;
    const float* xb = x + (long)b*3*NPTS;
    xt[g*3+0] = xb[n];
    xt[g*3+1] = xb[NPTS+n];
    xt[g*3+2] = xb[2*NPTS+n];
}

// =================== FPS: 4-wave + registers + DPP argmax (exact) ==========
__device__ __forceinline__ unsigned long long u64max(unsigned long long a,
                                                     unsigned long long b)
{ return a > b ? a : b; }

template<int CTRL>
__device__ __forceinline__ unsigned long long dpp_max_step(unsigned long long v)
{
    unsigned plo = (unsigned)__builtin_amdgcn_update_dpp(0, (int)(unsigned)v,      CTRL, 0xF, 0xF, true);
    unsigned phi = (unsigned)__builtin_amdgcn_update_dpp(0, (int)(unsigned)(v>>32), CTRL, 0xF, 0xF, true);
    unsigned long long p = ((unsigned long long)phi << 32) | plo;
    return u64max(v, p);
}

__device__ __forceinline__ unsigned long long wave_reduce_max(unsigned long long v)
{
    v = dpp_max_step<0x111>(v);
    v = dpp_max_step<0x112>(v);
    v = dpp_max_step<0x114>(v);
    v = dpp_max_step<0x118>(v);
    v = dpp_max_step<0x142>(v);
    v = dpp_max_step<0x143>(v);
    return v;
}

// Non-contracted ops in XLA's order; (dist<<32)|(2047-j) packing -> exact
// argmax, tie -> lowest j. Proven correct rounds 6-8.
template<int NPP>
__device__ void fps_stage_mw(const float4* __restrict__ pts, int m, int* sel,
                             int tid, unsigned long long* wv)
{
    float cx[NPP], cy[NPP], cz[NPP], dist[NPP];
#pragma unroll
    for (int r=0;r<NPP;r++){
        float4 p = pts[r*256 + tid];
        cx[r]=p.x; cy[r]=p.y; cz[r]=p.z; dist[r]=1e10f;
    }
    int w = tid>>6, lane = tid&63;
    int last = 0;
    if (tid==0) sel[0]=0;
    for (int i=1;i<m;i++){
        float4 lp = pts[last];
#pragma unroll
        for (int r=0;r<NPP;r++){
            float dx=__fsub_rn(cx[r],lp.x), dy=__fsub_rn(cy[r],lp.y), dz=__fsub_rn(cz[r],lp.z);
            float d = __fadd_rn(__fadd_rn(__fmul_rn(dx,dx), __fmul_rn(dy,dy)), __fmul_rn(dz,dz));
            dist[r] = fminf(dist[r], d);
        }
        unsigned long long t[(NPP+1)/2];
        if (NPP == 1){
            t[0] = ((unsigned long long)__float_as_uint(dist[0])<<32) | (unsigned)(2047 - tid);
        } else {
#pragma unroll
            for (int k=0;k<NPP/2;k++){
                unsigned long long a = ((unsigned long long)__float_as_uint(dist[2*k  ])<<32) | (unsigned)(2047 - ((2*k  )*256+tid));
                unsigned long long b = ((unsigned long long)__float_as_uint(dist[2*k+1])<<32) | (unsigned)(2047 - ((2*k+1)*256+tid));
                t[k] = u64max(a, b);
            }
#pragma unroll
            for (int s=NPP/4; s>=1; s>>=1)
#pragma unroll
                for (int k=0;k<s;k++) t[k] = u64max(t[k], t[k+s]);
        }
        unsigned long long best = wave_reduce_max(t[0]);
        if (lane==63) wv[(i&1)*4 + w] = best;
        __syncthreads();
        unsigned long long b0 = wv[(i&1)*4+0], b1 = wv[(i&1)*4+1];
        unsigned long long b2 = wv[(i&1)*4+2], b3 = wv[(i&1)*4+3];
        best = u64max(u64max(b0,b1), u64max(b2,b3));
        int win = 2047 - (int)(unsigned)best;
        last = win;
        if (tid==0) sel[i] = win;
    }
}

struct FpsSh {
    float4 pts1[2048]; float4 pts2[512]; float4 pts3[256];
    int sel1[512]; int sel2[256]; int sel3[128];
    unsigned long long wv[8];
};
struct GemmSh { __align__(16) float As[16][132]; __align__(16) float Bs[16][132]; };
union ShU { FpsSh f; GemmSh g; };

template<bool B> struct ShPick { using T = GemmSh; };
template<> struct ShPick<true> { using T = ShU; };
__device__ __forceinline__ GemmSh& gemsh(GemmSh& s){ return s; }
__device__ __forceinline__ GemmSh& gemsh(ShU& u){ return u.g; }

__device__ void fps_block(const float* __restrict__ x, int* __restrict__ idxF,
                          float* __restrict__ coorOut, int b, int tid, FpsSh& sh)
{
    const float* xb = x + (long)b*3*NPTS;
    for (int i=tid;i<2048;i+=256)
        sh.pts1[i] = make_float4(xb[i], xb[NPTS+i], xb[2*NPTS+i], 0.f);
    __syncthreads();
    fps_stage_mw<8>(sh.pts1, 512, sh.sel1, tid, sh.wv);
    __syncthreads();
    for (int i=tid;i<512;i+=256) sh.pts2[i] = sh.pts1[sh.sel1[i]];
    __syncthreads();
    fps_stage_mw<2>(sh.pts2, 256, sh.sel2, tid, sh.wv);
    __syncthreads();
    for (int i=tid;i<256;i+=256) sh.pts3[i] = sh.pts2[sh.sel2[i]];
    __syncthreads();
    fps_stage_mw<1>(sh.pts3, 128, sh.sel3, tid, sh.wv);
    __syncthreads();
    for (int i=tid;i<128;i+=256){
        int gi = sh.sel1[sh.sel2[sh.sel3[i]]];
        idxF[b*128+i] = gi;
        float4 p = sh.pts1[gi];
        coorOut[(long)b*384 + 0*128 + i] = p.x;
        coorOut[(long)b*384 + 1*128 + i] = p.y;
        coorOut[(long)b*384 + 2*128 + i] = p.z;
    }
}

// ------- block-1 fused kNN on raw coords (C=3); 1024 blocks for occupancy ---
__global__ __launch_bounds__(256)
void knn_c3(const float* __restrict__ x, int* __restrict__ idx)
{
    __shared__ float sx[NPTS], sy[NPTS], sz[NPTS];
    int b = blockIdx.x >> 7, rblk = blockIdx.x & 127;
    const float* xb = x + (long)b*3*NPTS;
    int tid = threadIdx.x;
    for (int i=tid;i<NPTS;i+=256){
        sx[i]=xb[i]; sy[i]=xb[NPTS+i]; sz[i]=xb[2*NPTS+i];
    }
    __syncthreads();
    int w = tid>>6, lane = tid&63;
    for (int rr=0; rr<4; rr++){
        int n = rblk*16 + w*4 + rr;
        float px=sx[n], py=sy[n], pz=sz[n];
        float tv[8]; int tix[8];
#pragma unroll
        for (int i=0;i<8;i++){ tv[i]=-FLT_MAX; tix[i]=0x7fffffff; }
        for (int it=0; it<8; it++){
            int c = it*256 + lane*4;
            float4 qx = *(const float4*)&sx[c];
            float4 qy = *(const float4*)&sy[c];
            float4 qz = *(const float4*)&sz[c];
            float dx, dy, dz;
            dx=qx.x-px; dy=qy.x-py; dz=qz.x-pz;
            ins8(tv,tix, -fmaf(dx,dx,fmaf(dy,dy,dz*dz)), c+0);
            dx=qx.y-px; dy=qy.y-py; dz=qz.y-pz;
            ins8(tv,tix, -fmaf(dx,dx,fmaf(dy,dy,dz*dz)), c+1);
            dx=qx.z-px; dy=qy.z-py; dz=qz.z-pz;
            ins8(tv,tix, -fmaf(dx,dx,fmaf(dy,dy,dz*dz)), c+2);
            dx=qx.w-px; dy=qy.w-py; dz=qz.w-pz;
            ins8(tv,tix, -fmaf(dx,dx,fmaf(dy,dy,dz*dz)), c+3);
        }
        merge_write8(tv, tix, lane, idx + ((long)(b*NPTS+n))*KNN);
    }
}

// ---------------- weight prep: wcat = [w1 ; w2-w1 ; rw] ----------------
__global__ void prep_w(const float* __restrict__ w, const float* __restrict__ rw,
                       float* __restrict__ wcat, int O, int C, int hasR)
{
    int t = blockIdx.x*256 + threadIdx.x;
    if (t >= O*C) return;
    int o = t / C, c = t % C;
    float a = w[o*2*C + c];
    wcat[o*C + c] = a;
    wcat[(O+o)*C + c] = w[o*2*C + C + c] - a;
    if (hasR) wcat[(2*O+o)*C + c] = rw[o*C + c];
}

// ---------------- row squared norms ----------------
__global__ void rownorm(const float* __restrict__ X, float* __restrict__ xx,
                        int lda, int C)
{
    int g = blockIdx.x*256 + threadIdx.x;
    if (g >= NB*NPTS) return;
    const float* r = X + (long)g*lda;
    float s = 0.f;
    for (int c=0;c<C;c++) s += r[c]*r[c];
    xx[g] = s;
}

// ------------- generic GEMM body: C[m][n] = sum_k A[m][k]*B[n][k] -----------
template<int VEC, bool SYM>
__device__ __forceinline__ void gemm_body(
    float (*As)[132], float (*Bs)[132],
    const float* __restrict__ A, const float* __restrict__ B, float* __restrict__ C,
    int Kd, int lda, int ldb, int ldc, int bx, int by, int tid)
{
    int tm = by * 128, tn = bx * 128;
    int ty = tid >> 4, tx = tid & 15;
    int cn0 = tx*4, cn1 = 64 + tx*4;
    float acc[8][8] = {};
    for (int k0 = 0; k0 < Kd; k0 += 16){
        if (VEC == 4){
#pragma unroll
            for (int i=0;i<2;i++){
                int e = tid + i*256;
                int rr = e >> 2, kq = e & 3;
                float4 av = *(const float4*)(A + (long)(tm+rr)*lda + k0 + kq*4);
                float4 bv = *(const float4*)(B + (long)(tn+rr)*ldb + k0 + kq*4);
                As[kq*4+0][rr]=av.x; As[kq*4+1][rr]=av.y; As[kq*4+2][rr]=av.z; As[kq*4+3][rr]=av.w;
                Bs[kq*4+0][rr]=bv.x; Bs[kq*4+1][rr]=bv.y; Bs[kq*4+2][rr]=bv.z; Bs[kq*4+3][rr]=bv.w;
            }
        } else {
#pragma unroll
            for (int i=0;i<8;i++){
                int e = tid + i*256;
                int kk = e & 15, rr = e >> 4;
                int ak = k0 + kk;
                As[kk][rr] = (ak < Kd) ? A[(long)(tm+rr)*lda + ak] : 0.f;
                Bs[kk][rr] = (ak < Kd) ? B[(long)(tn+rr)*ldb + ak] : 0.f;
            }
        }
        __syncthreads();
#pragma unroll
        for (int kk=0;kk<16;kk++){
            float4 a01 = *(const float4*)&As[kk][ty*8];
            float4 a23 = *(const float4*)&As[kk][ty*8+4];
            float4 b01 = *(const float4*)&Bs[kk][cn0];
            float4 b23 = *(const float4*)&Bs[kk][cn1];
            float aa[8] = {a01.x,a01.y,a01.z,a01.w,a23.x,a23.y,a23.z,a23.w};
            float bb[8] = {b01.x,b01.y,b01.z,b01.w,b23.x,b23.y,b23.z,b23.w};
#pragma unroll
            for (int i=0;i<8;i++)
#pragma unroll
                for (int j=0;j<8;j++)
                    acc[i][j] += aa[i]*bb[j];
        }
        __syncthreads();
    }
#pragma unroll
    for (int i=0;i<8;i++){
        long r = tm + ty*8 + i;
        float4 v0 = {acc[i][0],acc[i][1],acc[i][2],acc[i][3]};
        float4 v1 = {acc[i][4],acc[i][5],acc[i][6],acc[i][7]};
        *(float4*)(C + r*ldc + tn + cn0) = v0;
        *(float4*)(C + r*ldc + tn + cn1) = v1;
    }
    if (SYM && bx != by){
#pragma unroll
        for (int j=0;j<4;j++){
            long r0 = tn + cn0 + j;
            long r1 = tn + cn1 + j;
            float4 u0 = {acc[0][j],  acc[1][j],  acc[2][j],  acc[3][j]};
            float4 u1 = {acc[4][j],  acc[5][j],  acc[6][j],  acc[7][j]};
            float4 u2 = {acc[0][j+4],acc[1][j+4],acc[2][j+4],acc[3][j+4]};
            float4 u3 = {acc[4][j+4],acc[5][j+4],acc[6][j+4],acc[7][j+4]};
            *(float4*)(C + r0*ldc + tm + ty*8)     = u0;
            *(float4*)(C + r0*ldc + tm + ty*8 + 4) = u1;
            *(float4*)(C + r1*ldc + tm + ty*8)     = u2;
            *(float4*)(C + r1*ldc + tm + ty*8 + 4) = u3;
        }
    }
}

template<int VEC, bool SYM>
__global__ __launch_bounds__(256)
void gemm_nt(const float* __restrict__ A, const float* __restrict__ B,
             float* __restrict__ C,
             int Kd, int lda, int ldb, int ldc,
             long sA, long sB, long sC)
{
    if (SYM && blockIdx.y > blockIdx.x) return;
    __shared__ GemmSh sh;
    int bz = blockIdx.z;
    gemm_body<VEC,SYM>(sh.As, sh.Bs, A + (long)bz*sA, B + (long)bz*sB,
                       C + (long)bz*sC, Kd, lda, ldb, ldc,
                       blockIdx.x, blockIdx.y, threadIdx.x);
}

// ==== fused per-edge-block: dist-GEMM (4 batches, tri) + uvr GEMM [+ FPS] ===
template<bool FPS>
__global__ __launch_bounds__(256)
void edge_mega(const float* __restrict__ X, const float* __restrict__ W,
               float* __restrict__ D, float* __restrict__ U,
               int Kd, int lda, int ld, int nxU,
               const float* __restrict__ x, int* __restrict__ idxF,
               float* __restrict__ coorOut)
{
    __shared__ typename ShPick<FPS>::T sh;
    int id = blockIdx.x;
    if constexpr (FPS){
        if (id < 8){ fps_block(x, idxF, coorOut, id, threadIdx.x, ((ShU&)sh).f); return; }
        id -= 8;
    }
    GemmSh& g = gemsh(sh);
    if (id < 1024){                       // dist tiles: 4 batches x 16x16
        int bz = id >> 8, r = id & 255, by = r >> 4, bx = r & 15;
        if (by > bx) return;
        const float* Xz = X + (long)bz*NPTS*lda;
        gemm_body<4,true>(g.As, g.Bs, Xz, Xz, D + (long)bz*NPTS*NPTS,
                          Kd, lda, lda, 2048, bx, by, threadIdx.x);
        return;
    }
    id -= 1024;                           // uvr tiles
    gemm_body<4,false>(g.As, g.Bs, X, W, U, Kd, lda, Kd, ld,
                       id % nxU, id / nxU, threadIdx.x);
}

// ---------------- top-8 per row of D (value = 2*dot - xx[m]) ----------------
__global__ __launch_bounds__(256)
void topk8(const float* __restrict__ D, const float* __restrict__ xx,
           int* __restrict__ idx, int b0)
{
    int tid = threadIdx.x, w = tid>>6, lane = tid & 63;
    int gr = blockIdx.x*4 + w;
    int b = b0 + (gr >> 11);
    const float* drow = D + (long)gr*NPTS;
    const float* xb = xx + (long)b*NPTS;
    float tv[8]; int tix[8];
#pragma unroll
    for (int i=0;i<8;i++){ tv[i]=-FLT_MAX; tix[i]=0x7fffffff; }
    for (int it=0; it<8; it++){
        int c = it*256 + lane*4;
        float4 d4 = *(const float4*)(drow + c);
        float4 x4 = *(const float4*)(xb + c);
        ins8(tv,tix, 2.f*d4.x - x4.x, c+0);
        ins8(tv,tix, 2.f*d4.y - x4.y, c+1);
        ins8(tv,tix, 2.f*d4.z - x4.z, c+2);
        ins8(tv,tix, 2.f*d4.w - x4.w, c+3);
    }
    merge_write8(tv, tix, lane, idx + ((long)(b0*NPTS) + gr)*KNN);
}

// ------- edge bn stats + max/min: one gather pass produces everything -------
__global__ __launch_bounds__(256)
void stats_edge(const float* __restrict__ uvr, const int* __restrict__ idx,
                float* __restrict__ ps, float* __restrict__ pq,
                float* __restrict__ mxb, float* __restrict__ mnb,
                int O, int ld)
{
    int tid = threadIdx.x;
    int r0 = blockIdx.x * 128;
    float s0=0,q0=0,s1=0,q1=0;
    for (int rr=0; rr<128; rr++){
        int g = r0 + rr;
        int b = g >> 11;
        const int* ip = idx + (long)g*KNN;
        const float* vrow = uvr + (long)g*ld + O;
        const float* ub[8];
#pragma unroll
        for (int k=0;k<8;k++) ub[k] = uvr + (long)((b<<11) + ip[k])*ld;
        int o = tid;
        if (o < O){
            float vv = vrow[o];
            float mx=-FLT_MAX, mn=FLT_MAX;
#pragma unroll
            for (int k=0;k<8;k++){
                float f = ub[k][o]+vv;
                s0+=f; q0+=f*f; mx=fmaxf(mx,f); mn=fminf(mn,f);
            }
            mxb[(long)g*O+o]=mx; mnb[(long)g*O+o]=mn;
        }
        o = tid + 256;
        if (o < O){
            float vv = vrow[o];
            float mx=-FLT_MAX, mn=FLT_MAX;
#pragma unroll
            for (int k=0;k<8;k++){
                float f = ub[k][o]+vv;
                s1+=f; q1+=f*f; mx=fmaxf(mx,f); mn=fminf(mn,f);
            }
            mxb[(long)g*O+o]=mx; mnb[(long)g*O+o]=mn;
        }
    }
    if (tid < O){ ps[blockIdx.x*2048 + tid] = s0; pq[blockIdx.x*2048 + tid] = q0; }
    if (tid+256 < O){ ps[blockIdx.x*2048 + tid+256] = s1; pq[blockIdx.x*2048 + tid+256] = q1; }
}

// ---------------- stats -> affine (a, c) ----------------
__global__ void reduce_stats(const float* __restrict__ ps, const float* __restrict__ pq,
                             const float* __restrict__ gam, const float* __restrict__ bet,
                             float* __restrict__ ab, float* __restrict__ cb,
                             int O, int np, float invCnt)
{
    int o = blockIdx.x*256 + threadIdx.x;
    if (o >= O) return;
    float s=0.f, q=0.f;
    for (int p=0;p<np;p++){ s += ps[p*2048 + o]; q += pq[p*2048 + o]; }
    float m = s * invCnt;
    float var = q * invCnt - m*m;
    float a = gam[o] * rsqrtf(var + 1e-5f);
    ab[o] = a;
    cb[o] = bet[o] - m*a;
}

// -------- edge finalize: pure streaming (max/min precomputed in stats) ------
__global__ void finalize_edge(const float* __restrict__ mxb, const float* __restrict__ mnb,
                              const float* __restrict__ uvr,
                              const float* __restrict__ ab, const float* __restrict__ cb,
                              float* __restrict__ hcat, int lgO, int ld, int hoff, int hasR)
{
    long t = (long)blockIdx.x*256 + threadIdx.x;
    int O = 1 << lgO;
    int o = (int)(t & (O-1));
    int g = (int)(t >> lgO);
    float a = ab[o], c = cb[o];
    float mx = mxb[t], mn = mnb[t];
    float zz = (a > 0.f) ? (a*mx + c) : (a*mn + c);
    float outv = leakyf(zz);
    if (hasR) outv += uvr[(long)g*ld + 2*O + o];
    hcat[(long)g*1024 + hoff + o] = outv;
}

__global__ void colsum_fin(const float* __restrict__ part, float* __restrict__ hbar)
{
    int tid = threadIdx.x;
    float4 acc = {0,0,0,0};
    for (int p=0;p<128;p++){
        float4 v = ((const float4*)part)[p*256 + tid];
        acc.x+=v.x; acc.y+=v.y; acc.z+=v.z; acc.w+=v.w;
    }
    ((float4*)hbar)[tid] = acc;
}

// ====== MFMA bf16 Gram partials (lower-tri tiles) + folded colsum_part ======
__global__ __launch_bounds__(256)
void gram_colsum(const float* __restrict__ H, float* __restrict__ P,
                 float* __restrict__ cspart)
{
    __shared__ __align__(16) unsigned short As[128][40];
    __shared__ __align__(16) unsigned short Bs[128][40];
    int tid = threadIdx.x;
    if (blockIdx.x >= 288){
        int pb = blockIdx.x - 288;
        const float4* h4 = (const float4*)(H + (long)pb*128*1024);
        float4 acc = {0,0,0,0};
        for (int r=0;r<128;r++){
            float4 v = h4[r*256 + tid];
            acc.x+=v.x; acc.y+=v.y; acc.z+=v.z; acc.w+=v.w;
        }
        ((float4*)cspart)[pb*256 + tid] = acc;
        return;
    }
    int bz = blockIdx.x / 36, t36 = blockIdx.x % 36;
    int I = 0, q = t36, accq = 8;
    while (q >= accq){ q -= accq; accq--; I++; }
    int ti = (I + q)*128, tj = I*128;
    int w = tid>>6, lane = tid&63;
    int wr = (w>>1)*64, wc = (w&1)*64;
    f32x4 acc[16];
#pragma unroll
    for (int i=0;i<16;i++) acc[i] = (f32x4){0.f,0.f,0.f,0.f};
    const float* Hc = H + (long)bz*2048*1024;
    for (int m0=0; m0<2048; m0+=32){
#pragma unroll
        for (int it=0; it<4; it++){
            int e = tid + it*256;
            int mm = e >> 5;
            int c4 = (e & 31) * 4;
            const float* row = Hc + (long)(m0+mm)*1024;
            float4 av = *(const float4*)(row + ti + c4);
            float4 bv = *(const float4*)(row + tj + c4);
            int mg = mm >> 3, ml = mm & 7;
            float fa[4] = {av.x, av.y, av.z, av.w};
            float fb[4] = {bv.x, bv.y, bv.z, bv.w};
#pragma unroll
            for (int qq=0; qq<4; qq++){
                int ia = c4 + qq;
                int pos = ((mg ^ ((ia>>2)&3))<<3) + ml;
                As[ia][pos] = f2bf(fa[qq]);
                Bs[ia][pos] = f2bf(fb[qq]);
            }
        }
        __syncthreads();
        bf16x8 af[4], bf[4];
#pragma unroll
        for (int f=0; f<4; f++){
            int ra = wr + f*16 + (lane&15);
            int ga = ((lane>>4) ^ ((ra>>2)&3)) << 3;
            af[f] = *(const bf16x8*)&As[ra][ga];
            int rb = wc + f*16 + (lane&15);
            int gb = ((lane>>4) ^ ((rb>>2)&3)) << 3;
            bf[f] = *(const bf16x8*)&Bs[rb][gb];
        }
#pragma unroll
        for (int fi=0; fi<4; fi++)
#pragma unroll
        for (int fj=0; fj<4; fj++)
            acc[fi*4+fj] = __builtin_amdgcn_mfma_f32_16x16x32_bf16(
                af[fi], bf[fj], acc[fi*4+fj], 0, 0, 0);
        __syncthreads();
    }
    float* Pp = P + ((long)bz<<20);
#pragma unroll
    for (int fi=0; fi<4; fi++)
#pragma unroll
    for (int fj=0; fj<4; fj++){
        int row0 = ti + wr + fi*16 + (lane>>4)*4;
        int col  = tj + wc + fj*16 + (lane&15);
#pragma unroll
        for (int r4=0; r4<4; r4++)
            Pp[(long)(row0+r4)*1024 + col] = acc[fi*4+fj][r4];
    }
}

__global__ void greduce(const float* __restrict__ P, float* __restrict__ G)
{
    long i4 = (long)blockIdx.x*256 + threadIdx.x;
    float4 a = ((const float4*)P)[i4];
    for (int p=1;p<8;p++){
        float4 v = ((const float4*)P)[((long)p<<18) + i4];
        a.x+=v.x; a.y+=v.y; a.z+=v.z; a.w+=v.w;
    }
    ((float4*)G)[i4] = a;
}

__global__ void mirror_g(float* __restrict__ G)
{
    __shared__ float t[64][65];
    int q = blockIdx.x, I = 0, acc = 15;
    while (q >= acc){ q -= acc; acc--; I++; }
    int J = I + 1 + q;
    int tid = threadIdx.x;
#pragma unroll
    for (int k=0;k<16;k++){
        int e = tid + k*256;
        int sr = e>>6, sc = e&63;
        t[sr][sc] = G[(long)(J*64+sr)*1024 + I*64+sc];
    }
    __syncthreads();
#pragma unroll
    for (int k=0;k<16;k++){
        int e = tid + k*256;
        int dr = e>>6, dc = e&63;
        G[(long)(I*64+dr)*1024 + J*64+dc] = t[dc][dr];
    }
}

// ------- bn1d affine from Gram (T in 4 split-K parts, stride 2048*1024) -----
__global__ void bn5_prep(const float* __restrict__ w5, const float* __restrict__ T,
                         const float* __restrict__ hbar,
                         const float* __restrict__ g5, const float* __restrict__ b5,
                         float* __restrict__ ab, float* __restrict__ cb)
{
    int w = threadIdx.x>>6, lane = threadIdx.x&63;
    int n = blockIdx.x*4 + w;
    const float4* wr = (const float4*)(w5 + (long)n*1024);
    const float4* t0 = (const float4*)(T + (long)n*1024);
    const float4* t1 = (const float4*)(T + (1L<<21) + (long)n*1024);
    const float4* t2 = (const float4*)(T + (2L<<21) + (long)n*1024);
    const float4* t3 = (const float4*)(T + (3L<<21) + (long)n*1024);
    const float4* hb = (const float4*)hbar;
    float s1=0.f, s2=0.f;
    for (int i=lane;i<256;i+=64){
        float4 wv = wr[i], hv = hb[i];
        float4 a0=t0[i], a1=t1[i], a2=t2[i], a3=t3[i];
        float4 t4 = {a0.x+a1.x+a2.x+a3.x, a0.y+a1.y+a2.y+a3.y,
                     a0.z+a1.z+a2.z+a3.z, a0.w+a1.w+a2.w+a3.w};
        s1 += wv.x*hv.x + wv.y*hv.y + wv.z*hv.z + wv.w*hv.w;
        s2 += wv.x*t4.x + wv.y*t4.y + wv.z*t4.z + wv.w*t4.w;
    }
#pragma unroll
    for (int off=32; off; off>>=1){
        s1 += __shfl_xor(s1, off);
        s2 += __shfl_xor(s2, off);
    }
    if (lane==0){
        float m = s1*(1.f/16384.f);
        float qq = s2*(1.f/16384.f);
        float var = qq - m*m;
        float a = g5[n]*rsqrtf(var+1e-5f);
        ab[n]=a; cb[n]=b5[n]-m*a;
    }
}

// ---------------- gather selected hcat rows ----------------
__global__ void gather_rows(const float* __restrict__ src, const int* __restrict__ idxF,
                            float* __restrict__ dst)
{
    int r = blockIdx.x;
    int b = r >> 7;
    int srow = (b<<11) + idxF[r];
    const float4* s = (const float4*)(src + (long)srow*1024);
    float4* d = (float4*)(dst + (long)r*1024);
    for (int c=threadIdx.x; c<256; c+=256) d[c] = s[c];
}

// ------- final f: bn + leaky + max/mean (zsel in 4 split-K parts) -----------
__global__ void finalize_f(const float* __restrict__ zsel, const float* __restrict__ ab,
                           const float* __restrict__ cb, float* __restrict__ out)
{
    int b = blockIdx.x >> 3, oc = blockIdx.x & 7;
    int o = oc*256 + threadIdx.x;
    float a = ab[o], c = cb[o];
    float mx = -FLT_MAX, sm = 0.f;
    const float* zp = zsel + (long)b*128*2048 + o;
    const long PS = (long)1024*2048;
    for (int i=0;i<128;i++){
        long ofs = (long)i*2048;
        float z = zp[ofs] + zp[PS+ofs] + zp[2*PS+ofs] + zp[3*PS+ofs];
        float v = leakyf(a*z + c);
        mx = fmaxf(mx, v); sm += v;
    }
    out[b*4096 + o] = mx;
    out[b*4096 + 2048 + o] = sm * (1.f/128.f);
}

extern "C" void kernel_launch(void* const* d_in, const int* in_sizes, int n_in,
                              void* d_out, int out_size, void* d_ws, size_t ws_size,
                              hipStream_t stream)
{
    (void)in_sizes; (void)n_in; (void)out_size; (void)ws_size;
    const float* x   = (const float*)d_in[0];
    const float* w1  = (const float*)d_in[1];
    const float* w2  = (const float*)d_in[2];
    const float* w3  = (const float*)d_in[3];
    const float* w4  = (const float*)d_in[4];
    const float* w5  = (const float*)d_in[5];
    const float* rw1 = (const float*)d_in[6];
    const float* rw2 = (const float*)d_in[7];
    const float* rw3 = (const float*)d_in[8];
    const float* g1  = (const float*)d_in[9];  const float* b1 = (const float*)d_in[10];
    const float* g2  = (const float*)d_in[11]; const float* b2 = (const float*)d_in[12];
    const float* g3  = (const float*)d_in[13]; const float* b3 = (const float*)d_in[14];
    const float* g4  = (const float*)d_in[15]; const float* b4 = (const float*)d_in[16];
    const float* g5  = (const float*)d_in[17]; const float* b5 = (const float*)d_in[18];
    float* out = (float*)d_out;

    char* wsb = (char*)d_ws;
    size_t off = 0;
    auto alloc = [&](size_t bytes)->char* {
        char* p = wsb + off;
        off += (bytes + 255) & ~(size_t)255;
        return p;
    };
    float* xt    = (float*)alloc((size_t)16384*3*4);
    float* hcat  = (float*)alloc((size_t)16384*1024*4);
    // uvr region 96MB; later aliased by gramP (32MB), then T (32MB) + zsel (32MB)
    float* uvr   = (float*)alloc((size_t)16384*1536*4);
    float* gramP = uvr;
    float* T     = uvr;                                  // after greduce
    float* zsel  = uvr + (size_t)8*1024*1024;            // +32MB
    // Dbuf region 67MB; aliased by mxb/mnb (disjoint lifetime within a block)
    float* Dbuf  = (float*)alloc((size_t)4*2048*2048*4);
    float* mxb   = Dbuf;
    float* mnb   = Dbuf + (size_t)16384*512;
    float* G     = (float*)alloc((size_t)1024*1024*4);
    float* zselA = (float*)alloc((size_t)1024*1024*4);
    float* xx    = (float*)alloc((size_t)16384*4);
    int*   idx   = (int*)  alloc((size_t)16384*8*4);
    float* wcat  = (float*)alloc((size_t)1536*256*4);
    float* ps    = (float*)alloc((size_t)128*2048*4);
    float* pq    = (float*)alloc((size_t)128*2048*4);
    float* cspart= (float*)alloc((size_t)128*1024*4);
    float* hbar  = (float*)alloc((size_t)1024*4);
    float* ab    = (float*)alloc((size_t)2048*4);
    float* cb    = (float*)alloc((size_t)2048*4);
    int*   idxF  = (int*)  alloc((size_t)1024*4);

    transpose_x<<<64, 256, 0, stream>>>(x, xt);

    struct EB {
        const float* X; int lda, C, O, lgO, hoff, hasR;
        const float* w; const float* rw; const float* g; const float* bb;
    };
    EB eb[4] = {
        { xt,        3,    3,   128, 7, 0,   0, w1, nullptr, g1, b1 },
        { hcat+0,    1024, 128, 128, 7, 128, 1, w2, rw1,     g2, b2 },
        { hcat+128,  1024, 128, 256, 8, 256, 1, w3, rw2,     g3, b3 },
        { hcat+256,  1024, 256, 512, 9, 512, 1, w4, rw3,     g4, b4 },
    };
    for (int i=0;i<4;i++){
        EB e = eb[i];
        int ld = (2 + e.hasR) * e.O;
        int nxU = ld / 128;
        int tot = e.O * e.C;
        prep_w<<<(tot+255)/256, 256, 0, stream>>>(e.w, e.rw, wcat, e.O, e.C, e.hasR);
        if (i == 0){
            knn_c3<<<1024, 256, 0, stream>>>(x, idx);
            gemm_nt<1,false><<<dim3(nxU, 128, 1), 256, 0, stream>>>(
                e.X, wcat, uvr, e.C, e.lda, e.C, ld, 0, 0, 0);
        } else {
            rownorm<<<64, 256, 0, stream>>>(e.X, xx, e.lda, e.C);
            if (i == 3)
                edge_mega<true><<<8 + 1024 + nxU*128, 256, 0, stream>>>(
                    e.X, wcat, Dbuf, uvr, e.C, e.lda, ld, nxU, x, idxF, out);
            else
                edge_mega<false><<<1024 + nxU*128, 256, 0, stream>>>(
                    e.X, wcat, Dbuf, uvr, e.C, e.lda, ld, nxU,
                    nullptr, nullptr, nullptr);
            topk8<<<2048, 256, 0, stream>>>(Dbuf, xx, idx, 0);
            const float* X4 = e.X + (long)4*NPTS*e.lda;
            gemm_nt<4,true><<<dim3(16,16,4), 256, 0, stream>>>(
                X4, X4, Dbuf, e.C, e.lda, e.lda, 2048,
                (long)NPTS*e.lda, (long)NPTS*e.lda, (long)NPTS*NPTS);
            topk8<<<2048, 256, 0, stream>>>(Dbuf, xx, idx, 4);
        }
        stats_edge<<<128, 256, 0, stream>>>(uvr, idx, ps, pq, mxb, mnb, e.O, ld);
        reduce_stats<<<(e.O+255)/256, 256, 0, stream>>>(ps, pq, e.g, e.bb, ab, cb,
                                                        e.O, 128, 1.f/131072.f);
        finalize_edge<<<64*e.O, 256, 0, stream>>>(mxb, mnb, uvr, ab, cb, hcat,
                                                  e.lgO, ld, e.hoff, e.hasR);
    }

    // ----- block 5 via bf16-MFMA Gram + split-K late GEMMs -----
    gram_colsum<<<288 + 128, 256, 0, stream>>>(hcat, gramP, cspart);
    colsum_fin<<<1, 256, 0, stream>>>(cspart, hbar);
    greduce<<<1024, 256, 0, stream>>>(gramP, G);
    mirror_g<<<120, 256, 0, stream>>>(G);
    gemm_nt<4,false><<<dim3(8,16,4), 256, 0, stream>>>(
        w5, G, T, 256, 1024, 1024, 1024, 256, 256, (long)2048*1024);
    bn5_prep<<<512, 256, 0, stream>>>(w5, T, hbar, g5, b5, ab, cb);
    gather_rows<<<1024, 256, 0, stream>>>(hcat, idxF, zselA);
    gemm_nt<4,false><<<dim3(16,8,4), 256, 0, stream>>>(
        zselA, w5, zsel, 256, 1024, 1024, 2048, 256, 256, (long)1024*2048);
    finalize_f<<<64, 256, 0, stream>>>(zsel, ab, cb, out + 3072);
}